// Round 16
// baseline (426.121 us; speedup 1.0000x reference)
//
#include <hip/hip_runtime.h>

// ---------------------------------------------------------------------------
// mLSTM block, MI355X. B=2,S=2048,D=1024,NH=8,DH=128.
// v15: attn split to 32-q-row blocks (1024 blocks, 4/CU), wave = (q-half,
//      PV-channel-half), single-buffer LDS 39.4KB, QK duplicated per channel
//      half (cheap). GEMMs = v14. Numerics = v12 modulo LN half-combine.
// ---------------------------------------------------------------------------

typedef __bf16 bf16x8 __attribute__((ext_vector_type(8)));
typedef float f32x4 __attribute__((ext_vector_type(4)));
typedef unsigned short us8 __attribute__((ext_vector_type(8)));
typedef unsigned short us4 __attribute__((ext_vector_type(4)));

__device__ __forceinline__ unsigned short f2bf(float f) {
    unsigned int u = __builtin_bit_cast(unsigned int, f);
    unsigned int r = u + 0x7fffu + ((u >> 16) & 1u);
    return (unsigned short)(r >> 16);
}
__device__ __forceinline__ float bf2f(unsigned short h) {
    unsigned int u = ((unsigned int)h) << 16;
    return __builtin_bit_cast(float, u);
}
__device__ __forceinline__ f32x4 mfma16(bf16x8 a, bf16x8 b, f32x4 c) {
    return __builtin_amdgcn_mfma_f32_16x16x32_bf16(a, b, c, 0, 0, 0);
}

// ---------------- K0 ----------------
__global__ __launch_bounds__(256) void k_split_bf16(const float* __restrict__ in,
                                                    unsigned short* __restrict__ hi,
                                                    unsigned short* __restrict__ lo, int n) {
    int i = blockIdx.x * 256 + threadIdx.x;
    if (i < n) {
        float f = in[i];
        unsigned short h = f2bf(f);
        hi[i] = h;
        lo[i] = f2bf(f - bf2f(h));
    }
}

__global__ __launch_bounds__(256) void build_wcat(const float* __restrict__ Wq,
                                                  const float* __restrict__ Wk,
                                                  const float* __restrict__ Wv,
                                                  const float* __restrict__ Wog,
                                                  unsigned short* __restrict__ wh,
                                                  unsigned short* __restrict__ wl) {
    int idx = blockIdx.x * 256 + threadIdx.x;
    if (idx >= 2304 * 1024) return;
    int row = idx >> 10, col = idx & 1023;
    float v;
    if (row < 1024)      v = Wq[(size_t)row * 1024 + col] * 0.08838834764831845f;
    else if (row < 1152) v = Wk[(size_t)(row - 1024) * 1024 + col];
    else if (row < 1280) v = Wv[(size_t)(row - 1152) * 1024 + col];
    else                 v = Wog[(size_t)(row - 1280) * 1024 + col];
    unsigned short h = f2bf(v);
    wh[idx] = h;
    wl[idx] = f2bf(v - bf2f(h));
}

// ---------------- K1: gates ----------------
__global__ __launch_bounds__(256) void gates_kernel(const float* __restrict__ x,
                                                    const float* __restrict__ Wi,
                                                    const float* __restrict__ bi,
                                                    const float* __restrict__ Wf,
                                                    const float* __restrict__ bfb,
                                                    float* __restrict__ ipre,
                                                    float* __restrict__ lgf) {
    int bs = blockIdx.x;
    int b = bs >> 11, s = bs & 2047;
    const float* xr = x + (size_t)bs * 1024;
    int lane = threadIdx.x & 63, w = threadIdx.x >> 6;
    const float* W = (w < 2) ? Wi : Wf;
    int h0 = (w & 1) * 4;
    float dot0 = 0.f, dot1 = 0.f, dot2 = 0.f, dot3 = 0.f;
    for (int i = lane; i < 1024; i += 64) {
        float xv = xr[i];
        dot0 += xv * W[(size_t)(h0 + 0) * 1024 + i];
        dot1 += xv * W[(size_t)(h0 + 1) * 1024 + i];
        dot2 += xv * W[(size_t)(h0 + 2) * 1024 + i];
        dot3 += xv * W[(size_t)(h0 + 3) * 1024 + i];
    }
#pragma unroll
    for (int o = 32; o; o >>= 1) {
        dot0 += __shfl_xor(dot0, o);
        dot1 += __shfl_xor(dot1, o);
        dot2 += __shfl_xor(dot2, o);
        dot3 += __shfl_xor(dot3, o);
    }
    if (lane == 0) {
        float d[4] = {dot0, dot1, dot2, dot3};
#pragma unroll
        for (int j = 0; j < 4; j++) {
            int hh = h0 + j;
            if (w < 2) {
                float z = d[j] + bi[hh];
                z = 15.f * tanhf(z * (1.f / 15.f));
                ipre[((size_t)b * 8 + hh) * 2048 + s] = z;
            } else {
                float z = d[j] + bfb[hh];
                z = 15.f * tanhf(z * (1.f / 15.f));
                lgf[((size_t)b * 8 + hh) * 2048 + s] = fminf(z, 0.f) - log1pf(expf(-fabsf(z)));
            }
        }
    }
}

// ---------------- K2: scan ----------------
__global__ void scan_kernel(const float* __restrict__ ipre, const float* __restrict__ lgf,
                            float* __restrict__ csum, float* __restrict__ aarr,
                            float* __restrict__ marr) {
    int bh = blockIdx.x;
    int lane = threadIdx.x;
    const float* lf = lgf + (size_t)bh * 2048;
    const float* ip = ipre + (size_t)bh * 2048;
    float* cs = csum + (size_t)bh * 2048;
    float* aa = aarr + (size_t)bh * 2048;
    float* mm = marr + (size_t)bh * 2048;
    float carry = 0.f;
    float carrym = -1e30f;
    for (int c = 0; c < 32; c++) {
        float v = lf[c * 64 + lane];
#pragma unroll
        for (int o = 1; o < 64; o <<= 1) {
            float t = __shfl_up(v, o);
            if (lane >= o) v += t;
        }
        float cval = carry + v;
        cs[c * 64 + lane] = cval;
        float a = ip[c * 64 + lane] - cval;
        aa[c * 64 + lane] = a;
        float mv = a;
#pragma unroll
        for (int o = 1; o < 64; o <<= 1) {
            float t = __shfl_up(mv, o);
            if (lane >= o) mv = fmaxf(mv, t);
        }
        float mval = fmaxf(carrym, mv);
        mm[c * 64 + lane] = mval;
        carry = __shfl(cval, 63);
        carrym = __shfl(mval, 63);
    }
}

// ---- K3/K6: 3-product GEMM, 128x128 tile, early prefetch; og rows 1-product --
__global__ __launch_bounds__(256) void gemm_bt3(const unsigned short* __restrict__ Ah,
                                                const unsigned short* __restrict__ Al,
                                                const unsigned short* __restrict__ Bh,
                                                const unsigned short* __restrict__ Bl,
                                                void* __restrict__ Cp,
                                                unsigned short* __restrict__ Clo,
                                                int K, int ldc, int c_bf16, int og_y0) {
    __shared__ __attribute__((aligned(16))) unsigned short Ash[128 * 40];
    __shared__ __attribute__((aligned(16))) unsigned short Asl[128 * 40];
    __shared__ __attribute__((aligned(16))) unsigned short Bsh[128 * 40];
    __shared__ __attribute__((aligned(16))) unsigned short Bsl[128 * 40];
    const int tid = threadIdx.x;
    const int lane = tid & 63, wv = tid >> 6;
    const int wr = wv >> 1, wc = wv & 1;
    const int fr = lane & 15, fg = lane >> 4;
    const int srow = tid >> 1, scol = (tid & 1) * 16;
    const bool full3 = (blockIdx.y < (unsigned)og_y0);
    const size_t aoff = (size_t)(blockIdx.x * 128 + srow) * K + scol;
    const size_t boff = (size_t)(blockIdx.y * 128 + srow) * K + scol;
    f32x4 acc[4][4] = {};
    us8 avh0, avh1, avl0, avl1, bvh0, bvh1, bvl0, bvl1;
#define GLOAD(KT)                                                              \
    {                                                                          \
        avh0 = *(const us8*)(Ah + aoff + (KT));                                \
        avh1 = *(const us8*)(Ah + aoff + (KT) + 8);                            \
        avl0 = *(const us8*)(Al + aoff + (KT));                                \
        avl1 = *(const us8*)(Al + aoff + (KT) + 8);                            \
        bvh0 = *(const us8*)(Bh + boff + (KT));                                \
        bvh1 = *(const us8*)(Bh + boff + (KT) + 8);                            \
        bvl0 = *(const us8*)(Bl + boff + (KT));                                \
        bvl1 = *(const us8*)(Bl + boff + (KT) + 8);                            \
    }
    GLOAD(0);
    for (int kt = 0; kt < K; kt += 32) {
        __syncthreads();
        *(us8*)&Ash[srow * 40 + scol] = avh0;
        *(us8*)&Ash[srow * 40 + scol + 8] = avh1;
        *(us8*)&Asl[srow * 40 + scol] = avl0;
        *(us8*)&Asl[srow * 40 + scol + 8] = avl1;
        *(us8*)&Bsh[srow * 40 + scol] = bvh0;
        *(us8*)&Bsh[srow * 40 + scol + 8] = bvh1;
        *(us8*)&Bsl[srow * 40 + scol] = bvl0;
        *(us8*)&Bsl[srow * 40 + scol + 8] = bvl1;
        __syncthreads();
        if (kt + 32 < K) GLOAD(kt + 32);
        bf16x8 bfh[4], bfl[4];
#pragma unroll
        for (int j = 0; j < 4; j++) {
            bfh[j] = __builtin_bit_cast(bf16x8, *(const us8*)&Bsh[(64 * wc + 16 * j + fr) * 40 + fg * 8]);
            bfl[j] = __builtin_bit_cast(bf16x8, *(const us8*)&Bsl[(64 * wc + 16 * j + fr) * 40 + fg * 8]);
        }
        __builtin_amdgcn_s_setprio(1);
        if (full3) {
#pragma unroll
            for (int i = 0; i < 4; i++) {
                bf16x8 afh = __builtin_bit_cast(bf16x8, *(const us8*)&Ash[(64 * wr + 16 * i + fr) * 40 + fg * 8]);
                bf16x8 afl = __builtin_bit_cast(bf16x8, *(const us8*)&Asl[(64 * wr + 16 * i + fr) * 40 + fg * 8]);
#pragma unroll
                for (int j = 0; j < 4; j++) {
                    acc[i][j] = mfma16(afh, bfh[j], acc[i][j]);
                    acc[i][j] = mfma16(afh, bfl[j], acc[i][j]);
                    acc[i][j] = mfma16(afl, bfh[j], acc[i][j]);
                }
            }
        } else {
#pragma unroll
            for (int i = 0; i < 4; i++) {
                bf16x8 afh = __builtin_bit_cast(bf16x8, *(const us8*)&Ash[(64 * wr + 16 * i + fr) * 40 + fg * 8]);
#pragma unroll
                for (int j = 0; j < 4; j++)
                    acc[i][j] = mfma16(afh, bfh[j], acc[i][j]);
            }
        }
        __builtin_amdgcn_s_setprio(0);
    }
#undef GLOAD
#pragma unroll
    for (int i = 0; i < 4; i++)
#pragma unroll
        for (int j = 0; j < 4; j++)
#pragma unroll
            for (int e = 0; e < 4; e++) {
                int r = blockIdx.x * 128 + 64 * wr + 16 * i + fg * 4 + e;
                int c = blockIdx.y * 128 + 64 * wc + 16 * j + fr;
                float v = acc[i][j][e];
                if (c_bf16) {
                    unsigned short h = f2bf(v);
                    ((unsigned short*)Cp)[(size_t)r * ldc + c] = h;
                    Clo[(size_t)r * ldc + c] = f2bf(v - bf2f(h));
                } else {
                    ((float*)Cp)[(size_t)r * ldc + c] = v;
                }
            }
}

// ---------------- K4: vT via coalesced LDS-tiled transpose ----------------
__global__ __launch_bounds__(256) void make_vt(const unsigned short* __restrict__ ph,
                                               const unsigned short* __restrict__ pl,
                                               unsigned short* __restrict__ vTh,
                                               unsigned short* __restrict__ vTl) {
    __shared__ __attribute__((aligned(16))) unsigned short th[64 * 68];
    __shared__ __attribute__((aligned(16))) unsigned short tl[64 * 68];
    const int bid = blockIdx.x;
    const int st = bid & 31, ct = (bid >> 5) & 1, b = bid >> 6;
    const int tid = threadIdx.x;
    {
        const int sr = tid >> 2, cc = (tid & 3) * 16;
        const size_t rbase = (size_t)(b * 2048 + st * 64 + sr) * 2304 + 1152 + ct * 64 + cc;
        us8 a0 = *(const us8*)(ph + rbase);
        us8 a1 = *(const us8*)(ph + rbase + 8);
        us8 c0 = *(const us8*)(pl + rbase);
        us8 c1 = *(const us8*)(pl + rbase + 8);
        *(us8*)&th[sr * 68 + cc] = a0;
        *(us8*)&th[sr * 68 + cc + 8] = a1;
        *(us8*)&tl[sr * 68 + cc] = c0;
        *(us8*)&tl[sr * 68 + cc + 8] = c1;
    }
    __syncthreads();
    {
        const int cr = tid >> 2, ss = (tid & 3) * 16;
        us8 oh0, oh1, ol0, ol1;
#pragma unroll
        for (int e = 0; e < 8; e++) {
            oh0[e] = th[(ss + e) * 68 + cr];
            oh1[e] = th[(ss + 8 + e) * 68 + cr];
            ol0[e] = tl[(ss + e) * 68 + cr];
            ol1[e] = tl[(ss + 8 + e) * 68 + cr];
        }
        const size_t wbase = (size_t)b * 128 * 2048 + (size_t)(ct * 64 + cr) * 2048 + st * 64 + ss;
        *(us8*)&vTh[wbase] = oh0;
        *(us8*)&vTh[wbase + 8] = oh1;
        *(us8*)&vTl[wbase] = ol0;
        *(us8*)&vTl[wbase + 8] = ol1;
    }
}

// ---------------- K5: attn — 32-q-row blocks, wave=(q-half, ch-half) --------
__global__ __launch_bounds__(256, 4) void attn_fused(const unsigned short* __restrict__ projh,
                                                     const unsigned short* __restrict__ projl,
                                                     const unsigned short* __restrict__ vTh,
                                                     const unsigned short* __restrict__ vTl,
                                                     const float* __restrict__ aarr,
                                                     const float* __restrict__ marr,
                                                     const float* __restrict__ csum,
                                                     const float* __restrict__ lnw,
                                                     unsigned short* __restrict__ ho_hi,
                                                     unsigned short* __restrict__ ho_lo) {
    __shared__ __attribute__((aligned(16))) unsigned short Klh[32 * 148];
    __shared__ __attribute__((aligned(16))) unsigned short Kll[32 * 148];
    __shared__ __attribute__((aligned(16))) unsigned short Vlh[128 * 40];
    __shared__ __attribute__((aligned(16))) unsigned short Vll[128 * 40];
    __shared__ float al[32];
    __shared__ float lnc[2][16][2][2];   // [qhalf][fr][chhalf][{s1,s2}]

    // 1024 blocks = bh(16) x slot(64); qt32 = slot<32 ? slot : 95-slot
    // Same-CU blocks (i, i+256, i+512, i+768) get constant total work (130 tiles).
    const int idx = blockIdx.x;
    const int bh = idx & 15;
    const int slot = (idx >> 4) & 63;
    const int qt32 = (slot < 32) ? slot : (95 - slot);
    const int b = bh >> 3, h = bh & 7;
    const int tid = threadIdx.x, lane = tid & 63, w = tid >> 6;
    const int fr = lane & 15, fg = lane >> 4;
    const int qh = w & 1;                 // q-row half
    const int jbh = w >> 1;               // PV channel half (jb base = jbh*4)
    const int q0 = qt32 * 32;
    const int qg = q0 + 16 * qh + fr;     // this lane's q row

    // Q fragments hi/lo (B-operand layout, col=fr)
    bf16x8 qfh[4], qfl[4];
    {
        const size_t qoff = (size_t)(b * 2048 + qg) * 2304 + h * 128;
#pragma unroll
        for (int ks = 0; ks < 4; ks++) {
            qfh[ks] = __builtin_bit_cast(bf16x8, *(const us8*)(projh + qoff + ks * 32 + fg * 8));
            qfl[ks] = __builtin_bit_cast(bf16x8, *(const us8*)(projl + qoff + ks * 32 + fg * 8));
        }
    }
    const float ma_q = marr[(size_t)bh * 2048 + qg];

    f32x4 acc[4] = {};
    float b_run = 0.f;

    const int kr = tid >> 3, kc = (tid & 7) * 16;   // K staging
    const int vr = tid >> 1, vc = (tid & 1) * 16;   // V^T staging
    const size_t kbase = (size_t)(b * 2048) * 2304 + 1024;
    const size_t vtbase = (size_t)b * 128 * 2048;

    const int nt = qt32 + 1;
    us8 kh0, kh1, kl0, kl1, vh0, vh1, vl0, vl1;
    float a_st;
#define LOADT(T0)                                                              \
    {                                                                          \
        const size_t ko = kbase + (size_t)((T0) + kr) * 2304 + kc;             \
        const size_t vo = vtbase + (size_t)vr * 2048 + (T0) + vc;              \
        kh0 = *(const us8*)(projh + ko);                                       \
        kh1 = *(const us8*)(projh + ko + 8);                                   \
        kl0 = *(const us8*)(projl + ko);                                       \
        kl1 = *(const us8*)(projl + ko + 8);                                   \
        vh0 = *(const us8*)(vTh + vo);                                         \
        vh1 = *(const us8*)(vTh + vo + 8);                                     \
        vl0 = *(const us8*)(vTl + vo);                                         \
        vl1 = *(const us8*)(vTl + vo + 8);                                     \
        a_st = (tid < 32) ? aarr[(size_t)bh * 2048 + (T0) + tid] : 0.f;        \
    }

    LOADT(0);
    for (int kt = 0; kt < nt; kt++) {
        const int t0 = kt * 32;
        *(us8*)&Klh[kr * 148 + kc] = kh0;
        *(us8*)&Klh[kr * 148 + kc + 8] = kh1;
        *(us8*)&Kll[kr * 148 + kc] = kl0;
        *(us8*)&Kll[kr * 148 + kc + 8] = kl1;
        *(us8*)&Vlh[vr * 40 + vc] = vh0;
        *(us8*)&Vlh[vr * 40 + vc + 8] = vh1;
        *(us8*)&Vll[vr * 40 + vc] = vl0;
        *(us8*)&Vll[vr * 40 + vc + 8] = vl1;
        if (tid < 32) al[tid] = a_st;
        __syncthreads();
        if (kt + 1 < nt) LOADT(t0 + 32);

        // S^T = mfma(K, Q): D[key(row), q(col)]; 3-acc split
        float dj[2][4];
#pragma unroll
        for (int j = 0; j < 2; j++) {
            f32x4 sfa = {}, sfb = {}, sfc = {};
            __builtin_amdgcn_s_setprio(1);
#pragma unroll
            for (int ks = 0; ks < 4; ks++) {
                bf16x8 kfh = __builtin_bit_cast(bf16x8, *(const us8*)&Klh[(j * 16 + fr) * 148 + ks * 32 + fg * 8]);
                bf16x8 kfl = __builtin_bit_cast(bf16x8, *(const us8*)&Kll[(j * 16 + fr) * 148 + ks * 32 + fg * 8]);
                sfa = mfma16(kfh, qfh[ks], sfa);
                sfb = mfma16(kfh, qfl[ks], sfb);
                sfc = mfma16(kfl, qfh[ks], sfc);
            }
            __builtin_amdgcn_s_setprio(0);
            f32x4 sf = (sfa + sfb) + sfc;
#pragma unroll
            for (int r = 0; r < 4; r++) {
                const int kloc = j * 16 + fg * 4 + r;
                const int key = t0 + kloc;
                const float atv = al[kloc];
                dj[j][r] = (key <= qg) ? sf[r] * __expf(atv - ma_q) : 0.f;
            }
        }

        // b_run: sum over the 32 keys for q=fr (replicated over fg)
        {
            float ts = dj[0][0] + dj[0][1] + dj[0][2] + dj[0][3]
                     + dj[1][0] + dj[1][1] + dj[1][2] + dj[1][3];
            ts += __shfl_xor(ts, 16);
            ts += __shfl_xor(ts, 32);
            b_run += ts;
        }

        // D-frag -> B-frag relayout (in-register): p8[e] = P[q=fr][k=8g+e]
        float p8[8];
        const int srlo = 32 * ((lane >> 4) & 1) + fr;
#pragma unroll
        for (int e = 0; e < 8; e++) {
            const int sl = srlo + ((e >= 4) ? 16 : 0);
            const float v0 = __shfl(dj[0][e & 3], sl);
            const float v1 = __shfl(dj[1][e & 3], sl);
            p8[e] = (lane & 32) ? v1 : v0;
        }
        us8 phu, plu;
#pragma unroll
        for (int e = 0; e < 8; e++) {
            unsigned short hh = f2bf(p8[e]);
            phu[e] = hh;
            plu[e] = f2bf(p8[e] - bf2f(hh));
        }
        const bf16x8 pfh = __builtin_bit_cast(bf16x8, phu);
        const bf16x8 pfl = __builtin_bit_cast(bf16x8, plu);

        // PV: this wave's 4 jb (channel half jbh)
        __builtin_amdgcn_s_setprio(1);
#pragma unroll
        for (int jj = 0; jj < 4; jj++) {
            const int jb = jbh * 4 + jj;
            bf16x8 vfh = __builtin_bit_cast(bf16x8, *(const us8*)&Vlh[(jb * 16 + fr) * 40 + fg * 8]);
            bf16x8 vfl = __builtin_bit_cast(bf16x8, *(const us8*)&Vll[(jb * 16 + fr) * 40 + fg * 8]);
            acc[jj] = mfma16(vfh, pfh, acc[jj]);
            acc[jj] = mfma16(vfh, pfl, acc[jj]);
            acc[jj] = mfma16(vfl, pfh, acc[jj]);
        }
        __builtin_amdgcn_s_setprio(0);
        __syncthreads();
    }
#undef LOADT

    // finalize: n-divide (identical per wave), LN via cross-wave half-combine
    const float cs_q = csum[(size_t)bh * 2048 + qg];
    const float nf = __expf(-(cs_q + ma_q));
    const float n = fmaxf(fabsf(b_run), nf);
    const float inv = 1.f / (n + 1e-6f);
#pragma unroll
    for (int jj = 0; jj < 4; jj++) acc[jj] *= inv;

    float s1 = 0.f, s2 = 0.f;
#pragma unroll
    for (int jj = 0; jj < 4; jj++)
#pragma unroll
        for (int e = 0; e < 4; e++) {
            const float v = acc[jj][e];
            s1 += v;
            s2 += v * v;
        }
    s1 += __shfl_xor(s1, 16);
    s1 += __shfl_xor(s1, 32);
    s2 += __shfl_xor(s2, 16);
    s2 += __shfl_xor(s2, 32);
    if (fg == 0) {
        lnc[qh][fr][jbh][0] = s1;
        lnc[qh][fr][jbh][1] = s2;
    }
    __syncthreads();
    const float s1t = lnc[qh][fr][0][0] + lnc[qh][fr][1][0];
    const float s2t = lnc[qh][fr][0][1] + lnc[qh][fr][1][1];
    const float mu = s1t * (1.f / 128.f);
    const float var = fmaxf(s2t * (1.f / 128.f) - mu * mu, 0.f);
    const float rstd = rsqrtf(var + 1e-6f);

    const size_t obase = (size_t)(b * 2048 + qg) * 2304 + 1280 + h * 128 + fg * 4;
    const size_t hbase = (size_t)(b * 2048 + qg) * 1024 + h * 128 + fg * 4;
#pragma unroll
    for (int jj = 0; jj < 4; jj++) {
        const int jb = jbh * 4 + jj;
        us4 ogh = *(const us4*)(projh + obase + jb * 16);
        us4 ogl = *(const us4*)(projl + obase + jb * 16);
        f32x4 lw = *(const f32x4*)&lnw[h * 128 + jb * 16 + fg * 4];
        us4 hi4, lo4;
#pragma unroll
        for (int e = 0; e < 4; e++) {
            const float og = bf2f(ogh[e]) + bf2f(ogl[e]);
            const float sig = 1.f / (1.f + __expf(-og));
            const float ho = (acc[jj][e] - mu) * rstd * lw[e] * sig;
            unsigned short h1 = f2bf(ho);
            hi4[e] = h1;
            lo4[e] = f2bf(ho - bf2f(h1));
        }
        *(us4*)&ho_hi[hbase + jb * 16] = hi4;
        *(us4*)&ho_lo[hbase + jb * 16] = lo4;
    }
}

// ---------------------------------------------------------------------------
extern "C" void kernel_launch(void* const* d_in, const int* in_sizes, int n_in,
                              void* d_out, int out_size, void* d_ws, size_t ws_size,
                              hipStream_t stream) {
    (void)in_sizes; (void)n_in; (void)out_size; (void)ws_size;
    const float* x    = (const float*)d_in[0];
    const float* Wq   = (const float*)d_in[1];
    const float* Wk   = (const float*)d_in[2];
    const float* Wv   = (const float*)d_in[3];
    const float* Wog  = (const float*)d_in[4];
    const float* Wi   = (const float*)d_in[5];
    const float* bi   = (const float*)d_in[6];
    const float* Wf   = (const float*)d_in[7];
    const float* bfb  = (const float*)d_in[8];
    const float* lnw  = (const float*)d_in[9];
    const float* Wout = (const float*)d_in[10];

    char* p = (char*)d_ws;
    auto carve = [&](size_t bytes) -> char* {
        char* r = p;
        p += (bytes + 255) & ~(size_t)255;
        return r;
    };
    unsigned short* x_hi   = (unsigned short*)carve(4194304ull * 2);
    unsigned short* x_lo   = (unsigned short*)carve(4194304ull * 2);
    unsigned short* wc_hi  = (unsigned short*)carve(2359296ull * 2);
    unsigned short* wc_lo  = (unsigned short*)carve(2359296ull * 2);
    unsigned short* wo_hi  = (unsigned short*)carve(1048576ull * 2);
    unsigned short* wo_lo  = (unsigned short*)carve(1048576ull * 2);
    unsigned short* pr_hi  = (unsigned short*)carve(4096ull * 2304 * 2);
    unsigned short* pr_lo  = (unsigned short*)carve(4096ull * 2304 * 2);
    unsigned short* vT_hi  = (unsigned short*)carve(524288ull * 2);
    unsigned short* vT_lo  = (unsigned short*)carve(524288ull * 2);
    float* ipre    = (float*)carve(32768ull * 4);
    float* lgf_buf = (float*)carve(32768ull * 4);
    float* csum    = (float*)carve(32768ull * 4);
    float* aarr    = (float*)carve(32768ull * 4);
    float* marr    = (float*)carve(32768ull * 4);
    unsigned short* ho_hi = x_hi;   // x dead after proj GEMM
    unsigned short* ho_lo = x_lo;

    k_split_bf16<<<16384, 256, 0, stream>>>(x, x_hi, x_lo, 4194304);
    build_wcat<<<(2359296 + 255) / 256, 256, 0, stream>>>(Wq, Wk, Wv, Wog, wc_hi, wc_lo);
    k_split_bf16<<<4096, 256, 0, stream>>>(Wout, wo_hi, wo_lo, 1048576);
    gates_kernel<<<4096, 256, 0, stream>>>(x, Wi, bi, Wf, bfb, ipre, lgf_buf);
    scan_kernel<<<16, 64, 0, stream>>>(ipre, lgf_buf, csum, aarr, marr);
    gemm_bt3<<<dim3(32, 18), 256, 0, stream>>>(x_hi, x_lo, wc_hi, wc_lo, pr_hi, pr_lo, 1024, 2304, 1, 10);
    make_vt<<<128, 256, 0, stream>>>(pr_hi, pr_lo, vT_hi, vT_lo);
    attn_fused<<<1024, 256, 0, stream>>>(pr_hi, pr_lo, vT_hi, vT_lo, aarr, marr, csum, lnw, ho_hi, ho_lo);
    gemm_bt3<<<dim3(32, 8), 256, 0, stream>>>(ho_hi, ho_lo, wo_hi, wo_lo, d_out, nullptr, 1024, 1024, 0, 1000);
}

// Round 17
// 350.994 us; speedup vs baseline: 1.2140x; 1.2140x over previous
//
#include <hip/hip_runtime.h>

// ---------------------------------------------------------------------------
// mLSTM block, MI355X. B=2,S=2048,D=1024,NH=8,DH=128.
// v16: attn 512-thread blocks (8 waves = 4 q-subtiles x 2 ch-halves),
//      same 512-block grid & staging volume as v12, dbuf, 4 waves/SIMD.
//      GEMMs = v14 (og rows single-product). Numerics = v12 + LN half-combine.
// ---------------------------------------------------------------------------

typedef __bf16 bf16x8 __attribute__((ext_vector_type(8)));
typedef float f32x4 __attribute__((ext_vector_type(4)));
typedef unsigned short us8 __attribute__((ext_vector_type(8)));
typedef unsigned short us4 __attribute__((ext_vector_type(4)));

__device__ __forceinline__ unsigned short f2bf(float f) {
    unsigned int u = __builtin_bit_cast(unsigned int, f);
    unsigned int r = u + 0x7fffu + ((u >> 16) & 1u);
    return (unsigned short)(r >> 16);
}
__device__ __forceinline__ float bf2f(unsigned short h) {
    unsigned int u = ((unsigned int)h) << 16;
    return __builtin_bit_cast(float, u);
}
__device__ __forceinline__ f32x4 mfma16(bf16x8 a, bf16x8 b, f32x4 c) {
    return __builtin_amdgcn_mfma_f32_16x16x32_bf16(a, b, c, 0, 0, 0);
}

// ---------------- K0 ----------------
__global__ __launch_bounds__(256) void k_split_bf16(const float* __restrict__ in,
                                                    unsigned short* __restrict__ hi,
                                                    unsigned short* __restrict__ lo, int n) {
    int i = blockIdx.x * 256 + threadIdx.x;
    if (i < n) {
        float f = in[i];
        unsigned short h = f2bf(f);
        hi[i] = h;
        lo[i] = f2bf(f - bf2f(h));
    }
}

__global__ __launch_bounds__(256) void build_wcat(const float* __restrict__ Wq,
                                                  const float* __restrict__ Wk,
                                                  const float* __restrict__ Wv,
                                                  const float* __restrict__ Wog,
                                                  unsigned short* __restrict__ wh,
                                                  unsigned short* __restrict__ wl) {
    int idx = blockIdx.x * 256 + threadIdx.x;
    if (idx >= 2304 * 1024) return;
    int row = idx >> 10, col = idx & 1023;
    float v;
    if (row < 1024)      v = Wq[(size_t)row * 1024 + col] * 0.08838834764831845f;
    else if (row < 1152) v = Wk[(size_t)(row - 1024) * 1024 + col];
    else if (row < 1280) v = Wv[(size_t)(row - 1152) * 1024 + col];
    else                 v = Wog[(size_t)(row - 1280) * 1024 + col];
    unsigned short h = f2bf(v);
    wh[idx] = h;
    wl[idx] = f2bf(v - bf2f(h));
}

// ---------------- K1: gates ----------------
__global__ __launch_bounds__(256) void gates_kernel(const float* __restrict__ x,
                                                    const float* __restrict__ Wi,
                                                    const float* __restrict__ bi,
                                                    const float* __restrict__ Wf,
                                                    const float* __restrict__ bfb,
                                                    float* __restrict__ ipre,
                                                    float* __restrict__ lgf) {
    int bs = blockIdx.x;
    int b = bs >> 11, s = bs & 2047;
    const float* xr = x + (size_t)bs * 1024;
    int lane = threadIdx.x & 63, w = threadIdx.x >> 6;
    const float* W = (w < 2) ? Wi : Wf;
    int h0 = (w & 1) * 4;
    float dot0 = 0.f, dot1 = 0.f, dot2 = 0.f, dot3 = 0.f;
    for (int i = lane; i < 1024; i += 64) {
        float xv = xr[i];
        dot0 += xv * W[(size_t)(h0 + 0) * 1024 + i];
        dot1 += xv * W[(size_t)(h0 + 1) * 1024 + i];
        dot2 += xv * W[(size_t)(h0 + 2) * 1024 + i];
        dot3 += xv * W[(size_t)(h0 + 3) * 1024 + i];
    }
#pragma unroll
    for (int o = 32; o; o >>= 1) {
        dot0 += __shfl_xor(dot0, o);
        dot1 += __shfl_xor(dot1, o);
        dot2 += __shfl_xor(dot2, o);
        dot3 += __shfl_xor(dot3, o);
    }
    if (lane == 0) {
        float d[4] = {dot0, dot1, dot2, dot3};
#pragma unroll
        for (int j = 0; j < 4; j++) {
            int hh = h0 + j;
            if (w < 2) {
                float z = d[j] + bi[hh];
                z = 15.f * tanhf(z * (1.f / 15.f));
                ipre[((size_t)b * 8 + hh) * 2048 + s] = z;
            } else {
                float z = d[j] + bfb[hh];
                z = 15.f * tanhf(z * (1.f / 15.f));
                lgf[((size_t)b * 8 + hh) * 2048 + s] = fminf(z, 0.f) - log1pf(expf(-fabsf(z)));
            }
        }
    }
}

// ---------------- K2: scan ----------------
__global__ void scan_kernel(const float* __restrict__ ipre, const float* __restrict__ lgf,
                            float* __restrict__ csum, float* __restrict__ aarr,
                            float* __restrict__ marr) {
    int bh = blockIdx.x;
    int lane = threadIdx.x;
    const float* lf = lgf + (size_t)bh * 2048;
    const float* ip = ipre + (size_t)bh * 2048;
    float* cs = csum + (size_t)bh * 2048;
    float* aa = aarr + (size_t)bh * 2048;
    float* mm = marr + (size_t)bh * 2048;
    float carry = 0.f;
    float carrym = -1e30f;
    for (int c = 0; c < 32; c++) {
        float v = lf[c * 64 + lane];
#pragma unroll
        for (int o = 1; o < 64; o <<= 1) {
            float t = __shfl_up(v, o);
            if (lane >= o) v += t;
        }
        float cval = carry + v;
        cs[c * 64 + lane] = cval;
        float a = ip[c * 64 + lane] - cval;
        aa[c * 64 + lane] = a;
        float mv = a;
#pragma unroll
        for (int o = 1; o < 64; o <<= 1) {
            float t = __shfl_up(mv, o);
            if (lane >= o) mv = fmaxf(mv, t);
        }
        float mval = fmaxf(carrym, mv);
        mm[c * 64 + lane] = mval;
        carry = __shfl(cval, 63);
        carrym = __shfl(mval, 63);
    }
}

// ---- K3/K6: 3-product GEMM, 128x128 tile, early prefetch; og rows 1-product --
__global__ __launch_bounds__(256) void gemm_bt3(const unsigned short* __restrict__ Ah,
                                                const unsigned short* __restrict__ Al,
                                                const unsigned short* __restrict__ Bh,
                                                const unsigned short* __restrict__ Bl,
                                                void* __restrict__ Cp,
                                                unsigned short* __restrict__ Clo,
                                                int K, int ldc, int c_bf16, int og_y0) {
    __shared__ __attribute__((aligned(16))) unsigned short Ash[128 * 40];
    __shared__ __attribute__((aligned(16))) unsigned short Asl[128 * 40];
    __shared__ __attribute__((aligned(16))) unsigned short Bsh[128 * 40];
    __shared__ __attribute__((aligned(16))) unsigned short Bsl[128 * 40];
    const int tid = threadIdx.x;
    const int lane = tid & 63, wv = tid >> 6;
    const int wr = wv >> 1, wc = wv & 1;
    const int fr = lane & 15, fg = lane >> 4;
    const int srow = tid >> 1, scol = (tid & 1) * 16;
    const bool full3 = (blockIdx.y < (unsigned)og_y0);
    const size_t aoff = (size_t)(blockIdx.x * 128 + srow) * K + scol;
    const size_t boff = (size_t)(blockIdx.y * 128 + srow) * K + scol;
    f32x4 acc[4][4] = {};
    us8 avh0, avh1, avl0, avl1, bvh0, bvh1, bvl0, bvl1;
#define GLOAD(KT)                                                              \
    {                                                                          \
        avh0 = *(const us8*)(Ah + aoff + (KT));                                \
        avh1 = *(const us8*)(Ah + aoff + (KT) + 8);                            \
        avl0 = *(const us8*)(Al + aoff + (KT));                                \
        avl1 = *(const us8*)(Al + aoff + (KT) + 8);                            \
        bvh0 = *(const us8*)(Bh + boff + (KT));                                \
        bvh1 = *(const us8*)(Bh + boff + (KT) + 8);                            \
        bvl0 = *(const us8*)(Bl + boff + (KT));                                \
        bvl1 = *(const us8*)(Bl + boff + (KT) + 8);                            \
    }
    GLOAD(0);
    for (int kt = 0; kt < K; kt += 32) {
        __syncthreads();
        *(us8*)&Ash[srow * 40 + scol] = avh0;
        *(us8*)&Ash[srow * 40 + scol + 8] = avh1;
        *(us8*)&Asl[srow * 40 + scol] = avl0;
        *(us8*)&Asl[srow * 40 + scol + 8] = avl1;
        *(us8*)&Bsh[srow * 40 + scol] = bvh0;
        *(us8*)&Bsh[srow * 40 + scol + 8] = bvh1;
        *(us8*)&Bsl[srow * 40 + scol] = bvl0;
        *(us8*)&Bsl[srow * 40 + scol + 8] = bvl1;
        __syncthreads();
        if (kt + 32 < K) GLOAD(kt + 32);
        bf16x8 bfh[4], bfl[4];
#pragma unroll
        for (int j = 0; j < 4; j++) {
            bfh[j] = __builtin_bit_cast(bf16x8, *(const us8*)&Bsh[(64 * wc + 16 * j + fr) * 40 + fg * 8]);
            bfl[j] = __builtin_bit_cast(bf16x8, *(const us8*)&Bsl[(64 * wc + 16 * j + fr) * 40 + fg * 8]);
        }
        __builtin_amdgcn_s_setprio(1);
        if (full3) {
#pragma unroll
            for (int i = 0; i < 4; i++) {
                bf16x8 afh = __builtin_bit_cast(bf16x8, *(const us8*)&Ash[(64 * wr + 16 * i + fr) * 40 + fg * 8]);
                bf16x8 afl = __builtin_bit_cast(bf16x8, *(const us8*)&Asl[(64 * wr + 16 * i + fr) * 40 + fg * 8]);
#pragma unroll
                for (int j = 0; j < 4; j++) {
                    acc[i][j] = mfma16(afh, bfh[j], acc[i][j]);
                    acc[i][j] = mfma16(afh, bfl[j], acc[i][j]);
                    acc[i][j] = mfma16(afl, bfh[j], acc[i][j]);
                }
            }
        } else {
#pragma unroll
            for (int i = 0; i < 4; i++) {
                bf16x8 afh = __builtin_bit_cast(bf16x8, *(const us8*)&Ash[(64 * wr + 16 * i + fr) * 40 + fg * 8]);
#pragma unroll
                for (int j = 0; j < 4; j++)
                    acc[i][j] = mfma16(afh, bfh[j], acc[i][j]);
            }
        }
        __builtin_amdgcn_s_setprio(0);
    }
#undef GLOAD
#pragma unroll
    for (int i = 0; i < 4; i++)
#pragma unroll
        for (int j = 0; j < 4; j++)
#pragma unroll
            for (int e = 0; e < 4; e++) {
                int r = blockIdx.x * 128 + 64 * wr + 16 * i + fg * 4 + e;
                int c = blockIdx.y * 128 + 64 * wc + 16 * j + fr;
                float v = acc[i][j][e];
                if (c_bf16) {
                    unsigned short h = f2bf(v);
                    ((unsigned short*)Cp)[(size_t)r * ldc + c] = h;
                    Clo[(size_t)r * ldc + c] = f2bf(v - bf2f(h));
                } else {
                    ((float*)Cp)[(size_t)r * ldc + c] = v;
                }
            }
}

// ---------------- K4: vT via coalesced LDS-tiled transpose ----------------
__global__ __launch_bounds__(256) void make_vt(const unsigned short* __restrict__ ph,
                                               const unsigned short* __restrict__ pl,
                                               unsigned short* __restrict__ vTh,
                                               unsigned short* __restrict__ vTl) {
    __shared__ __attribute__((aligned(16))) unsigned short th[64 * 68];
    __shared__ __attribute__((aligned(16))) unsigned short tl[64 * 68];
    const int bid = blockIdx.x;
    const int st = bid & 31, ct = (bid >> 5) & 1, b = bid >> 6;
    const int tid = threadIdx.x;
    {
        const int sr = tid >> 2, cc = (tid & 3) * 16;
        const size_t rbase = (size_t)(b * 2048 + st * 64 + sr) * 2304 + 1152 + ct * 64 + cc;
        us8 a0 = *(const us8*)(ph + rbase);
        us8 a1 = *(const us8*)(ph + rbase + 8);
        us8 c0 = *(const us8*)(pl + rbase);
        us8 c1 = *(const us8*)(pl + rbase + 8);
        *(us8*)&th[sr * 68 + cc] = a0;
        *(us8*)&th[sr * 68 + cc + 8] = a1;
        *(us8*)&tl[sr * 68 + cc] = c0;
        *(us8*)&tl[sr * 68 + cc + 8] = c1;
    }
    __syncthreads();
    {
        const int cr = tid >> 2, ss = (tid & 3) * 16;
        us8 oh0, oh1, ol0, ol1;
#pragma unroll
        for (int e = 0; e < 8; e++) {
            oh0[e] = th[(ss + e) * 68 + cr];
            oh1[e] = th[(ss + 8 + e) * 68 + cr];
            ol0[e] = tl[(ss + e) * 68 + cr];
            ol1[e] = tl[(ss + 8 + e) * 68 + cr];
        }
        const size_t wbase = (size_t)b * 128 * 2048 + (size_t)(ct * 64 + cr) * 2048 + st * 64 + ss;
        *(us8*)&vTh[wbase] = oh0;
        *(us8*)&vTh[wbase + 8] = oh1;
        *(us8*)&vTl[wbase] = ol0;
        *(us8*)&vTl[wbase + 8] = ol1;
    }
}

// ---------------- K5: attn — 512 threads, 8 waves = (q-subtile, ch-half) ----
__global__ __launch_bounds__(512, 4) void attn_fused(const unsigned short* __restrict__ projh,
                                                     const unsigned short* __restrict__ projl,
                                                     const unsigned short* __restrict__ vTh,
                                                     const unsigned short* __restrict__ vTl,
                                                     const float* __restrict__ aarr,
                                                     const float* __restrict__ marr,
                                                     const float* __restrict__ csum,
                                                     const float* __restrict__ lnw,
                                                     unsigned short* __restrict__ ho_hi,
                                                     unsigned short* __restrict__ ho_lo) {
    __shared__ __attribute__((aligned(16))) unsigned short Klh[2][32 * 148];
    __shared__ __attribute__((aligned(16))) unsigned short Kll[2][32 * 148];
    __shared__ __attribute__((aligned(16))) unsigned short Vlh[2][128 * 40];
    __shared__ __attribute__((aligned(16))) unsigned short Vll[2][128 * 40];
    __shared__ float al[2][32];

    // 512 blocks; (i, i+256) -> (bh,qt),(bh,31-qt) complementary pairing
    const int idx = blockIdx.x;
    const int half = idx >> 8;
    const int pid = idx & 255;
    const int bh = pid & 15;
    const int qt0 = pid >> 4;
    const int qt = half ? (31 - qt0) : qt0;
    const int b = bh >> 3, h = bh & 7;
    const int tid = threadIdx.x, lane = tid & 63, w = tid >> 6;
    const int fr = lane & 15, fg = lane >> 4;
    const int qsub = w & 3;               // q-subtile (16 rows)
    const int jbh = w >> 2;               // PV channel half
    const int q0 = qt * 64;
    const int qg = q0 + 16 * qsub + fr;   // this lane's q row

    // Q fragments hi/lo (B-operand layout, col=fr)
    bf16x8 qfh[4], qfl[4];
    {
        const size_t qoff = (size_t)(b * 2048 + qg) * 2304 + h * 128;
#pragma unroll
        for (int ks = 0; ks < 4; ks++) {
            qfh[ks] = __builtin_bit_cast(bf16x8, *(const us8*)(projh + qoff + ks * 32 + fg * 8));
            qfl[ks] = __builtin_bit_cast(bf16x8, *(const us8*)(projl + qoff + ks * 32 + fg * 8));
        }
    }
    const float ma_q = marr[(size_t)bh * 2048 + qg];

    f32x4 acc[4] = {};
    float b_run = 0.f;

    // 512-thread staging: K 1 us8/thread, V 1 us8/thread
    const int kr = tid >> 4, kc = (tid & 15) * 8;   // K: 32 rows x 128 cols
    const int vr = tid >> 2, vc = (tid & 3) * 8;    // V^T: 128 rows x 32 cols
    const size_t kbase = (size_t)(b * 2048) * 2304 + 1024;
    const size_t vtbase = (size_t)b * 128 * 2048;

    const int nt = 2 * qt + 2;
    us8 kh0, kl0, vh0, vl0;
    float a_st;
#define LOADT(T0)                                                              \
    {                                                                          \
        const size_t ko = kbase + (size_t)((T0) + kr) * 2304 + kc;             \
        const size_t vo = vtbase + (size_t)vr * 2048 + (T0) + vc;              \
        kh0 = *(const us8*)(projh + ko);                                       \
        kl0 = *(const us8*)(projl + ko);                                       \
        vh0 = *(const us8*)(vTh + vo);                                         \
        vl0 = *(const us8*)(vTl + vo);                                         \
        a_st = (tid < 32) ? aarr[(size_t)bh * 2048 + (T0) + tid] : 0.f;        \
    }
#define STORET(BUF)                                                            \
    {                                                                          \
        *(us8*)&Klh[BUF][kr * 148 + kc] = kh0;                                 \
        *(us8*)&Kll[BUF][kr * 148 + kc] = kl0;                                 \
        *(us8*)&Vlh[BUF][vr * 40 + vc] = vh0;                                  \
        *(us8*)&Vll[BUF][vr * 40 + vc] = vl0;                                  \
        if (tid < 32) al[BUF][tid] = a_st;                                     \
    }

    LOADT(0);
    STORET(0);
    if (nt > 1) LOADT(32);
    __syncthreads();

    for (int kt = 0; kt < nt; kt++) {
        const int cur = kt & 1;
        const int t0 = kt * 32;
        if (kt + 1 < nt) {
            STORET(cur ^ 1);
            if (kt + 2 < nt) LOADT((kt + 2) * 32);
        }

        // S^T = mfma(K, Q): D[key(row), q(col)]; 3-acc split
        float dj[2][4];
#pragma unroll
        for (int j = 0; j < 2; j++) {
            f32x4 sfa = {}, sfb = {}, sfc = {};
            __builtin_amdgcn_s_setprio(1);
#pragma unroll
            for (int ks = 0; ks < 4; ks++) {
                bf16x8 kfh = __builtin_bit_cast(bf16x8, *(const us8*)&Klh[cur][(j * 16 + fr) * 148 + ks * 32 + fg * 8]);
                bf16x8 kfl = __builtin_bit_cast(bf16x8, *(const us8*)&Kll[cur][(j * 16 + fr) * 148 + ks * 32 + fg * 8]);
                sfa = mfma16(kfh, qfh[ks], sfa);
                sfb = mfma16(kfh, qfl[ks], sfb);
                sfc = mfma16(kfl, qfh[ks], sfc);
            }
            __builtin_amdgcn_s_setprio(0);
            f32x4 sf = (sfa + sfb) + sfc;
#pragma unroll
            for (int r = 0; r < 4; r++) {
                const int kloc = j * 16 + fg * 4 + r;
                const int key = t0 + kloc;
                const float atv = al[cur][kloc];
                dj[j][r] = (key <= qg) ? sf[r] * __expf(atv - ma_q) : 0.f;
            }
        }

        // b_run: sum over the 32 keys for q=fr (replicated over fg)
        {
            float ts = dj[0][0] + dj[0][1] + dj[0][2] + dj[0][3]
                     + dj[1][0] + dj[1][1] + dj[1][2] + dj[1][3];
            ts += __shfl_xor(ts, 16);
            ts += __shfl_xor(ts, 32);
            b_run += ts;
        }

        // D-frag -> B-frag relayout (in-register): p8[e] = P[q=fr][k=8g+e]
        float p8[8];
        const int srlo = 32 * ((lane >> 4) & 1) + fr;
#pragma unroll
        for (int e = 0; e < 8; e++) {
            const int sl = srlo + ((e >= 4) ? 16 : 0);
            const float v0 = __shfl(dj[0][e & 3], sl);
            const float v1 = __shfl(dj[1][e & 3], sl);
            p8[e] = (lane & 32) ? v1 : v0;
        }
        us8 phu, plu;
#pragma unroll
        for (int e = 0; e < 8; e++) {
            unsigned short hh = f2bf(p8[e]);
            phu[e] = hh;
            plu[e] = f2bf(p8[e] - bf2f(hh));
        }
        const bf16x8 pfh = __builtin_bit_cast(bf16x8, phu);
        const bf16x8 pfl = __builtin_bit_cast(bf16x8, plu);

        // PV: this wave's 4 jb (channel half jbh), V^T from LDS
        __builtin_amdgcn_s_setprio(1);
#pragma unroll
        for (int jj = 0; jj < 4; jj++) {
            const int jb = jbh * 4 + jj;
            bf16x8 vfh = __builtin_bit_cast(bf16x8, *(const us8*)&Vlh[cur][(jb * 16 + fr) * 40 + fg * 8]);
            bf16x8 vfl = __builtin_bit_cast(bf16x8, *(const us8*)&Vll[cur][(jb * 16 + fr) * 40 + fg * 8]);
            acc[jj] = mfma16(vfh, pfh, acc[jj]);
            acc[jj] = mfma16(vfh, pfl, acc[jj]);
            acc[jj] = mfma16(vfl, pfh, acc[jj]);
        }
        __builtin_amdgcn_s_setprio(0);
        __syncthreads();
    }
#undef LOADT
#undef STORET

    // finalize: n-divide (identical per ch-half wave), LN half-combine via LDS
    const float cs_q = csum[(size_t)bh * 2048 + qg];
    const float nf = __expf(-(cs_q + ma_q));
    const float n = fmaxf(fabsf(b_run), nf);
    const float inv = 1.f / (n + 1e-6f);
#pragma unroll
    for (int jj = 0; jj < 4; jj++) acc[jj] *= inv;

    float s1 = 0.f, s2 = 0.f;
#pragma unroll
    for (int jj = 0; jj < 4; jj++)
#pragma unroll
        for (int e = 0; e < 4; e++) {
            const float v = acc[jj][e];
            s1 += v;
            s2 += v * v;
        }
    s1 += __shfl_xor(s1, 16);
    s1 += __shfl_xor(s1, 32);
    s2 += __shfl_xor(s2, 16);
    s2 += __shfl_xor(s2, 32);
    // scratch aliased onto Klh (all LDS reads done; loop ended with barrier)
    float* lncp = (float*)&Klh[0][0];     // [qsub][fr][jbh][{s1,s2}] = 256 floats
    if (fg == 0) {
        lncp[((qsub * 16 + fr) * 2 + jbh) * 2 + 0] = s1;
        lncp[((qsub * 16 + fr) * 2 + jbh) * 2 + 1] = s2;
    }
    __syncthreads();
    const float s1t = lncp[((qsub * 16 + fr) * 2 + 0) * 2 + 0] + lncp[((qsub * 16 + fr) * 2 + 1) * 2 + 0];
    const float s2t = lncp[((qsub * 16 + fr) * 2 + 0) * 2 + 1] + lncp[((qsub * 16 + fr) * 2 + 1) * 2 + 1];
    const float mu = s1t * (1.f / 128.f);
    const float var = fmaxf(s2t * (1.f / 128.f) - mu * mu, 0.f);
    const float rstd = rsqrtf(var + 1e-6f);

    const size_t obase = (size_t)(b * 2048 + qg) * 2304 + 1280 + h * 128 + fg * 4;
    const size_t hbase = (size_t)(b * 2048 + qg) * 1024 + h * 128 + fg * 4;
#pragma unroll
    for (int jj = 0; jj < 4; jj++) {
        const int jb = jbh * 4 + jj;
        us4 ogh = *(const us4*)(projh + obase + jb * 16);
        us4 ogl = *(const us4*)(projl + obase + jb * 16);
        f32x4 lw = *(const f32x4*)&lnw[h * 128 + jb * 16 + fg * 4];
        us4 hi4, lo4;
#pragma unroll
        for (int e = 0; e < 4; e++) {
            const float og = bf2f(ogh[e]) + bf2f(ogl[e]);
            const float sig = 1.f / (1.f + __expf(-og));
            const float ho = (acc[jj][e] - mu) * rstd * lw[e] * sig;
            unsigned short h1 = f2bf(ho);
            hi4[e] = h1;
            lo4[e] = f2bf(ho - bf2f(h1));
        }
        *(us4*)&ho_hi[hbase + jb * 16] = hi4;
        *(us4*)&ho_lo[hbase + jb * 16] = lo4;
    }
}

// ---------------------------------------------------------------------------
extern "C" void kernel_launch(void* const* d_in, const int* in_sizes, int n_in,
                              void* d_out, int out_size, void* d_ws, size_t ws_size,
                              hipStream_t stream) {
    (void)in_sizes; (void)n_in; (void)out_size; (void)ws_size;
    const float* x    = (const float*)d_in[0];
    const float* Wq   = (const float*)d_in[1];
    const float* Wk   = (const float*)d_in[2];
    const float* Wv   = (const float*)d_in[3];
    const float* Wog  = (const float*)d_in[4];
    const float* Wi   = (const float*)d_in[5];
    const float* bi   = (const float*)d_in[6];
    const float* Wf   = (const float*)d_in[7];
    const float* bfb  = (const float*)d_in[8];
    const float* lnw  = (const float*)d_in[9];
    const float* Wout = (const float*)d_in[10];

    char* p = (char*)d_ws;
    auto carve = [&](size_t bytes) -> char* {
        char* r = p;
        p += (bytes + 255) & ~(size_t)255;
        return r;
    };
    unsigned short* x_hi   = (unsigned short*)carve(4194304ull * 2);
    unsigned short* x_lo   = (unsigned short*)carve(4194304ull * 2);
    unsigned short* wc_hi  = (unsigned short*)carve(2359296ull * 2);
    unsigned short* wc_lo  = (unsigned short*)carve(2359296ull * 2);
    unsigned short* wo_hi  = (unsigned short*)carve(1048576ull * 2);
    unsigned short* wo_lo  = (unsigned short*)carve(1048576ull * 2);
    unsigned short* pr_hi  = (unsigned short*)carve(4096ull * 2304 * 2);
    unsigned short* pr_lo  = (unsigned short*)carve(4096ull * 2304 * 2);
    unsigned short* vT_hi  = (unsigned short*)carve(524288ull * 2);
    unsigned short* vT_lo  = (unsigned short*)carve(524288ull * 2);
    float* ipre    = (float*)carve(32768ull * 4);
    float* lgf_buf = (float*)carve(32768ull * 4);
    float* csum    = (float*)carve(32768ull * 4);
    float* aarr    = (float*)carve(32768ull * 4);
    float* marr    = (float*)carve(32768ull * 4);
    unsigned short* ho_hi = x_hi;   // x dead after proj GEMM
    unsigned short* ho_lo = x_lo;

    k_split_bf16<<<16384, 256, 0, stream>>>(x, x_hi, x_lo, 4194304);
    build_wcat<<<(2359296 + 255) / 256, 256, 0, stream>>>(Wq, Wk, Wv, Wog, wc_hi, wc_lo);
    k_split_bf16<<<4096, 256, 0, stream>>>(Wout, wo_hi, wo_lo, 1048576);
    gates_kernel<<<4096, 256, 0, stream>>>(x, Wi, bi, Wf, bfb, ipre, lgf_buf);
    scan_kernel<<<16, 64, 0, stream>>>(ipre, lgf_buf, csum, aarr, marr);
    gemm_bt3<<<dim3(32, 18), 256, 0, stream>>>(x_hi, x_lo, wc_hi, wc_lo, pr_hi, pr_lo, 1024, 2304, 1, 10);
    make_vt<<<128, 256, 0, stream>>>(pr_hi, pr_lo, vT_hi, vT_lo);
    attn_fused<<<512, 512, 0, stream>>>(pr_hi, pr_lo, vT_hi, vT_lo, aarr, marr, csum, lnw, ho_hi, ho_lo);
    gemm_bt3<<<dim3(32, 8), 256, 0, stream>>>(ho_hi, ho_lo, wo_hi, wo_lo, d_out, nullptr, 1024, 1024, 0, 1000);
}

// Round 18
// 339.465 us; speedup vs baseline: 1.2553x; 1.0340x over previous
//
#include <hip/hip_runtime.h>

// ---------------------------------------------------------------------------
// mLSTM block, MI355X. B=2,S=2048,D=1024,NH=8,DH=128.
// v17 = R13 best config (v12 attn dbuf, no-prefetch GEMM, coalesced make_vt)
//       + og-rows single-product in proj GEMM (no register-pressure cost).
// ---------------------------------------------------------------------------

typedef __bf16 bf16x8 __attribute__((ext_vector_type(8)));
typedef float f32x4 __attribute__((ext_vector_type(4)));
typedef unsigned short us8 __attribute__((ext_vector_type(8)));
typedef unsigned short us4 __attribute__((ext_vector_type(4)));

__device__ __forceinline__ unsigned short f2bf(float f) {
    unsigned int u = __builtin_bit_cast(unsigned int, f);
    unsigned int r = u + 0x7fffu + ((u >> 16) & 1u);
    return (unsigned short)(r >> 16);
}
__device__ __forceinline__ float bf2f(unsigned short h) {
    unsigned int u = ((unsigned int)h) << 16;
    return __builtin_bit_cast(float, u);
}
__device__ __forceinline__ f32x4 mfma16(bf16x8 a, bf16x8 b, f32x4 c) {
    return __builtin_amdgcn_mfma_f32_16x16x32_bf16(a, b, c, 0, 0, 0);
}

// ---------------- K0 ----------------
__global__ __launch_bounds__(256) void k_split_bf16(const float* __restrict__ in,
                                                    unsigned short* __restrict__ hi,
                                                    unsigned short* __restrict__ lo, int n) {
    int i = blockIdx.x * 256 + threadIdx.x;
    if (i < n) {
        float f = in[i];
        unsigned short h = f2bf(f);
        hi[i] = h;
        lo[i] = f2bf(f - bf2f(h));
    }
}

__global__ __launch_bounds__(256) void build_wcat(const float* __restrict__ Wq,
                                                  const float* __restrict__ Wk,
                                                  const float* __restrict__ Wv,
                                                  const float* __restrict__ Wog,
                                                  unsigned short* __restrict__ wh,
                                                  unsigned short* __restrict__ wl) {
    int idx = blockIdx.x * 256 + threadIdx.x;
    if (idx >= 2304 * 1024) return;
    int row = idx >> 10, col = idx & 1023;
    float v;
    if (row < 1024)      v = Wq[(size_t)row * 1024 + col] * 0.08838834764831845f;
    else if (row < 1152) v = Wk[(size_t)(row - 1024) * 1024 + col];
    else if (row < 1280) v = Wv[(size_t)(row - 1152) * 1024 + col];
    else                 v = Wog[(size_t)(row - 1280) * 1024 + col];
    unsigned short h = f2bf(v);
    wh[idx] = h;
    wl[idx] = f2bf(v - bf2f(h));
}

// ---------------- K1: gates ----------------
__global__ __launch_bounds__(256) void gates_kernel(const float* __restrict__ x,
                                                    const float* __restrict__ Wi,
                                                    const float* __restrict__ bi,
                                                    const float* __restrict__ Wf,
                                                    const float* __restrict__ bfb,
                                                    float* __restrict__ ipre,
                                                    float* __restrict__ lgf) {
    int bs = blockIdx.x;
    int b = bs >> 11, s = bs & 2047;
    const float* xr = x + (size_t)bs * 1024;
    int lane = threadIdx.x & 63, w = threadIdx.x >> 6;
    const float* W = (w < 2) ? Wi : Wf;
    int h0 = (w & 1) * 4;
    float dot0 = 0.f, dot1 = 0.f, dot2 = 0.f, dot3 = 0.f;
    for (int i = lane; i < 1024; i += 64) {
        float xv = xr[i];
        dot0 += xv * W[(size_t)(h0 + 0) * 1024 + i];
        dot1 += xv * W[(size_t)(h0 + 1) * 1024 + i];
        dot2 += xv * W[(size_t)(h0 + 2) * 1024 + i];
        dot3 += xv * W[(size_t)(h0 + 3) * 1024 + i];
    }
#pragma unroll
    for (int o = 32; o; o >>= 1) {
        dot0 += __shfl_xor(dot0, o);
        dot1 += __shfl_xor(dot1, o);
        dot2 += __shfl_xor(dot2, o);
        dot3 += __shfl_xor(dot3, o);
    }
    if (lane == 0) {
        float d[4] = {dot0, dot1, dot2, dot3};
#pragma unroll
        for (int j = 0; j < 4; j++) {
            int hh = h0 + j;
            if (w < 2) {
                float z = d[j] + bi[hh];
                z = 15.f * tanhf(z * (1.f / 15.f));
                ipre[((size_t)b * 8 + hh) * 2048 + s] = z;
            } else {
                float z = d[j] + bfb[hh];
                z = 15.f * tanhf(z * (1.f / 15.f));
                lgf[((size_t)b * 8 + hh) * 2048 + s] = fminf(z, 0.f) - log1pf(expf(-fabsf(z)));
            }
        }
    }
}

// ---------------- K2: scan ----------------
__global__ void scan_kernel(const float* __restrict__ ipre, const float* __restrict__ lgf,
                            float* __restrict__ csum, float* __restrict__ aarr,
                            float* __restrict__ marr) {
    int bh = blockIdx.x;
    int lane = threadIdx.x;
    const float* lf = lgf + (size_t)bh * 2048;
    const float* ip = ipre + (size_t)bh * 2048;
    float* cs = csum + (size_t)bh * 2048;
    float* aa = aarr + (size_t)bh * 2048;
    float* mm = marr + (size_t)bh * 2048;
    float carry = 0.f;
    float carrym = -1e30f;
    for (int c = 0; c < 32; c++) {
        float v = lf[c * 64 + lane];
#pragma unroll
        for (int o = 1; o < 64; o <<= 1) {
            float t = __shfl_up(v, o);
            if (lane >= o) v += t;
        }
        float cval = carry + v;
        cs[c * 64 + lane] = cval;
        float a = ip[c * 64 + lane] - cval;
        aa[c * 64 + lane] = a;
        float mv = a;
#pragma unroll
        for (int o = 1; o < 64; o <<= 1) {
            float t = __shfl_up(mv, o);
            if (lane >= o) mv = fmaxf(mv, t);
        }
        float mval = fmaxf(carrym, mv);
        mm[c * 64 + lane] = mval;
        carry = __shfl(cval, 63);
        carrym = __shfl(mval, 63);
    }
}

// ---- K3/K6: 3-product GEMM, 128x128 tile; og rows (blockIdx.y>=og_y0) 1-product
__global__ __launch_bounds__(256) void gemm_bt3(const unsigned short* __restrict__ Ah,
                                                const unsigned short* __restrict__ Al,
                                                const unsigned short* __restrict__ Bh,
                                                const unsigned short* __restrict__ Bl,
                                                void* __restrict__ Cp,
                                                unsigned short* __restrict__ Clo,
                                                int K, int ldc, int c_bf16, int og_y0) {
    __shared__ __attribute__((aligned(16))) unsigned short Ash[128 * 40];
    __shared__ __attribute__((aligned(16))) unsigned short Asl[128 * 40];
    __shared__ __attribute__((aligned(16))) unsigned short Bsh[128 * 40];
    __shared__ __attribute__((aligned(16))) unsigned short Bsl[128 * 40];
    const int tid = threadIdx.x;
    const int lane = tid & 63, wv = tid >> 6;
    const int wr = wv >> 1, wc = wv & 1;
    const int fr = lane & 15, fg = lane >> 4;
    const int srow = tid >> 1, scol = (tid & 1) * 16;
    const bool full3 = (blockIdx.y < (unsigned)og_y0);
    const size_t aoff = (size_t)(blockIdx.x * 128 + srow) * K + scol;
    const size_t boff = (size_t)(blockIdx.y * 128 + srow) * K + scol;
    f32x4 acc[4][4] = {};
    for (int kt = 0; kt < K; kt += 32) {
        us8 avh0 = *(const us8*)(Ah + aoff + kt);
        us8 avh1 = *(const us8*)(Ah + aoff + kt + 8);
        us8 avl0 = *(const us8*)(Al + aoff + kt);
        us8 avl1 = *(const us8*)(Al + aoff + kt + 8);
        us8 bvh0 = *(const us8*)(Bh + boff + kt);
        us8 bvh1 = *(const us8*)(Bh + boff + kt + 8);
        us8 bvl0 = *(const us8*)(Bl + boff + kt);
        us8 bvl1 = *(const us8*)(Bl + boff + kt + 8);
        __syncthreads();
        *(us8*)&Ash[srow * 40 + scol] = avh0;
        *(us8*)&Ash[srow * 40 + scol + 8] = avh1;
        *(us8*)&Asl[srow * 40 + scol] = avl0;
        *(us8*)&Asl[srow * 40 + scol + 8] = avl1;
        *(us8*)&Bsh[srow * 40 + scol] = bvh0;
        *(us8*)&Bsh[srow * 40 + scol + 8] = bvh1;
        *(us8*)&Bsl[srow * 40 + scol] = bvl0;
        *(us8*)&Bsl[srow * 40 + scol + 8] = bvl1;
        __syncthreads();
        bf16x8 bfh[4], bfl[4];
#pragma unroll
        for (int j = 0; j < 4; j++) {
            bfh[j] = __builtin_bit_cast(bf16x8, *(const us8*)&Bsh[(64 * wc + 16 * j + fr) * 40 + fg * 8]);
            bfl[j] = __builtin_bit_cast(bf16x8, *(const us8*)&Bsl[(64 * wc + 16 * j + fr) * 40 + fg * 8]);
        }
        __builtin_amdgcn_s_setprio(1);
        if (full3) {
#pragma unroll
            for (int i = 0; i < 4; i++) {
                bf16x8 afh = __builtin_bit_cast(bf16x8, *(const us8*)&Ash[(64 * wr + 16 * i + fr) * 40 + fg * 8]);
                bf16x8 afl = __builtin_bit_cast(bf16x8, *(const us8*)&Asl[(64 * wr + 16 * i + fr) * 40 + fg * 8]);
#pragma unroll
                for (int j = 0; j < 4; j++) {
                    acc[i][j] = mfma16(afh, bfh[j], acc[i][j]);
                    acc[i][j] = mfma16(afh, bfl[j], acc[i][j]);
                    acc[i][j] = mfma16(afl, bfh[j], acc[i][j]);
                }
            }
        } else {
#pragma unroll
            for (int i = 0; i < 4; i++) {
                bf16x8 afh = __builtin_bit_cast(bf16x8, *(const us8*)&Ash[(64 * wr + 16 * i + fr) * 40 + fg * 8]);
#pragma unroll
                for (int j = 0; j < 4; j++)
                    acc[i][j] = mfma16(afh, bfh[j], acc[i][j]);
            }
        }
        __builtin_amdgcn_s_setprio(0);
    }
#pragma unroll
    for (int i = 0; i < 4; i++)
#pragma unroll
        for (int j = 0; j < 4; j++)
#pragma unroll
            for (int e = 0; e < 4; e++) {
                int r = blockIdx.x * 128 + 64 * wr + 16 * i + fg * 4 + e;
                int c = blockIdx.y * 128 + 64 * wc + 16 * j + fr;
                float v = acc[i][j][e];
                if (c_bf16) {
                    unsigned short h = f2bf(v);
                    ((unsigned short*)Cp)[(size_t)r * ldc + c] = h;
                    Clo[(size_t)r * ldc + c] = f2bf(v - bf2f(h));
                } else {
                    ((float*)Cp)[(size_t)r * ldc + c] = v;
                }
            }
}

// ---------------- K4: vT via coalesced LDS-tiled transpose ----------------
__global__ __launch_bounds__(256) void make_vt(const unsigned short* __restrict__ ph,
                                               const unsigned short* __restrict__ pl,
                                               unsigned short* __restrict__ vTh,
                                               unsigned short* __restrict__ vTl) {
    __shared__ __attribute__((aligned(16))) unsigned short th[64 * 68];
    __shared__ __attribute__((aligned(16))) unsigned short tl[64 * 68];
    const int bid = blockIdx.x;
    const int st = bid & 31, ct = (bid >> 5) & 1, b = bid >> 6;
    const int tid = threadIdx.x;
    {
        const int sr = tid >> 2, cc = (tid & 3) * 16;
        const size_t rbase = (size_t)(b * 2048 + st * 64 + sr) * 2304 + 1152 + ct * 64 + cc;
        us8 a0 = *(const us8*)(ph + rbase);
        us8 a1 = *(const us8*)(ph + rbase + 8);
        us8 c0 = *(const us8*)(pl + rbase);
        us8 c1 = *(const us8*)(pl + rbase + 8);
        *(us8*)&th[sr * 68 + cc] = a0;
        *(us8*)&th[sr * 68 + cc + 8] = a1;
        *(us8*)&tl[sr * 68 + cc] = c0;
        *(us8*)&tl[sr * 68 + cc + 8] = c1;
    }
    __syncthreads();
    {
        const int cr = tid >> 2, ss = (tid & 3) * 16;
        us8 oh0, oh1, ol0, ol1;
#pragma unroll
        for (int e = 0; e < 8; e++) {
            oh0[e] = th[(ss + e) * 68 + cr];
            oh1[e] = th[(ss + 8 + e) * 68 + cr];
            ol0[e] = tl[(ss + e) * 68 + cr];
            ol1[e] = tl[(ss + 8 + e) * 68 + cr];
        }
        const size_t wbase = (size_t)b * 128 * 2048 + (size_t)(ct * 64 + cr) * 2048 + st * 64 + ss;
        *(us8*)&vTh[wbase] = oh0;
        *(us8*)&vTh[wbase + 8] = oh1;
        *(us8*)&vTl[wbase] = ol0;
        *(us8*)&vTl[wbase + 8] = ol1;
    }
}

// ---------------- K5: fused attn — v12 verbatim (dbuf, 3-acc QK, reg-P) -----
__global__ __launch_bounds__(256, 2) void attn_fused(const unsigned short* __restrict__ projh,
                                                     const unsigned short* __restrict__ projl,
                                                     const unsigned short* __restrict__ vTh,
                                                     const unsigned short* __restrict__ vTl,
                                                     const float* __restrict__ aarr,
                                                     const float* __restrict__ marr,
                                                     const float* __restrict__ csum,
                                                     const float* __restrict__ lnw,
                                                     unsigned short* __restrict__ ho_hi,
                                                     unsigned short* __restrict__ ho_lo) {
    __shared__ __attribute__((aligned(16))) unsigned short Klh[2][32 * 148];
    __shared__ __attribute__((aligned(16))) unsigned short Kll[2][32 * 148];
    __shared__ __attribute__((aligned(16))) unsigned short Vlh[2][128 * 40];
    __shared__ __attribute__((aligned(16))) unsigned short Vll[2][128 * 40];
    __shared__ float al[2][32];

    const int idx = blockIdx.x;
    const int half = idx >> 8;
    const int pid = idx & 255;
    const int bh = pid & 15;
    const int qt0 = pid >> 4;
    const int qt = half ? (31 - qt0) : qt0;
    const int b = bh >> 3, h = bh & 7;
    const int tid = threadIdx.x, lane = tid & 63, w = tid >> 6;
    const int fr = lane & 15, fg = lane >> 4;
    const int q0 = qt * 64;
    const int qg = q0 + 16 * w + fr;

    bf16x8 qfh[4], qfl[4];
    {
        const size_t qoff = (size_t)(b * 2048 + qg) * 2304 + h * 128;
#pragma unroll
        for (int ks = 0; ks < 4; ks++) {
            qfh[ks] = __builtin_bit_cast(bf16x8, *(const us8*)(projh + qoff + ks * 32 + fg * 8));
            qfl[ks] = __builtin_bit_cast(bf16x8, *(const us8*)(projl + qoff + ks * 32 + fg * 8));
        }
    }
    const float ma_q = marr[(size_t)bh * 2048 + qg];

    f32x4 acc[8] = {};
    float b_run = 0.f;

    const int kr = tid >> 3, kc = (tid & 7) * 16;
    const int vr = tid >> 1, vc = (tid & 1) * 16;
    const size_t kbase = (size_t)(b * 2048) * 2304 + 1024;
    const size_t vtbase = (size_t)b * 128 * 2048;

    const int nt = 2 * qt + 2;
    us8 kh0, kh1, kl0, kl1, vh0, vh1, vl0, vl1;
    float a_st;
#define LOADT(T0)                                                              \
    {                                                                          \
        const size_t ko = kbase + (size_t)((T0) + kr) * 2304 + kc;             \
        const size_t vo = vtbase + (size_t)vr * 2048 + (T0) + vc;              \
        kh0 = *(const us8*)(projh + ko);                                       \
        kh1 = *(const us8*)(projh + ko + 8);                                   \
        kl0 = *(const us8*)(projl + ko);                                       \
        kl1 = *(const us8*)(projl + ko + 8);                                   \
        vh0 = *(const us8*)(vTh + vo);                                         \
        vh1 = *(const us8*)(vTh + vo + 8);                                     \
        vl0 = *(const us8*)(vTl + vo);                                         \
        vl1 = *(const us8*)(vTl + vo + 8);                                     \
        a_st = (tid < 32) ? aarr[(size_t)bh * 2048 + (T0) + tid] : 0.f;        \
    }
#define STORET(BUF)                                                            \
    {                                                                          \
        *(us8*)&Klh[BUF][kr * 148 + kc] = kh0;                                 \
        *(us8*)&Klh[BUF][kr * 148 + kc + 8] = kh1;                             \
        *(us8*)&Kll[BUF][kr * 148 + kc] = kl0;                                 \
        *(us8*)&Kll[BUF][kr * 148 + kc + 8] = kl1;                             \
        *(us8*)&Vlh[BUF][vr * 40 + vc] = vh0;                                  \
        *(us8*)&Vlh[BUF][vr * 40 + vc + 8] = vh1;                              \
        *(us8*)&Vll[BUF][vr * 40 + vc] = vl0;                                  \
        *(us8*)&Vll[BUF][vr * 40 + vc + 8] = vl1;                              \
        if (tid < 32) al[BUF][tid] = a_st;                                     \
    }

    LOADT(0);
    STORET(0);
    if (nt > 1) LOADT(32);
    __syncthreads();

    for (int kt = 0; kt < nt; kt++) {
        const int cur = kt & 1;
        const int t0 = kt * 32;
        if (kt + 1 < nt) {
            STORET(cur ^ 1);
            if (kt + 2 < nt) LOADT((kt + 2) * 32);
        }

        float dj[2][4];
#pragma unroll
        for (int j = 0; j < 2; j++) {
            f32x4 sfa = {}, sfb = {}, sfc = {};
            __builtin_amdgcn_s_setprio(1);
#pragma unroll
            for (int ks = 0; ks < 4; ks++) {
                bf16x8 kfh = __builtin_bit_cast(bf16x8, *(const us8*)&Klh[cur][(j * 16 + fr) * 148 + ks * 32 + fg * 8]);
                bf16x8 kfl = __builtin_bit_cast(bf16x8, *(const us8*)&Kll[cur][(j * 16 + fr) * 148 + ks * 32 + fg * 8]);
                sfa = mfma16(kfh, qfh[ks], sfa);
                sfb = mfma16(kfh, qfl[ks], sfb);
                sfc = mfma16(kfl, qfh[ks], sfc);
            }
            __builtin_amdgcn_s_setprio(0);
            f32x4 sf = (sfa + sfb) + sfc;
#pragma unroll
            for (int r = 0; r < 4; r++) {
                const int kloc = j * 16 + fg * 4 + r;
                const int key = t0 + kloc;
                const float atv = al[cur][kloc];
                dj[j][r] = (key <= qg) ? sf[r] * __expf(atv - ma_q) : 0.f;
            }
        }

        {
            float ts = dj[0][0] + dj[0][1] + dj[0][2] + dj[0][3]
                     + dj[1][0] + dj[1][1] + dj[1][2] + dj[1][3];
            ts += __shfl_xor(ts, 16);
            ts += __shfl_xor(ts, 32);
            b_run += ts;
        }

        float p8[8];
        const int srlo = 32 * ((lane >> 4) & 1) + fr;
#pragma unroll
        for (int e = 0; e < 8; e++) {
            const int sl = srlo + ((e >= 4) ? 16 : 0);
            const float v0 = __shfl(dj[0][e & 3], sl);
            const float v1 = __shfl(dj[1][e & 3], sl);
            p8[e] = (lane & 32) ? v1 : v0;
        }
        us8 phu, plu;
#pragma unroll
        for (int e = 0; e < 8; e++) {
            unsigned short hh = f2bf(p8[e]);
            phu[e] = hh;
            plu[e] = f2bf(p8[e] - bf2f(hh));
        }
        const bf16x8 pfh = __builtin_bit_cast(bf16x8, phu);
        const bf16x8 pfl = __builtin_bit_cast(bf16x8, plu);

        __builtin_amdgcn_s_setprio(1);
#pragma unroll
        for (int jb = 0; jb < 8; jb++) {
            bf16x8 vfh = __builtin_bit_cast(bf16x8, *(const us8*)&Vlh[cur][(jb * 16 + fr) * 40 + fg * 8]);
            bf16x8 vfl = __builtin_bit_cast(bf16x8, *(const us8*)&Vll[cur][(jb * 16 + fr) * 40 + fg * 8]);
            acc[jb] = mfma16(vfh, pfh, acc[jb]);
            acc[jb] = mfma16(vfh, pfl, acc[jb]);
            acc[jb] = mfma16(vfl, pfh, acc[jb]);
        }
        __builtin_amdgcn_s_setprio(0);
        __syncthreads();
    }
#undef LOADT
#undef STORET

    const float cs_q = csum[(size_t)bh * 2048 + qg];
    const float nf = __expf(-(cs_q + ma_q));
    const float n = fmaxf(fabsf(b_run), nf);
    const float inv = 1.f / (n + 1e-6f);
#pragma unroll
    for (int jb = 0; jb < 8; jb++) acc[jb] *= inv;

    float s1 = 0.f;
#pragma unroll
    for (int jb = 0; jb < 8; jb++) s1 += acc[jb][0] + acc[jb][1] + acc[jb][2] + acc[jb][3];
    s1 += __shfl_xor(s1, 16);
    s1 += __shfl_xor(s1, 32);
    const float mu = s1 * (1.f / 128.f);
    float vv = 0.f;
#pragma unroll
    for (int jb = 0; jb < 8; jb++)
#pragma unroll
        for (int e = 0; e < 4; e++) {
            float d = acc[jb][e] - mu;
            vv += d * d;
        }
    vv += __shfl_xor(vv, 16);
    vv += __shfl_xor(vv, 32);
    const float rstd = rsqrtf(vv * (1.f / 128.f) + 1e-6f);

    const size_t obase = (size_t)(b * 2048 + qg) * 2304 + 1280 + h * 128 + fg * 4;
    const size_t hbase = (size_t)(b * 2048 + qg) * 1024 + h * 128 + fg * 4;
#pragma unroll
    for (int jb = 0; jb < 8; jb++) {
        us4 ogh = *(const us4*)(projh + obase + jb * 16);
        us4 ogl = *(const us4*)(projl + obase + jb * 16);
        f32x4 lw = *(const f32x4*)&lnw[h * 128 + jb * 16 + fg * 4];
        us4 hi4, lo4;
#pragma unroll
        for (int e = 0; e < 4; e++) {
            const float og = bf2f(ogh[e]) + bf2f(ogl[e]);
            const float sig = 1.f / (1.f + __expf(-og));
            const float ho = (acc[jb][e] - mu) * rstd * lw[e] * sig;
            unsigned short h1 = f2bf(ho);
            hi4[e] = h1;
            lo4[e] = f2bf(ho - bf2f(h1));
        }
        *(us4*)&ho_hi[hbase + jb * 16] = hi4;
        *(us4*)&ho_lo[hbase + jb * 16] = lo4;
    }
}

// ---------------------------------------------------------------------------
extern "C" void kernel_launch(void* const* d_in, const int* in_sizes, int n_in,
                              void* d_out, int out_size, void* d_ws, size_t ws_size,
                              hipStream_t stream) {
    (void)in_sizes; (void)n_in; (void)out_size; (void)ws_size;
    const float* x    = (const float*)d_in[0];
    const float* Wq   = (const float*)d_in[1];
    const float* Wk   = (const float*)d_in[2];
    const float* Wv   = (const float*)d_in[3];
    const float* Wog  = (const float*)d_in[4];
    const float* Wi   = (const float*)d_in[5];
    const float* bi   = (const float*)d_in[6];
    const float* Wf   = (const float*)d_in[7];
    const float* bfb  = (const float*)d_in[8];
    const float* lnw  = (const float*)d_in[9];
    const float* Wout = (const float*)d_in[10];

    char* p = (char*)d_ws;
    auto carve = [&](size_t bytes) -> char* {
        char* r = p;
        p += (bytes + 255) & ~(size_t)255;
        return r;
    };
    unsigned short* x_hi   = (unsigned short*)carve(4194304ull * 2);
    unsigned short* x_lo   = (unsigned short*)carve(4194304ull * 2);
    unsigned short* wc_hi  = (unsigned short*)carve(2359296ull * 2);
    unsigned short* wc_lo  = (unsigned short*)carve(2359296ull * 2);
    unsigned short* wo_hi  = (unsigned short*)carve(1048576ull * 2);
    unsigned short* wo_lo  = (unsigned short*)carve(1048576ull * 2);
    unsigned short* pr_hi  = (unsigned short*)carve(4096ull * 2304 * 2);
    unsigned short* pr_lo  = (unsigned short*)carve(4096ull * 2304 * 2);
    unsigned short* vT_hi  = (unsigned short*)carve(524288ull * 2);
    unsigned short* vT_lo  = (unsigned short*)carve(524288ull * 2);
    float* ipre    = (float*)carve(32768ull * 4);
    float* lgf_buf = (float*)carve(32768ull * 4);
    float* csum    = (float*)carve(32768ull * 4);
    float* aarr    = (float*)carve(32768ull * 4);
    float* marr    = (float*)carve(32768ull * 4);
    unsigned short* ho_hi = x_hi;   // x dead after proj GEMM
    unsigned short* ho_lo = x_lo;

    k_split_bf16<<<16384, 256, 0, stream>>>(x, x_hi, x_lo, 4194304);
    build_wcat<<<(2359296 + 255) / 256, 256, 0, stream>>>(Wq, Wk, Wv, Wog, wc_hi, wc_lo);
    k_split_bf16<<<4096, 256, 0, stream>>>(Wout, wo_hi, wo_lo, 1048576);
    gates_kernel<<<4096, 256, 0, stream>>>(x, Wi, bi, Wf, bfb, ipre, lgf_buf);
    scan_kernel<<<16, 64, 0, stream>>>(ipre, lgf_buf, csum, aarr, marr);
    gemm_bt3<<<dim3(32, 18), 256, 0, stream>>>(x_hi, x_lo, wc_hi, wc_lo, pr_hi, pr_lo, 1024, 2304, 1, 10);
    make_vt<<<128, 256, 0, stream>>>(pr_hi, pr_lo, vT_hi, vT_lo);
    attn_fused<<<512, 256, 0, stream>>>(pr_hi, pr_lo, vT_hi, vT_lo, aarr, marr, csum, lnw, ho_hi, ho_lo);
    gemm_bt3<<<dim3(32, 8), 256, 0, stream>>>(ho_hi, ho_lo, wo_hi, wo_lo, d_out, nullptr, 1024, 1024, 0, 1000);
}

// Round 19
// 330.693 us; speedup vs baseline: 1.2886x; 1.0265x over previous
//
#include <hip/hip_runtime.h>

// ---------------------------------------------------------------------------
// mLSTM block, MI355X. B=2,S=2048,D=1024,NH=8,DH=128.
// v18 = v17 + attn K-loop unrolled x2 over the dbuf pair: QK of two tiles
//       interleaved (6 independent MFMA chains), PV_A overlaps relayout_B.
//       Bitwise-identical numerics to v12 (absmax 0.015625).
// ---------------------------------------------------------------------------

typedef __bf16 bf16x8 __attribute__((ext_vector_type(8)));
typedef float f32x4 __attribute__((ext_vector_type(4)));
typedef unsigned short us8 __attribute__((ext_vector_type(8)));
typedef unsigned short us4 __attribute__((ext_vector_type(4)));

__device__ __forceinline__ unsigned short f2bf(float f) {
    unsigned int u = __builtin_bit_cast(unsigned int, f);
    unsigned int r = u + 0x7fffu + ((u >> 16) & 1u);
    return (unsigned short)(r >> 16);
}
__device__ __forceinline__ float bf2f(unsigned short h) {
    unsigned int u = ((unsigned int)h) << 16;
    return __builtin_bit_cast(float, u);
}
__device__ __forceinline__ f32x4 mfma16(bf16x8 a, bf16x8 b, f32x4 c) {
    return __builtin_amdgcn_mfma_f32_16x16x32_bf16(a, b, c, 0, 0, 0);
}

// ---------------- K0 ----------------
__global__ __launch_bounds__(256) void k_split_bf16(const float* __restrict__ in,
                                                    unsigned short* __restrict__ hi,
                                                    unsigned short* __restrict__ lo, int n) {
    int i = blockIdx.x * 256 + threadIdx.x;
    if (i < n) {
        float f = in[i];
        unsigned short h = f2bf(f);
        hi[i] = h;
        lo[i] = f2bf(f - bf2f(h));
    }
}

__global__ __launch_bounds__(256) void build_wcat(const float* __restrict__ Wq,
                                                  const float* __restrict__ Wk,
                                                  const float* __restrict__ Wv,
                                                  const float* __restrict__ Wog,
                                                  unsigned short* __restrict__ wh,
                                                  unsigned short* __restrict__ wl) {
    int idx = blockIdx.x * 256 + threadIdx.x;
    if (idx >= 2304 * 1024) return;
    int row = idx >> 10, col = idx & 1023;
    float v;
    if (row < 1024)      v = Wq[(size_t)row * 1024 + col] * 0.08838834764831845f;
    else if (row < 1152) v = Wk[(size_t)(row - 1024) * 1024 + col];
    else if (row < 1280) v = Wv[(size_t)(row - 1152) * 1024 + col];
    else                 v = Wog[(size_t)(row - 1280) * 1024 + col];
    unsigned short h = f2bf(v);
    wh[idx] = h;
    wl[idx] = f2bf(v - bf2f(h));
}

// ---------------- K1: gates ----------------
__global__ __launch_bounds__(256) void gates_kernel(const float* __restrict__ x,
                                                    const float* __restrict__ Wi,
                                                    const float* __restrict__ bi,
                                                    const float* __restrict__ Wf,
                                                    const float* __restrict__ bfb,
                                                    float* __restrict__ ipre,
                                                    float* __restrict__ lgf) {
    int bs = blockIdx.x;
    int b = bs >> 11, s = bs & 2047;
    const float* xr = x + (size_t)bs * 1024;
    int lane = threadIdx.x & 63, w = threadIdx.x >> 6;
    const float* W = (w < 2) ? Wi : Wf;
    int h0 = (w & 1) * 4;
    float dot0 = 0.f, dot1 = 0.f, dot2 = 0.f, dot3 = 0.f;
    for (int i = lane; i < 1024; i += 64) {
        float xv = xr[i];
        dot0 += xv * W[(size_t)(h0 + 0) * 1024 + i];
        dot1 += xv * W[(size_t)(h0 + 1) * 1024 + i];
        dot2 += xv * W[(size_t)(h0 + 2) * 1024 + i];
        dot3 += xv * W[(size_t)(h0 + 3) * 1024 + i];
    }
#pragma unroll
    for (int o = 32; o; o >>= 1) {
        dot0 += __shfl_xor(dot0, o);
        dot1 += __shfl_xor(dot1, o);
        dot2 += __shfl_xor(dot2, o);
        dot3 += __shfl_xor(dot3, o);
    }
    if (lane == 0) {
        float d[4] = {dot0, dot1, dot2, dot3};
#pragma unroll
        for (int j = 0; j < 4; j++) {
            int hh = h0 + j;
            if (w < 2) {
                float z = d[j] + bi[hh];
                z = 15.f * tanhf(z * (1.f / 15.f));
                ipre[((size_t)b * 8 + hh) * 2048 + s] = z;
            } else {
                float z = d[j] + bfb[hh];
                z = 15.f * tanhf(z * (1.f / 15.f));
                lgf[((size_t)b * 8 + hh) * 2048 + s] = fminf(z, 0.f) - log1pf(expf(-fabsf(z)));
            }
        }
    }
}

// ---------------- K2: scan ----------------
__global__ void scan_kernel(const float* __restrict__ ipre, const float* __restrict__ lgf,
                            float* __restrict__ csum, float* __restrict__ aarr,
                            float* __restrict__ marr) {
    int bh = blockIdx.x;
    int lane = threadIdx.x;
    const float* lf = lgf + (size_t)bh * 2048;
    const float* ip = ipre + (size_t)bh * 2048;
    float* cs = csum + (size_t)bh * 2048;
    float* aa = aarr + (size_t)bh * 2048;
    float* mm = marr + (size_t)bh * 2048;
    float carry = 0.f;
    float carrym = -1e30f;
    for (int c = 0; c < 32; c++) {
        float v = lf[c * 64 + lane];
#pragma unroll
        for (int o = 1; o < 64; o <<= 1) {
            float t = __shfl_up(v, o);
            if (lane >= o) v += t;
        }
        float cval = carry + v;
        cs[c * 64 + lane] = cval;
        float a = ip[c * 64 + lane] - cval;
        aa[c * 64 + lane] = a;
        float mv = a;
#pragma unroll
        for (int o = 1; o < 64; o <<= 1) {
            float t = __shfl_up(mv, o);
            if (lane >= o) mv = fmaxf(mv, t);
        }
        float mval = fmaxf(carrym, mv);
        mm[c * 64 + lane] = mval;
        carry = __shfl(cval, 63);
        carrym = __shfl(mval, 63);
    }
}

// ---- K3/K6: 3-product GEMM, 128x128 tile; og rows (blockIdx.y>=og_y0) 1-product
__global__ __launch_bounds__(256) void gemm_bt3(const unsigned short* __restrict__ Ah,
                                                const unsigned short* __restrict__ Al,
                                                const unsigned short* __restrict__ Bh,
                                                const unsigned short* __restrict__ Bl,
                                                void* __restrict__ Cp,
                                                unsigned short* __restrict__ Clo,
                                                int K, int ldc, int c_bf16, int og_y0) {
    __shared__ __attribute__((aligned(16))) unsigned short Ash[128 * 40];
    __shared__ __attribute__((aligned(16))) unsigned short Asl[128 * 40];
    __shared__ __attribute__((aligned(16))) unsigned short Bsh[128 * 40];
    __shared__ __attribute__((aligned(16))) unsigned short Bsl[128 * 40];
    const int tid = threadIdx.x;
    const int lane = tid & 63, wv = tid >> 6;
    const int wr = wv >> 1, wc = wv & 1;
    const int fr = lane & 15, fg = lane >> 4;
    const int srow = tid >> 1, scol = (tid & 1) * 16;
    const bool full3 = (blockIdx.y < (unsigned)og_y0);
    const size_t aoff = (size_t)(blockIdx.x * 128 + srow) * K + scol;
    const size_t boff = (size_t)(blockIdx.y * 128 + srow) * K + scol;
    f32x4 acc[4][4] = {};
    for (int kt = 0; kt < K; kt += 32) {
        us8 avh0 = *(const us8*)(Ah + aoff + kt);
        us8 avh1 = *(const us8*)(Ah + aoff + kt + 8);
        us8 avl0 = *(const us8*)(Al + aoff + kt);
        us8 avl1 = *(const us8*)(Al + aoff + kt + 8);
        us8 bvh0 = *(const us8*)(Bh + boff + kt);
        us8 bvh1 = *(const us8*)(Bh + boff + kt + 8);
        us8 bvl0 = *(const us8*)(Bl + boff + kt);
        us8 bvl1 = *(const us8*)(Bl + boff + kt + 8);
        __syncthreads();
        *(us8*)&Ash[srow * 40 + scol] = avh0;
        *(us8*)&Ash[srow * 40 + scol + 8] = avh1;
        *(us8*)&Asl[srow * 40 + scol] = avl0;
        *(us8*)&Asl[srow * 40 + scol + 8] = avl1;
        *(us8*)&Bsh[srow * 40 + scol] = bvh0;
        *(us8*)&Bsh[srow * 40 + scol + 8] = bvh1;
        *(us8*)&Bsl[srow * 40 + scol] = bvl0;
        *(us8*)&Bsl[srow * 40 + scol + 8] = bvl1;
        __syncthreads();
        bf16x8 bfh[4], bfl[4];
#pragma unroll
        for (int j = 0; j < 4; j++) {
            bfh[j] = __builtin_bit_cast(bf16x8, *(const us8*)&Bsh[(64 * wc + 16 * j + fr) * 40 + fg * 8]);
            bfl[j] = __builtin_bit_cast(bf16x8, *(const us8*)&Bsl[(64 * wc + 16 * j + fr) * 40 + fg * 8]);
        }
        __builtin_amdgcn_s_setprio(1);
        if (full3) {
#pragma unroll
            for (int i = 0; i < 4; i++) {
                bf16x8 afh = __builtin_bit_cast(bf16x8, *(const us8*)&Ash[(64 * wr + 16 * i + fr) * 40 + fg * 8]);
                bf16x8 afl = __builtin_bit_cast(bf16x8, *(const us8*)&Asl[(64 * wr + 16 * i + fr) * 40 + fg * 8]);
#pragma unroll
                for (int j = 0; j < 4; j++) {
                    acc[i][j] = mfma16(afh, bfh[j], acc[i][j]);
                    acc[i][j] = mfma16(afh, bfl[j], acc[i][j]);
                    acc[i][j] = mfma16(afl, bfh[j], acc[i][j]);
                }
            }
        } else {
#pragma unroll
            for (int i = 0; i < 4; i++) {
                bf16x8 afh = __builtin_bit_cast(bf16x8, *(const us8*)&Ash[(64 * wr + 16 * i + fr) * 40 + fg * 8]);
#pragma unroll
                for (int j = 0; j < 4; j++)
                    acc[i][j] = mfma16(afh, bfh[j], acc[i][j]);
            }
        }
        __builtin_amdgcn_s_setprio(0);
    }
#pragma unroll
    for (int i = 0; i < 4; i++)
#pragma unroll
        for (int j = 0; j < 4; j++)
#pragma unroll
            for (int e = 0; e < 4; e++) {
                int r = blockIdx.x * 128 + 64 * wr + 16 * i + fg * 4 + e;
                int c = blockIdx.y * 128 + 64 * wc + 16 * j + fr;
                float v = acc[i][j][e];
                if (c_bf16) {
                    unsigned short h = f2bf(v);
                    ((unsigned short*)Cp)[(size_t)r * ldc + c] = h;
                    Clo[(size_t)r * ldc + c] = f2bf(v - bf2f(h));
                } else {
                    ((float*)Cp)[(size_t)r * ldc + c] = v;
                }
            }
}

// ---------------- K4: vT via coalesced LDS-tiled transpose ----------------
__global__ __launch_bounds__(256) void make_vt(const unsigned short* __restrict__ ph,
                                               const unsigned short* __restrict__ pl,
                                               unsigned short* __restrict__ vTh,
                                               unsigned short* __restrict__ vTl) {
    __shared__ __attribute__((aligned(16))) unsigned short th[64 * 68];
    __shared__ __attribute__((aligned(16))) unsigned short tl[64 * 68];
    const int bid = blockIdx.x;
    const int st = bid & 31, ct = (bid >> 5) & 1, b = bid >> 6;
    const int tid = threadIdx.x;
    {
        const int sr = tid >> 2, cc = (tid & 3) * 16;
        const size_t rbase = (size_t)(b * 2048 + st * 64 + sr) * 2304 + 1152 + ct * 64 + cc;
        us8 a0 = *(const us8*)(ph + rbase);
        us8 a1 = *(const us8*)(ph + rbase + 8);
        us8 c0 = *(const us8*)(pl + rbase);
        us8 c1 = *(const us8*)(pl + rbase + 8);
        *(us8*)&th[sr * 68 + cc] = a0;
        *(us8*)&th[sr * 68 + cc + 8] = a1;
        *(us8*)&tl[sr * 68 + cc] = c0;
        *(us8*)&tl[sr * 68 + cc + 8] = c1;
    }
    __syncthreads();
    {
        const int cr = tid >> 2, ss = (tid & 3) * 16;
        us8 oh0, oh1, ol0, ol1;
#pragma unroll
        for (int e = 0; e < 8; e++) {
            oh0[e] = th[(ss + e) * 68 + cr];
            oh1[e] = th[(ss + 8 + e) * 68 + cr];
            ol0[e] = tl[(ss + e) * 68 + cr];
            ol1[e] = tl[(ss + 8 + e) * 68 + cr];
        }
        const size_t wbase = (size_t)b * 128 * 2048 + (size_t)(ct * 64 + cr) * 2048 + st * 64 + ss;
        *(us8*)&vTh[wbase] = oh0;
        *(us8*)&vTh[wbase + 8] = oh1;
        *(us8*)&vTl[wbase] = ol0;
        *(us8*)&vTl[wbase + 8] = ol1;
    }
}

// ---------------- K5: fused attn — dbuf pair, K-loop unrolled x2 ------------
__global__ __launch_bounds__(256, 2) void attn_fused(const unsigned short* __restrict__ projh,
                                                     const unsigned short* __restrict__ projl,
                                                     const unsigned short* __restrict__ vTh,
                                                     const unsigned short* __restrict__ vTl,
                                                     const float* __restrict__ aarr,
                                                     const float* __restrict__ marr,
                                                     const float* __restrict__ csum,
                                                     const float* __restrict__ lnw,
                                                     unsigned short* __restrict__ ho_hi,
                                                     unsigned short* __restrict__ ho_lo) {
    __shared__ __attribute__((aligned(16))) unsigned short Klh[2][32 * 148];
    __shared__ __attribute__((aligned(16))) unsigned short Kll[2][32 * 148];
    __shared__ __attribute__((aligned(16))) unsigned short Vlh[2][128 * 40];
    __shared__ __attribute__((aligned(16))) unsigned short Vll[2][128 * 40];
    __shared__ float al[2][32];

    const int idx = blockIdx.x;
    const int half = idx >> 8;
    const int pid = idx & 255;
    const int bh = pid & 15;
    const int qt0 = pid >> 4;
    const int qt = half ? (31 - qt0) : qt0;
    const int b = bh >> 3, h = bh & 7;
    const int tid = threadIdx.x, lane = tid & 63, w = tid >> 6;
    const int fr = lane & 15, fg = lane >> 4;
    const int q0 = qt * 64;
    const int qg = q0 + 16 * w + fr;

    bf16x8 qfh[4], qfl[4];
    {
        const size_t qoff = (size_t)(b * 2048 + qg) * 2304 + h * 128;
#pragma unroll
        for (int ks = 0; ks < 4; ks++) {
            qfh[ks] = __builtin_bit_cast(bf16x8, *(const us8*)(projh + qoff + ks * 32 + fg * 8));
            qfl[ks] = __builtin_bit_cast(bf16x8, *(const us8*)(projl + qoff + ks * 32 + fg * 8));
        }
    }
    const float ma_q = marr[(size_t)bh * 2048 + qg];

    f32x4 acc[8] = {};
    float b_run = 0.f;

    const int kr = tid >> 3, kc = (tid & 7) * 16;
    const int vr = tid >> 1, vc = (tid & 1) * 16;
    const size_t kbase = (size_t)(b * 2048) * 2304 + 1024;
    const size_t vtbase = (size_t)b * 128 * 2048;

    const int nt = 2 * qt + 2;   // always even
    us8 kh0A, kh1A, kl0A, kl1A, vh0A, vh1A, vl0A, vl1A;
    us8 kh0B, kh1B, kl0B, kl1B, vh0B, vh1B, vl0B, vl1B;
    float a_stA, a_stB;
#define LOADPAIR(T0)                                                           \
    {                                                                          \
        const size_t koA = kbase + (size_t)((T0) + kr) * 2304 + kc;            \
        const size_t voA = vtbase + (size_t)vr * 2048 + (T0) + vc;             \
        kh0A = *(const us8*)(projh + koA);                                     \
        kh1A = *(const us8*)(projh + koA + 8);                                 \
        kl0A = *(const us8*)(projl + koA);                                     \
        kl1A = *(const us8*)(projl + koA + 8);                                 \
        vh0A = *(const us8*)(vTh + voA);                                       \
        vh1A = *(const us8*)(vTh + voA + 8);                                   \
        vl0A = *(const us8*)(vTl + voA);                                       \
        vl1A = *(const us8*)(vTl + voA + 8);                                   \
        a_stA = (tid < 32) ? aarr[(size_t)bh * 2048 + (T0) + tid] : 0.f;       \
        const size_t koB = koA + 32ull * 2304;                                 \
        const size_t voB = voA + 32;                                           \
        kh0B = *(const us8*)(projh + koB);                                     \
        kh1B = *(const us8*)(projh + koB + 8);                                 \
        kl0B = *(const us8*)(projl + koB);                                     \
        kl1B = *(const us8*)(projl + koB + 8);                                 \
        vh0B = *(const us8*)(vTh + voB);                                       \
        vh1B = *(const us8*)(vTh + voB + 8);                                   \
        vl0B = *(const us8*)(vTl + voB);                                       \
        vl1B = *(const us8*)(vTl + voB + 8);                                   \
        a_stB = (tid < 32) ? aarr[(size_t)bh * 2048 + (T0) + 32 + tid] : 0.f;  \
    }
#define STOREPAIR()                                                            \
    {                                                                          \
        *(us8*)&Klh[0][kr * 148 + kc] = kh0A;                                  \
        *(us8*)&Klh[0][kr * 148 + kc + 8] = kh1A;                              \
        *(us8*)&Kll[0][kr * 148 + kc] = kl0A;                                  \
        *(us8*)&Kll[0][kr * 148 + kc + 8] = kl1A;                              \
        *(us8*)&Vlh[0][vr * 40 + vc] = vh0A;                                   \
        *(us8*)&Vlh[0][vr * 40 + vc + 8] = vh1A;                               \
        *(us8*)&Vll[0][vr * 40 + vc] = vl0A;                                   \
        *(us8*)&Vll[0][vr * 40 + vc + 8] = vl1A;                               \
        *(us8*)&Klh[1][kr * 148 + kc] = kh0B;                                  \
        *(us8*)&Klh[1][kr * 148 + kc + 8] = kh1B;                              \
        *(us8*)&Kll[1][kr * 148 + kc] = kl0B;                                  \
        *(us8*)&Kll[1][kr * 148 + kc + 8] = kl1B;                              \
        *(us8*)&Vlh[1][vr * 40 + vc] = vh0B;                                   \
        *(us8*)&Vlh[1][vr * 40 + vc + 8] = vh1B;                               \
        *(us8*)&Vll[1][vr * 40 + vc] = vl0B;                                   \
        *(us8*)&Vll[1][vr * 40 + vc + 8] = vl1B;                               \
        if (tid < 32) {                                                        \
            al[0][tid] = a_stA;                                                \
            al[1][tid] = a_stB;                                                \
        }                                                                      \
    }

    LOADPAIR(0);
    STOREPAIR();
    if (nt > 2) LOADPAIR(64);
    __syncthreads();

    for (int kt = 0;;) {
        const int t0 = kt * 32;

        // --- QK for both tiles, interleaved (6 independent chains) ---
        float djA[2][4], djB[2][4];
#pragma unroll
        for (int j = 0; j < 2; j++) {
            f32x4 sfaA = {}, sfbA = {}, sfcA = {};
            f32x4 sfaB = {}, sfbB = {}, sfcB = {};
            __builtin_amdgcn_s_setprio(1);
#pragma unroll
            for (int ks = 0; ks < 4; ks++) {
                bf16x8 kfhA = __builtin_bit_cast(bf16x8, *(const us8*)&Klh[0][(j * 16 + fr) * 148 + ks * 32 + fg * 8]);
                bf16x8 kflA = __builtin_bit_cast(bf16x8, *(const us8*)&Kll[0][(j * 16 + fr) * 148 + ks * 32 + fg * 8]);
                bf16x8 kfhB = __builtin_bit_cast(bf16x8, *(const us8*)&Klh[1][(j * 16 + fr) * 148 + ks * 32 + fg * 8]);
                bf16x8 kflB = __builtin_bit_cast(bf16x8, *(const us8*)&Kll[1][(j * 16 + fr) * 148 + ks * 32 + fg * 8]);
                sfaA = mfma16(kfhA, qfh[ks], sfaA);
                sfaB = mfma16(kfhB, qfh[ks], sfaB);
                sfbA = mfma16(kfhA, qfl[ks], sfbA);
                sfbB = mfma16(kfhB, qfl[ks], sfbB);
                sfcA = mfma16(kflA, qfh[ks], sfcA);
                sfcB = mfma16(kflB, qfh[ks], sfcB);
            }
            __builtin_amdgcn_s_setprio(0);
            f32x4 sfA = (sfaA + sfbA) + sfcA;
            f32x4 sfB = (sfaB + sfbB) + sfcB;
#pragma unroll
            for (int r = 0; r < 4; r++) {
                const int kloc = j * 16 + fg * 4 + r;
                const float atvA = al[0][kloc];
                const float atvB = al[1][kloc];
                djA[j][r] = ((t0 + kloc) <= qg) ? sfA[r] * __expf(atvA - ma_q) : 0.f;
                djB[j][r] = ((t0 + 32 + kloc) <= qg) ? sfB[r] * __expf(atvB - ma_q) : 0.f;
            }
        }

        // b_run: tile A then tile B (preserves v12 order)
        {
            float tsA = djA[0][0] + djA[0][1] + djA[0][2] + djA[0][3]
                      + djA[1][0] + djA[1][1] + djA[1][2] + djA[1][3];
            tsA += __shfl_xor(tsA, 16);
            tsA += __shfl_xor(tsA, 32);
            b_run += tsA;
            float tsB = djB[0][0] + djB[0][1] + djB[0][2] + djB[0][3]
                      + djB[1][0] + djB[1][1] + djB[1][2] + djB[1][3];
            tsB += __shfl_xor(tsB, 16);
            tsB += __shfl_xor(tsB, 32);
            b_run += tsB;
        }

        const int srlo = 32 * ((lane >> 4) & 1) + fr;
        // --- relayout A -> PV A ---
        {
            float p8[8];
#pragma unroll
            for (int e = 0; e < 8; e++) {
                const int sl = srlo + ((e >= 4) ? 16 : 0);
                const float v0 = __shfl(djA[0][e & 3], sl);
                const float v1 = __shfl(djA[1][e & 3], sl);
                p8[e] = (lane & 32) ? v1 : v0;
            }
            us8 phu, plu;
#pragma unroll
            for (int e = 0; e < 8; e++) {
                unsigned short hh = f2bf(p8[e]);
                phu[e] = hh;
                plu[e] = f2bf(p8[e] - bf2f(hh));
            }
            const bf16x8 pfh = __builtin_bit_cast(bf16x8, phu);
            const bf16x8 pfl = __builtin_bit_cast(bf16x8, plu);
            __builtin_amdgcn_s_setprio(1);
#pragma unroll
            for (int jb = 0; jb < 8; jb++) {
                bf16x8 vfh = __builtin_bit_cast(bf16x8, *(const us8*)&Vlh[0][(jb * 16 + fr) * 40 + fg * 8]);
                bf16x8 vfl = __builtin_bit_cast(bf16x8, *(const us8*)&Vll[0][(jb * 16 + fr) * 40 + fg * 8]);
                acc[jb] = mfma16(vfh, pfh, acc[jb]);
                acc[jb] = mfma16(vfh, pfl, acc[jb]);
                acc[jb] = mfma16(vfl, pfh, acc[jb]);
            }
            __builtin_amdgcn_s_setprio(0);
        }
        // --- relayout B -> PV B ---
        {
            float p8[8];
#pragma unroll
            for (int e = 0; e < 8; e++) {
                const int sl = srlo + ((e >= 4) ? 16 : 0);
                const float v0 = __shfl(djB[0][e & 3], sl);
                const float v1 = __shfl(djB[1][e & 3], sl);
                p8[e] = (lane & 32) ? v1 : v0;
            }
            us8 phu, plu;
#pragma unroll
            for (int e = 0; e < 8; e++) {
                unsigned short hh = f2bf(p8[e]);
                phu[e] = hh;
                plu[e] = f2bf(p8[e] - bf2f(hh));
            }
            const bf16x8 pfh = __builtin_bit_cast(bf16x8, phu);
            const bf16x8 pfl = __builtin_bit_cast(bf16x8, plu);
            __builtin_amdgcn_s_setprio(1);
#pragma unroll
            for (int jb = 0; jb < 8; jb++) {
                bf16x8 vfh = __builtin_bit_cast(bf16x8, *(const us8*)&Vlh[1][(jb * 16 + fr) * 40 + fg * 8]);
                bf16x8 vfl = __builtin_bit_cast(bf16x8, *(const us8*)&Vll[1][(jb * 16 + fr) * 40 + fg * 8]);
                acc[jb] = mfma16(vfh, pfh, acc[jb]);
                acc[jb] = mfma16(vfh, pfl, acc[jb]);
                acc[jb] = mfma16(vfl, pfh, acc[jb]);
            }
            __builtin_amdgcn_s_setprio(0);
        }

        kt += 2;
        if (kt >= nt) break;
        __syncthreads();                 // all waves done reading bufs
        STOREPAIR();                     // bufs <- regs (tiles kt, kt+1)
        if (kt + 2 < nt) LOADPAIR((kt + 2) * 32);
        __syncthreads();                 // writes visible
    }
#undef LOADPAIR
#undef STOREPAIR

    const float cs_q = csum[(size_t)bh * 2048 + qg];
    const float nf = __expf(-(cs_q + ma_q));
    const float n = fmaxf(fabsf(b_run), nf);
    const float inv = 1.f / (n + 1e-6f);
#pragma unroll
    for (int jb = 0; jb < 8; jb++) acc[jb] *= inv;

    float s1 = 0.f;
#pragma unroll
    for (int jb = 0; jb < 8; jb++) s1 += acc[jb][0] + acc[jb][1] + acc[jb][2] + acc[jb][3];
    s1 += __shfl_xor(s1, 16);
    s1 += __shfl_xor(s1, 32);
    const float mu = s1 * (1.f / 128.f);
    float vv = 0.f;
#pragma unroll
    for (int jb = 0; jb < 8; jb++)
#pragma unroll
        for (int e = 0; e < 4; e++) {
            float d = acc[jb][e] - mu;
            vv += d * d;
        }
    vv += __shfl_xor(vv, 16);
    vv += __shfl_xor(vv, 32);
    const float rstd = rsqrtf(vv * (1.f / 128.f) + 1e-6f);

    const size_t obase = (size_t)(b * 2048 + qg) * 2304 + 1280 + h * 128 + fg * 4;
    const size_t hbase = (size_t)(b * 2048 + qg) * 1024 + h * 128 + fg * 4;
#pragma unroll
    for (int jb = 0; jb < 8; jb++) {
        us4 ogh = *(const us4*)(projh + obase + jb * 16);
        us4 ogl = *(const us4*)(projl + obase + jb * 16);
        f32x4 lw = *(const f32x4*)&lnw[h * 128 + jb * 16 + fg * 4];
        us4 hi4, lo4;
#pragma unroll
        for (int e = 0; e < 4; e++) {
            const float og = bf2f(ogh[e]) + bf2f(ogl[e]);
            const float sig = 1.f / (1.f + __expf(-og));
            const float ho = (acc[jb][e] - mu) * rstd * lw[e] * sig;
            unsigned short h1 = f2bf(ho);
            hi4[e] = h1;
            lo4[e] = f2bf(ho - bf2f(h1));
        }
        *(us4*)&ho_hi[hbase + jb * 16] = hi4;
        *(us4*)&ho_lo[hbase + jb * 16] = lo4;
    }
}

// ---------------------------------------------------------------------------
extern "C" void kernel_launch(void* const* d_in, const int* in_sizes, int n_in,
                              void* d_out, int out_size, void* d_ws, size_t ws_size,
                              hipStream_t stream) {
    (void)in_sizes; (void)n_in; (void)out_size; (void)ws_size;
    const float* x    = (const float*)d_in[0];
    const float* Wq   = (const float*)d_in[1];
    const float* Wk   = (const float*)d_in[2];
    const float* Wv   = (const float*)d_in[3];
    const float* Wog  = (const float*)d_in[4];
    const float* Wi   = (const float*)d_in[5];
    const float* bi   = (const float*)d_in[6];
    const float* Wf   = (const float*)d_in[7];
    const float* bfb  = (const float*)d_in[8];
    const float* lnw  = (const float*)d_in[9];
    const float* Wout = (const float*)d_in[10];

    char* p = (char*)d_ws;
    auto carve = [&](size_t bytes) -> char* {
        char* r = p;
        p += (bytes + 255) & ~(size_t)255;
        return r;
    };
    unsigned short* x_hi   = (unsigned short*)carve(4194304ull * 2);
    unsigned short* x_lo   = (unsigned short*)carve(4194304ull * 2);
    unsigned short* wc_hi  = (unsigned short*)carve(2359296ull * 2);
    unsigned short* wc_lo  = (unsigned short*)carve(2359296ull * 2);
    unsigned short* wo_hi  = (unsigned short*)carve(1048576ull * 2);
    unsigned short* wo_lo  = (unsigned short*)carve(1048576ull * 2);
    unsigned short* pr_hi  = (unsigned short*)carve(4096ull * 2304 * 2);
    unsigned short* pr_lo  = (unsigned short*)carve(4096ull * 2304 * 2);
    unsigned short* vT_hi  = (unsigned short*)carve(524288ull * 2);
    unsigned short* vT_lo  = (unsigned short*)carve(524288ull * 2);
    float* ipre    = (float*)carve(32768ull * 4);
    float* lgf_buf = (float*)carve(32768ull * 4);
    float* csum    = (float*)carve(32768ull * 4);
    float* aarr    = (float*)carve(32768ull * 4);
    float* marr    = (float*)carve(32768ull * 4);
    unsigned short* ho_hi = x_hi;   // x dead after proj GEMM
    unsigned short* ho_lo = x_lo;

    k_split_bf16<<<16384, 256, 0, stream>>>(x, x_hi, x_lo, 4194304);
    build_wcat<<<(2359296 + 255) / 256, 256, 0, stream>>>(Wq, Wk, Wv, Wog, wc_hi, wc_lo);
    k_split_bf16<<<4096, 256, 0, stream>>>(Wout, wo_hi, wo_lo, 1048576);
    gates_kernel<<<4096, 256, 0, stream>>>(x, Wi, bi, Wf, bfb, ipre, lgf_buf);
    scan_kernel<<<16, 64, 0, stream>>>(ipre, lgf_buf, csum, aarr, marr);
    gemm_bt3<<<dim3(32, 18), 256, 0, stream>>>(x_hi, x_lo, wc_hi, wc_lo, pr_hi, pr_lo, 1024, 2304, 1, 10);
    make_vt<<<128, 256, 0, stream>>>(pr_hi, pr_lo, vT_hi, vT_lo);
    attn_fused<<<512, 256, 0, stream>>>(pr_hi, pr_lo, vT_hi, vT_lo, aarr, marr, csum, lnw, ho_hi, ho_lo);
    gemm_bt3<<<dim3(32, 8), 256, 0, stream>>>(ho_hi, ho_lo, wo_hi, wo_lo, d_out, nullptr, 1024, 1024, 0, 1000);
}

// Round 20
// 323.592 us; speedup vs baseline: 1.3168x; 1.0219x over previous
//
#include <hip/hip_runtime.h>

// ---------------------------------------------------------------------------
// mLSTM block, MI355X. B=2,S=2048,D=1024,NH=8,DH=128.
// v19 = v18 (attn unroll x2, og-single GEMM) + fused float4 prep kernel
//       (x-split + Wcat-build + Wout-split in one launch). Numerics identical.
// ---------------------------------------------------------------------------

typedef __bf16 bf16x8 __attribute__((ext_vector_type(8)));
typedef float f32x4 __attribute__((ext_vector_type(4)));
typedef unsigned short us8 __attribute__((ext_vector_type(8)));
typedef unsigned short us4 __attribute__((ext_vector_type(4)));

__device__ __forceinline__ unsigned short f2bf(float f) {
    unsigned int u = __builtin_bit_cast(unsigned int, f);
    unsigned int r = u + 0x7fffu + ((u >> 16) & 1u);
    return (unsigned short)(r >> 16);
}
__device__ __forceinline__ float bf2f(unsigned short h) {
    unsigned int u = ((unsigned int)h) << 16;
    return __builtin_bit_cast(float, u);
}
__device__ __forceinline__ f32x4 mfma16(bf16x8 a, bf16x8 b, f32x4 c) {
    return __builtin_amdgcn_mfma_f32_16x16x32_bf16(a, b, c, 0, 0, 0);
}

// ---------------- K0: fused prep — x split, Wcat build, Wout split (float4) --
__global__ __launch_bounds__(256) void prep(const float* __restrict__ x,
                                            const float* __restrict__ Wq,
                                            const float* __restrict__ Wk,
                                            const float* __restrict__ Wv,
                                            const float* __restrict__ Wog,
                                            const float* __restrict__ Wout,
                                            unsigned short* __restrict__ x_hi,
                                            unsigned short* __restrict__ x_lo,
                                            unsigned short* __restrict__ wc_hi,
                                            unsigned short* __restrict__ wc_lo,
                                            unsigned short* __restrict__ wo_hi,
                                            unsigned short* __restrict__ wo_lo) {
    const int id = blockIdx.x * 256 + threadIdx.x;
    f32x4 v;
    unsigned short* dh;
    unsigned short* dl;
    size_t off;
    if (id < 1048576) {                       // x: 4194304 elems / 4
        off = (size_t)id * 4;
        v = *(const f32x4*)(x + off);
        dh = x_hi; dl = x_lo;
    } else if (id < 1048576 + 589824) {       // wcat: 2304*1024 / 4
        const int e = id - 1048576;
        const int row = e >> 8;
        const int col = (e & 255) * 4;
        off = (size_t)row * 1024 + col;
        if (row < 1024) {
            v = *(const f32x4*)(Wq + off);
#pragma unroll
            for (int t = 0; t < 4; t++) v[t] *= 0.08838834764831845f;
        } else if (row < 1152) {
            v = *(const f32x4*)(Wk + (size_t)(row - 1024) * 1024 + col);
        } else if (row < 1280) {
            v = *(const f32x4*)(Wv + (size_t)(row - 1152) * 1024 + col);
        } else {
            v = *(const f32x4*)(Wog + (size_t)(row - 1280) * 1024 + col);
        }
        dh = wc_hi; dl = wc_lo;
    } else {                                  // Wout: 1048576 / 4
        const int e = id - 1048576 - 589824;
        if (e >= 262144) return;
        off = (size_t)e * 4;
        v = *(const f32x4*)(Wout + off);
        dh = wo_hi; dl = wo_lo;
    }
    us4 h4, l4;
#pragma unroll
    for (int t = 0; t < 4; t++) {
        unsigned short hh = f2bf(v[t]);
        h4[t] = hh;
        l4[t] = f2bf(v[t] - bf2f(hh));
    }
    *(us4*)(dh + off) = h4;
    *(us4*)(dl + off) = l4;
}

// ---------------- K1: gates ----------------
__global__ __launch_bounds__(256) void gates_kernel(const float* __restrict__ x,
                                                    const float* __restrict__ Wi,
                                                    const float* __restrict__ bi,
                                                    const float* __restrict__ Wf,
                                                    const float* __restrict__ bfb,
                                                    float* __restrict__ ipre,
                                                    float* __restrict__ lgf) {
    int bs = blockIdx.x;
    int b = bs >> 11, s = bs & 2047;
    const float* xr = x + (size_t)bs * 1024;
    int lane = threadIdx.x & 63, w = threadIdx.x >> 6;
    const float* W = (w < 2) ? Wi : Wf;
    int h0 = (w & 1) * 4;
    float dot0 = 0.f, dot1 = 0.f, dot2 = 0.f, dot3 = 0.f;
    for (int i = lane; i < 1024; i += 64) {
        float xv = xr[i];
        dot0 += xv * W[(size_t)(h0 + 0) * 1024 + i];
        dot1 += xv * W[(size_t)(h0 + 1) * 1024 + i];
        dot2 += xv * W[(size_t)(h0 + 2) * 1024 + i];
        dot3 += xv * W[(size_t)(h0 + 3) * 1024 + i];
    }
#pragma unroll
    for (int o = 32; o; o >>= 1) {
        dot0 += __shfl_xor(dot0, o);
        dot1 += __shfl_xor(dot1, o);
        dot2 += __shfl_xor(dot2, o);
        dot3 += __shfl_xor(dot3, o);
    }
    if (lane == 0) {
        float d[4] = {dot0, dot1, dot2, dot3};
#pragma unroll
        for (int j = 0; j < 4; j++) {
            int hh = h0 + j;
            if (w < 2) {
                float z = d[j] + bi[hh];
                z = 15.f * tanhf(z * (1.f / 15.f));
                ipre[((size_t)b * 8 + hh) * 2048 + s] = z;
            } else {
                float z = d[j] + bfb[hh];
                z = 15.f * tanhf(z * (1.f / 15.f));
                lgf[((size_t)b * 8 + hh) * 2048 + s] = fminf(z, 0.f) - log1pf(expf(-fabsf(z)));
            }
        }
    }
}

// ---------------- K2: scan ----------------
__global__ void scan_kernel(const float* __restrict__ ipre, const float* __restrict__ lgf,
                            float* __restrict__ csum, float* __restrict__ aarr,
                            float* __restrict__ marr) {
    int bh = blockIdx.x;
    int lane = threadIdx.x;
    const float* lf = lgf + (size_t)bh * 2048;
    const float* ip = ipre + (size_t)bh * 2048;
    float* cs = csum + (size_t)bh * 2048;
    float* aa = aarr + (size_t)bh * 2048;
    float* mm = marr + (size_t)bh * 2048;
    float carry = 0.f;
    float carrym = -1e30f;
    for (int c = 0; c < 32; c++) {
        float v = lf[c * 64 + lane];
#pragma unroll
        for (int o = 1; o < 64; o <<= 1) {
            float t = __shfl_up(v, o);
            if (lane >= o) v += t;
        }
        float cval = carry + v;
        cs[c * 64 + lane] = cval;
        float a = ip[c * 64 + lane] - cval;
        aa[c * 64 + lane] = a;
        float mv = a;
#pragma unroll
        for (int o = 1; o < 64; o <<= 1) {
            float t = __shfl_up(mv, o);
            if (lane >= o) mv = fmaxf(mv, t);
        }
        float mval = fmaxf(carrym, mv);
        mm[c * 64 + lane] = mval;
        carry = __shfl(cval, 63);
        carrym = __shfl(mval, 63);
    }
}

// ---- K3/K6: 3-product GEMM, 128x128 tile; og rows (blockIdx.y>=og_y0) 1-product
__global__ __launch_bounds__(256) void gemm_bt3(const unsigned short* __restrict__ Ah,
                                                const unsigned short* __restrict__ Al,
                                                const unsigned short* __restrict__ Bh,
                                                const unsigned short* __restrict__ Bl,
                                                void* __restrict__ Cp,
                                                unsigned short* __restrict__ Clo,
                                                int K, int ldc, int c_bf16, int og_y0) {
    __shared__ __attribute__((aligned(16))) unsigned short Ash[128 * 40];
    __shared__ __attribute__((aligned(16))) unsigned short Asl[128 * 40];
    __shared__ __attribute__((aligned(16))) unsigned short Bsh[128 * 40];
    __shared__ __attribute__((aligned(16))) unsigned short Bsl[128 * 40];
    const int tid = threadIdx.x;
    const int lane = tid & 63, wv = tid >> 6;
    const int wr = wv >> 1, wc = wv & 1;
    const int fr = lane & 15, fg = lane >> 4;
    const int srow = tid >> 1, scol = (tid & 1) * 16;
    const bool full3 = (blockIdx.y < (unsigned)og_y0);
    const size_t aoff = (size_t)(blockIdx.x * 128 + srow) * K + scol;
    const size_t boff = (size_t)(blockIdx.y * 128 + srow) * K + scol;
    f32x4 acc[4][4] = {};
    for (int kt = 0; kt < K; kt += 32) {
        us8 avh0 = *(const us8*)(Ah + aoff + kt);
        us8 avh1 = *(const us8*)(Ah + aoff + kt + 8);
        us8 avl0 = *(const us8*)(Al + aoff + kt);
        us8 avl1 = *(const us8*)(Al + aoff + kt + 8);
        us8 bvh0 = *(const us8*)(Bh + boff + kt);
        us8 bvh1 = *(const us8*)(Bh + boff + kt + 8);
        us8 bvl0 = *(const us8*)(Bl + boff + kt);
        us8 bvl1 = *(const us8*)(Bl + boff + kt + 8);
        __syncthreads();
        *(us8*)&Ash[srow * 40 + scol] = avh0;
        *(us8*)&Ash[srow * 40 + scol + 8] = avh1;
        *(us8*)&Asl[srow * 40 + scol] = avl0;
        *(us8*)&Asl[srow * 40 + scol + 8] = avl1;
        *(us8*)&Bsh[srow * 40 + scol] = bvh0;
        *(us8*)&Bsh[srow * 40 + scol + 8] = bvh1;
        *(us8*)&Bsl[srow * 40 + scol] = bvl0;
        *(us8*)&Bsl[srow * 40 + scol + 8] = bvl1;
        __syncthreads();
        bf16x8 bfh[4], bfl[4];
#pragma unroll
        for (int j = 0; j < 4; j++) {
            bfh[j] = __builtin_bit_cast(bf16x8, *(const us8*)&Bsh[(64 * wc + 16 * j + fr) * 40 + fg * 8]);
            bfl[j] = __builtin_bit_cast(bf16x8, *(const us8*)&Bsl[(64 * wc + 16 * j + fr) * 40 + fg * 8]);
        }
        __builtin_amdgcn_s_setprio(1);
        if (full3) {
#pragma unroll
            for (int i = 0; i < 4; i++) {
                bf16x8 afh = __builtin_bit_cast(bf16x8, *(const us8*)&Ash[(64 * wr + 16 * i + fr) * 40 + fg * 8]);
                bf16x8 afl = __builtin_bit_cast(bf16x8, *(const us8*)&Asl[(64 * wr + 16 * i + fr) * 40 + fg * 8]);
#pragma unroll
                for (int j = 0; j < 4; j++) {
                    acc[i][j] = mfma16(afh, bfh[j], acc[i][j]);
                    acc[i][j] = mfma16(afh, bfl[j], acc[i][j]);
                    acc[i][j] = mfma16(afl, bfh[j], acc[i][j]);
                }
            }
        } else {
#pragma unroll
            for (int i = 0; i < 4; i++) {
                bf16x8 afh = __builtin_bit_cast(bf16x8, *(const us8*)&Ash[(64 * wr + 16 * i + fr) * 40 + fg * 8]);
#pragma unroll
                for (int j = 0; j < 4; j++)
                    acc[i][j] = mfma16(afh, bfh[j], acc[i][j]);
            }
        }
        __builtin_amdgcn_s_setprio(0);
    }
#pragma unroll
    for (int i = 0; i < 4; i++)
#pragma unroll
        for (int j = 0; j < 4; j++)
#pragma unroll
            for (int e = 0; e < 4; e++) {
                int r = blockIdx.x * 128 + 64 * wr + 16 * i + fg * 4 + e;
                int c = blockIdx.y * 128 + 64 * wc + 16 * j + fr;
                float v = acc[i][j][e];
                if (c_bf16) {
                    unsigned short h = f2bf(v);
                    ((unsigned short*)Cp)[(size_t)r * ldc + c] = h;
                    Clo[(size_t)r * ldc + c] = f2bf(v - bf2f(h));
                } else {
                    ((float*)Cp)[(size_t)r * ldc + c] = v;
                }
            }
}

// ---------------- K4: vT via coalesced LDS-tiled transpose ----------------
__global__ __launch_bounds__(256) void make_vt(const unsigned short* __restrict__ ph,
                                               const unsigned short* __restrict__ pl,
                                               unsigned short* __restrict__ vTh,
                                               unsigned short* __restrict__ vTl) {
    __shared__ __attribute__((aligned(16))) unsigned short th[64 * 68];
    __shared__ __attribute__((aligned(16))) unsigned short tl[64 * 68];
    const int bid = blockIdx.x;
    const int st = bid & 31, ct = (bid >> 5) & 1, b = bid >> 6;
    const int tid = threadIdx.x;
    {
        const int sr = tid >> 2, cc = (tid & 3) * 16;
        const size_t rbase = (size_t)(b * 2048 + st * 64 + sr) * 2304 + 1152 + ct * 64 + cc;
        us8 a0 = *(const us8*)(ph + rbase);
        us8 a1 = *(const us8*)(ph + rbase + 8);
        us8 c0 = *(const us8*)(pl + rbase);
        us8 c1 = *(const us8*)(pl + rbase + 8);
        *(us8*)&th[sr * 68 + cc] = a0;
        *(us8*)&th[sr * 68 + cc + 8] = a1;
        *(us8*)&tl[sr * 68 + cc] = c0;
        *(us8*)&tl[sr * 68 + cc + 8] = c1;
    }
    __syncthreads();
    {
        const int cr = tid >> 2, ss = (tid & 3) * 16;
        us8 oh0, oh1, ol0, ol1;
#pragma unroll
        for (int e = 0; e < 8; e++) {
            oh0[e] = th[(ss + e) * 68 + cr];
            oh1[e] = th[(ss + 8 + e) * 68 + cr];
            ol0[e] = tl[(ss + e) * 68 + cr];
            ol1[e] = tl[(ss + 8 + e) * 68 + cr];
        }
        const size_t wbase = (size_t)b * 128 * 2048 + (size_t)(ct * 64 + cr) * 2048 + st * 64 + ss;
        *(us8*)&vTh[wbase] = oh0;
        *(us8*)&vTh[wbase + 8] = oh1;
        *(us8*)&vTl[wbase] = ol0;
        *(us8*)&vTl[wbase + 8] = ol1;
    }
}

// ---------------- K5: fused attn — dbuf pair, K-loop unrolled x2 ------------
__global__ __launch_bounds__(256, 2) void attn_fused(const unsigned short* __restrict__ projh,
                                                     const unsigned short* __restrict__ projl,
                                                     const unsigned short* __restrict__ vTh,
                                                     const unsigned short* __restrict__ vTl,
                                                     const float* __restrict__ aarr,
                                                     const float* __restrict__ marr,
                                                     const float* __restrict__ csum,
                                                     const float* __restrict__ lnw,
                                                     unsigned short* __restrict__ ho_hi,
                                                     unsigned short* __restrict__ ho_lo) {
    __shared__ __attribute__((aligned(16))) unsigned short Klh[2][32 * 148];
    __shared__ __attribute__((aligned(16))) unsigned short Kll[2][32 * 148];
    __shared__ __attribute__((aligned(16))) unsigned short Vlh[2][128 * 40];
    __shared__ __attribute__((aligned(16))) unsigned short Vll[2][128 * 40];
    __shared__ float al[2][32];

    const int idx = blockIdx.x;
    const int half = idx >> 8;
    const int pid = idx & 255;
    const int bh = pid & 15;
    const int qt0 = pid >> 4;
    const int qt = half ? (31 - qt0) : qt0;
    const int b = bh >> 3, h = bh & 7;
    const int tid = threadIdx.x, lane = tid & 63, w = tid >> 6;
    const int fr = lane & 15, fg = lane >> 4;
    const int q0 = qt * 64;
    const int qg = q0 + 16 * w + fr;

    bf16x8 qfh[4], qfl[4];
    {
        const size_t qoff = (size_t)(b * 2048 + qg) * 2304 + h * 128;
#pragma unroll
        for (int ks = 0; ks < 4; ks++) {
            qfh[ks] = __builtin_bit_cast(bf16x8, *(const us8*)(projh + qoff + ks * 32 + fg * 8));
            qfl[ks] = __builtin_bit_cast(bf16x8, *(const us8*)(projl + qoff + ks * 32 + fg * 8));
        }
    }
    const float ma_q = marr[(size_t)bh * 2048 + qg];

    f32x4 acc[8] = {};
    float b_run = 0.f;

    const int kr = tid >> 3, kc = (tid & 7) * 16;
    const int vr = tid >> 1, vc = (tid & 1) * 16;
    const size_t kbase = (size_t)(b * 2048) * 2304 + 1024;
    const size_t vtbase = (size_t)b * 128 * 2048;

    const int nt = 2 * qt + 2;   // always even
    us8 kh0A, kh1A, kl0A, kl1A, vh0A, vh1A, vl0A, vl1A;
    us8 kh0B, kh1B, kl0B, kl1B, vh0B, vh1B, vl0B, vl1B;
    float a_stA, a_stB;
#define LOADPAIR(T0)                                                           \
    {                                                                          \
        const size_t koA = kbase + (size_t)((T0) + kr) * 2304 + kc;            \
        const size_t voA = vtbase + (size_t)vr * 2048 + (T0) + vc;             \
        kh0A = *(const us8*)(projh + koA);                                     \
        kh1A = *(const us8*)(projh + koA + 8);                                 \
        kl0A = *(const us8*)(projl + koA);                                     \
        kl1A = *(const us8*)(projl + koA + 8);                                 \
        vh0A = *(const us8*)(vTh + voA);                                       \
        vh1A = *(const us8*)(vTh + voA + 8);                                   \
        vl0A = *(const us8*)(vTl + voA);                                       \
        vl1A = *(const us8*)(vTl + voA + 8);                                   \
        a_stA = (tid < 32) ? aarr[(size_t)bh * 2048 + (T0) + tid] : 0.f;       \
        const size_t koB = koA + 32ull * 2304;                                 \
        const size_t voB = voA + 32;                                           \
        kh0B = *(const us8*)(projh + koB);                                     \
        kh1B = *(const us8*)(projh + koB + 8);                                 \
        kl0B = *(const us8*)(projl + koB);                                     \
        kl1B = *(const us8*)(projl + koB + 8);                                 \
        vh0B = *(const us8*)(vTh + voB);                                       \
        vh1B = *(const us8*)(vTh + voB + 8);                                   \
        vl0B = *(const us8*)(vTl + voB);                                       \
        vl1B = *(const us8*)(vTl + voB + 8);                                   \
        a_stB = (tid < 32) ? aarr[(size_t)bh * 2048 + (T0) + 32 + tid] : 0.f;  \
    }
#define STOREPAIR()                                                            \
    {                                                                          \
        *(us8*)&Klh[0][kr * 148 + kc] = kh0A;                                  \
        *(us8*)&Klh[0][kr * 148 + kc + 8] = kh1A;                              \
        *(us8*)&Kll[0][kr * 148 + kc] = kl0A;                                  \
        *(us8*)&Kll[0][kr * 148 + kc + 8] = kl1A;                              \
        *(us8*)&Vlh[0][vr * 40 + vc] = vh0A;                                   \
        *(us8*)&Vlh[0][vr * 40 + vc + 8] = vh1A;                               \
        *(us8*)&Vll[0][vr * 40 + vc] = vl0A;                                   \
        *(us8*)&Vll[0][vr * 40 + vc + 8] = vl1A;                               \
        *(us8*)&Klh[1][kr * 148 + kc] = kh0B;                                  \
        *(us8*)&Klh[1][kr * 148 + kc + 8] = kh1B;                              \
        *(us8*)&Kll[1][kr * 148 + kc] = kl0B;                                  \
        *(us8*)&Kll[1][kr * 148 + kc + 8] = kl1B;                              \
        *(us8*)&Vlh[1][vr * 40 + vc] = vh0B;                                   \
        *(us8*)&Vlh[1][vr * 40 + vc + 8] = vh1B;                               \
        *(us8*)&Vll[1][vr * 40 + vc] = vl0B;                                   \
        *(us8*)&Vll[1][vr * 40 + vc + 8] = vl1B;                               \
        if (tid < 32) {                                                        \
            al[0][tid] = a_stA;                                                \
            al[1][tid] = a_stB;                                                \
        }                                                                      \
    }

    LOADPAIR(0);
    STOREPAIR();
    if (nt > 2) LOADPAIR(64);
    __syncthreads();

    for (int kt = 0;;) {
        const int t0 = kt * 32;

        float djA[2][4], djB[2][4];
#pragma unroll
        for (int j = 0; j < 2; j++) {
            f32x4 sfaA = {}, sfbA = {}, sfcA = {};
            f32x4 sfaB = {}, sfbB = {}, sfcB = {};
            __builtin_amdgcn_s_setprio(1);
#pragma unroll
            for (int ks = 0; ks < 4; ks++) {
                bf16x8 kfhA = __builtin_bit_cast(bf16x8, *(const us8*)&Klh[0][(j * 16 + fr) * 148 + ks * 32 + fg * 8]);
                bf16x8 kflA = __builtin_bit_cast(bf16x8, *(const us8*)&Kll[0][(j * 16 + fr) * 148 + ks * 32 + fg * 8]);
                bf16x8 kfhB = __builtin_bit_cast(bf16x8, *(const us8*)&Klh[1][(j * 16 + fr) * 148 + ks * 32 + fg * 8]);
                bf16x8 kflB = __builtin_bit_cast(bf16x8, *(const us8*)&Kll[1][(j * 16 + fr) * 148 + ks * 32 + fg * 8]);
                sfaA = mfma16(kfhA, qfh[ks], sfaA);
                sfaB = mfma16(kfhB, qfh[ks], sfaB);
                sfbA = mfma16(kfhA, qfl[ks], sfbA);
                sfbB = mfma16(kfhB, qfl[ks], sfbB);
                sfcA = mfma16(kflA, qfh[ks], sfcA);
                sfcB = mfma16(kflB, qfh[ks], sfcB);
            }
            __builtin_amdgcn_s_setprio(0);
            f32x4 sfA = (sfaA + sfbA) + sfcA;
            f32x4 sfB = (sfaB + sfbB) + sfcB;
#pragma unroll
            for (int r = 0; r < 4; r++) {
                const int kloc = j * 16 + fg * 4 + r;
                const float atvA = al[0][kloc];
                const float atvB = al[1][kloc];
                djA[j][r] = ((t0 + kloc) <= qg) ? sfA[r] * __expf(atvA - ma_q) : 0.f;
                djB[j][r] = ((t0 + 32 + kloc) <= qg) ? sfB[r] * __expf(atvB - ma_q) : 0.f;
            }
        }

        {
            float tsA = djA[0][0] + djA[0][1] + djA[0][2] + djA[0][3]
                      + djA[1][0] + djA[1][1] + djA[1][2] + djA[1][3];
            tsA += __shfl_xor(tsA, 16);
            tsA += __shfl_xor(tsA, 32);
            b_run += tsA;
            float tsB = djB[0][0] + djB[0][1] + djB[0][2] + djB[0][3]
                      + djB[1][0] + djB[1][1] + djB[1][2] + djB[1][3];
            tsB += __shfl_xor(tsB, 16);
            tsB += __shfl_xor(tsB, 32);
            b_run += tsB;
        }

        const int srlo = 32 * ((lane >> 4) & 1) + fr;
        {
            float p8[8];
#pragma unroll
            for (int e = 0; e < 8; e++) {
                const int sl = srlo + ((e >= 4) ? 16 : 0);
                const float v0 = __shfl(djA[0][e & 3], sl);
                const float v1 = __shfl(djA[1][e & 3], sl);
                p8[e] = (lane & 32) ? v1 : v0;
            }
            us8 phu, plu;
#pragma unroll
            for (int e = 0; e < 8; e++) {
                unsigned short hh = f2bf(p8[e]);
                phu[e] = hh;
                plu[e] = f2bf(p8[e] - bf2f(hh));
            }
            const bf16x8 pfh = __builtin_bit_cast(bf16x8, phu);
            const bf16x8 pfl = __builtin_bit_cast(bf16x8, plu);
            __builtin_amdgcn_s_setprio(1);
#pragma unroll
            for (int jb = 0; jb < 8; jb++) {
                bf16x8 vfh = __builtin_bit_cast(bf16x8, *(const us8*)&Vlh[0][(jb * 16 + fr) * 40 + fg * 8]);
                bf16x8 vfl = __builtin_bit_cast(bf16x8, *(const us8*)&Vll[0][(jb * 16 + fr) * 40 + fg * 8]);
                acc[jb] = mfma16(vfh, pfh, acc[jb]);
                acc[jb] = mfma16(vfh, pfl, acc[jb]);
                acc[jb] = mfma16(vfl, pfh, acc[jb]);
            }
            __builtin_amdgcn_s_setprio(0);
        }
        {
            float p8[8];
#pragma unroll
            for (int e = 0; e < 8; e++) {
                const int sl = srlo + ((e >= 4) ? 16 : 0);
                const float v0 = __shfl(djB[0][e & 3], sl);
                const float v1 = __shfl(djB[1][e & 3], sl);
                p8[e] = (lane & 32) ? v1 : v0;
            }
            us8 phu, plu;
#pragma unroll
            for (int e = 0; e < 8; e++) {
                unsigned short hh = f2bf(p8[e]);
                phu[e] = hh;
                plu[e] = f2bf(p8[e] - bf2f(hh));
            }
            const bf16x8 pfh = __builtin_bit_cast(bf16x8, phu);
            const bf16x8 pfl = __builtin_bit_cast(bf16x8, plu);
            __builtin_amdgcn_s_setprio(1);
#pragma unroll
            for (int jb = 0; jb < 8; jb++) {
                bf16x8 vfh = __builtin_bit_cast(bf16x8, *(const us8*)&Vlh[1][(jb * 16 + fr) * 40 + fg * 8]);
                bf16x8 vfl = __builtin_bit_cast(bf16x8, *(const us8*)&Vll[1][(jb * 16 + fr) * 40 + fg * 8]);
                acc[jb] = mfma16(vfh, pfh, acc[jb]);
                acc[jb] = mfma16(vfh, pfl, acc[jb]);
                acc[jb] = mfma16(vfl, pfh, acc[jb]);
            }
            __builtin_amdgcn_s_setprio(0);
        }

        kt += 2;
        if (kt >= nt) break;
        __syncthreads();
        STOREPAIR();
        if (kt + 2 < nt) LOADPAIR((kt + 2) * 32);
        __syncthreads();
    }
#undef LOADPAIR
#undef STOREPAIR

    const float cs_q = csum[(size_t)bh * 2048 + qg];
    const float nf = __expf(-(cs_q + ma_q));
    const float n = fmaxf(fabsf(b_run), nf);
    const float inv = 1.f / (n + 1e-6f);
#pragma unroll
    for (int jb = 0; jb < 8; jb++) acc[jb] *= inv;

    float s1 = 0.f;
#pragma unroll
    for (int jb = 0; jb < 8; jb++) s1 += acc[jb][0] + acc[jb][1] + acc[jb][2] + acc[jb][3];
    s1 += __shfl_xor(s1, 16);
    s1 += __shfl_xor(s1, 32);
    const float mu = s1 * (1.f / 128.f);
    float vv = 0.f;
#pragma unroll
    for (int jb = 0; jb < 8; jb++)
#pragma unroll
        for (int e = 0; e < 4; e++) {
            float d = acc[jb][e] - mu;
            vv += d * d;
        }
    vv += __shfl_xor(vv, 16);
    vv += __shfl_xor(vv, 32);
    const float rstd = rsqrtf(vv * (1.f / 128.f) + 1e-6f);

    const size_t obase = (size_t)(b * 2048 + qg) * 2304 + 1280 + h * 128 + fg * 4;
    const size_t hbase = (size_t)(b * 2048 + qg) * 1024 + h * 128 + fg * 4;
#pragma unroll
    for (int jb = 0; jb < 8; jb++) {
        us4 ogh = *(const us4*)(projh + obase + jb * 16);
        us4 ogl = *(const us4*)(projl + obase + jb * 16);
        f32x4 lw = *(const f32x4*)&lnw[h * 128 + jb * 16 + fg * 4];
        us4 hi4, lo4;
#pragma unroll
        for (int e = 0; e < 4; e++) {
            const float og = bf2f(ogh[e]) + bf2f(ogl[e]);
            const float sig = 1.f / (1.f + __expf(-og));
            const float ho = (acc[jb][e] - mu) * rstd * lw[e] * sig;
            unsigned short h1 = f2bf(ho);
            hi4[e] = h1;
            lo4[e] = f2bf(ho - bf2f(h1));
        }
        *(us4*)&ho_hi[hbase + jb * 16] = hi4;
        *(us4*)&ho_lo[hbase + jb * 16] = lo4;
    }
}

// ---------------------------------------------------------------------------
extern "C" void kernel_launch(void* const* d_in, const int* in_sizes, int n_in,
                              void* d_out, int out_size, void* d_ws, size_t ws_size,
                              hipStream_t stream) {
    (void)in_sizes; (void)n_in; (void)out_size; (void)ws_size;
    const float* x    = (const float*)d_in[0];
    const float* Wq   = (const float*)d_in[1];
    const float* Wk   = (const float*)d_in[2];
    const float* Wv   = (const float*)d_in[3];
    const float* Wog  = (const float*)d_in[4];
    const float* Wi   = (const float*)d_in[5];
    const float* bi   = (const float*)d_in[6];
    const float* Wf   = (const float*)d_in[7];
    const float* bfb  = (const float*)d_in[8];
    const float* lnw  = (const float*)d_in[9];
    const float* Wout = (const float*)d_in[10];

    char* p = (char*)d_ws;
    auto carve = [&](size_t bytes) -> char* {
        char* r = p;
        p += (bytes + 255) & ~(size_t)255;
        return r;
    };
    unsigned short* x_hi   = (unsigned short*)carve(4194304ull * 2);
    unsigned short* x_lo   = (unsigned short*)carve(4194304ull * 2);
    unsigned short* wc_hi  = (unsigned short*)carve(2359296ull * 2);
    unsigned short* wc_lo  = (unsigned short*)carve(2359296ull * 2);
    unsigned short* wo_hi  = (unsigned short*)carve(1048576ull * 2);
    unsigned short* wo_lo  = (unsigned short*)carve(1048576ull * 2);
    unsigned short* pr_hi  = (unsigned short*)carve(4096ull * 2304 * 2);
    unsigned short* pr_lo  = (unsigned short*)carve(4096ull * 2304 * 2);
    unsigned short* vT_hi  = (unsigned short*)carve(524288ull * 2);
    unsigned short* vT_lo  = (unsigned short*)carve(524288ull * 2);
    float* ipre    = (float*)carve(32768ull * 4);
    float* lgf_buf = (float*)carve(32768ull * 4);
    float* csum    = (float*)carve(32768ull * 4);
    float* aarr    = (float*)carve(32768ull * 4);
    float* marr    = (float*)carve(32768ull * 4);
    unsigned short* ho_hi = x_hi;   // x dead after proj GEMM
    unsigned short* ho_lo = x_lo;

    prep<<<7424, 256, 0, stream>>>(x, Wq, Wk, Wv, Wog, Wout,
                                   x_hi, x_lo, wc_hi, wc_lo, wo_hi, wo_lo);
    gates_kernel<<<4096, 256, 0, stream>>>(x, Wi, bi, Wf, bfb, ipre, lgf_buf);
    scan_kernel<<<16, 64, 0, stream>>>(ipre, lgf_buf, csum, aarr, marr);
    gemm_bt3<<<dim3(32, 18), 256, 0, stream>>>(x_hi, x_lo, wc_hi, wc_lo, pr_hi, pr_lo, 1024, 2304, 1, 10);
    make_vt<<<128, 256, 0, stream>>>(pr_hi, pr_lo, vT_hi, vT_lo);
    attn_fused<<<512, 256, 0, stream>>>(pr_hi, pr_lo, vT_hi, vT_lo, aarr, marr, csum, lnw, ho_hi, ho_lo);
    gemm_bt3<<<dim3(32, 8), 256, 0, stream>>>(ho_hi, ho_lo, wo_hi, wo_lo, d_out, nullptr, 1024, 1024, 0, 1000);
}

// Round 21
// 319.138 us; speedup vs baseline: 1.3352x; 1.0140x over previous
//
#include <hip/hip_runtime.h>

// ---------------------------------------------------------------------------
// mLSTM block, MI355X. B=2,S=2048,D=1024,NH=8,DH=128.
// v20 = v19 + GEMM staging via __builtin_amdgcn_global_load_lds (width=16,
//       linear 128x32 LDS tiles, og blocks skip lo-staging). Numerics bitwise
//       identical to v19 (absmax 0.015625).
// ---------------------------------------------------------------------------

typedef __bf16 bf16x8 __attribute__((ext_vector_type(8)));
typedef float f32x4 __attribute__((ext_vector_type(4)));
typedef unsigned short us8 __attribute__((ext_vector_type(8)));
typedef unsigned short us4 __attribute__((ext_vector_type(4)));

__device__ __forceinline__ unsigned short f2bf(float f) {
    unsigned int u = __builtin_bit_cast(unsigned int, f);
    unsigned int r = u + 0x7fffu + ((u >> 16) & 1u);
    return (unsigned short)(r >> 16);
}
__device__ __forceinline__ float bf2f(unsigned short h) {
    unsigned int u = ((unsigned int)h) << 16;
    return __builtin_bit_cast(float, u);
}
__device__ __forceinline__ f32x4 mfma16(bf16x8 a, bf16x8 b, f32x4 c) {
    return __builtin_amdgcn_mfma_f32_16x16x32_bf16(a, b, c, 0, 0, 0);
}
__device__ __forceinline__ void gll16(const unsigned short* gsrc, unsigned short* ldst) {
    __builtin_amdgcn_global_load_lds(
        (__attribute__((address_space(1))) void*)gsrc,
        (__attribute__((address_space(3))) void*)ldst, 16, 0, 0);
}

// ---------------- K0: fused prep — x split, Wcat build, Wout split (float4) --
__global__ __launch_bounds__(256) void prep(const float* __restrict__ x,
                                            const float* __restrict__ Wq,
                                            const float* __restrict__ Wk,
                                            const float* __restrict__ Wv,
                                            const float* __restrict__ Wog,
                                            const float* __restrict__ Wout,
                                            unsigned short* __restrict__ x_hi,
                                            unsigned short* __restrict__ x_lo,
                                            unsigned short* __restrict__ wc_hi,
                                            unsigned short* __restrict__ wc_lo,
                                            unsigned short* __restrict__ wo_hi,
                                            unsigned short* __restrict__ wo_lo) {
    const int id = blockIdx.x * 256 + threadIdx.x;
    f32x4 v;
    unsigned short* dh;
    unsigned short* dl;
    size_t off;
    if (id < 1048576) {
        off = (size_t)id * 4;
        v = *(const f32x4*)(x + off);
        dh = x_hi; dl = x_lo;
    } else if (id < 1048576 + 589824) {
        const int e = id - 1048576;
        const int row = e >> 8;
        const int col = (e & 255) * 4;
        off = (size_t)row * 1024 + col;
        if (row < 1024) {
            v = *(const f32x4*)(Wq + off);
#pragma unroll
            for (int t = 0; t < 4; t++) v[t] *= 0.08838834764831845f;
        } else if (row < 1152) {
            v = *(const f32x4*)(Wk + (size_t)(row - 1024) * 1024 + col);
        } else if (row < 1280) {
            v = *(const f32x4*)(Wv + (size_t)(row - 1152) * 1024 + col);
        } else {
            v = *(const f32x4*)(Wog + (size_t)(row - 1280) * 1024 + col);
        }
        dh = wc_hi; dl = wc_lo;
    } else {
        const int e = id - 1048576 - 589824;
        if (e >= 262144) return;
        off = (size_t)e * 4;
        v = *(const f32x4*)(Wout + off);
        dh = wo_hi; dl = wo_lo;
    }
    us4 h4, l4;
#pragma unroll
    for (int t = 0; t < 4; t++) {
        unsigned short hh = f2bf(v[t]);
        h4[t] = hh;
        l4[t] = f2bf(v[t] - bf2f(hh));
    }
    *(us4*)(dh + off) = h4;
    *(us4*)(dl + off) = l4;
}

// ---------------- K1: gates ----------------
__global__ __launch_bounds__(256) void gates_kernel(const float* __restrict__ x,
                                                    const float* __restrict__ Wi,
                                                    const float* __restrict__ bi,
                                                    const float* __restrict__ Wf,
                                                    const float* __restrict__ bfb,
                                                    float* __restrict__ ipre,
                                                    float* __restrict__ lgf) {
    int bs = blockIdx.x;
    int b = bs >> 11, s = bs & 2047;
    const float* xr = x + (size_t)bs * 1024;
    int lane = threadIdx.x & 63, w = threadIdx.x >> 6;
    const float* W = (w < 2) ? Wi : Wf;
    int h0 = (w & 1) * 4;
    float dot0 = 0.f, dot1 = 0.f, dot2 = 0.f, dot3 = 0.f;
    for (int i = lane; i < 1024; i += 64) {
        float xv = xr[i];
        dot0 += xv * W[(size_t)(h0 + 0) * 1024 + i];
        dot1 += xv * W[(size_t)(h0 + 1) * 1024 + i];
        dot2 += xv * W[(size_t)(h0 + 2) * 1024 + i];
        dot3 += xv * W[(size_t)(h0 + 3) * 1024 + i];
    }
#pragma unroll
    for (int o = 32; o; o >>= 1) {
        dot0 += __shfl_xor(dot0, o);
        dot1 += __shfl_xor(dot1, o);
        dot2 += __shfl_xor(dot2, o);
        dot3 += __shfl_xor(dot3, o);
    }
    if (lane == 0) {
        float d[4] = {dot0, dot1, dot2, dot3};
#pragma unroll
        for (int j = 0; j < 4; j++) {
            int hh = h0 + j;
            if (w < 2) {
                float z = d[j] + bi[hh];
                z = 15.f * tanhf(z * (1.f / 15.f));
                ipre[((size_t)b * 8 + hh) * 2048 + s] = z;
            } else {
                float z = d[j] + bfb[hh];
                z = 15.f * tanhf(z * (1.f / 15.f));
                lgf[((size_t)b * 8 + hh) * 2048 + s] = fminf(z, 0.f) - log1pf(expf(-fabsf(z)));
            }
        }
    }
}

// ---------------- K2: scan ----------------
__global__ void scan_kernel(const float* __restrict__ ipre, const float* __restrict__ lgf,
                            float* __restrict__ csum, float* __restrict__ aarr,
                            float* __restrict__ marr) {
    int bh = blockIdx.x;
    int lane = threadIdx.x;
    const float* lf = lgf + (size_t)bh * 2048;
    const float* ip = ipre + (size_t)bh * 2048;
    float* cs = csum + (size_t)bh * 2048;
    float* aa = aarr + (size_t)bh * 2048;
    float* mm = marr + (size_t)bh * 2048;
    float carry = 0.f;
    float carrym = -1e30f;
    for (int c = 0; c < 32; c++) {
        float v = lf[c * 64 + lane];
#pragma unroll
        for (int o = 1; o < 64; o <<= 1) {
            float t = __shfl_up(v, o);
            if (lane >= o) v += t;
        }
        float cval = carry + v;
        cs[c * 64 + lane] = cval;
        float a = ip[c * 64 + lane] - cval;
        aa[c * 64 + lane] = a;
        float mv = a;
#pragma unroll
        for (int o = 1; o < 64; o <<= 1) {
            float t = __shfl_up(mv, o);
            if (lane >= o) mv = fmaxf(mv, t);
        }
        float mval = fmaxf(carrym, mv);
        mm[c * 64 + lane] = mval;
        carry = __shfl(cval, 63);
        carrym = __shfl(mval, 63);
    }
}

// ---- K3/K6: 3-product GEMM, 128x128 tile, global_load_lds staging (linear
//      [128][32] LDS tiles); og rows (blockIdx.y>=og_y0) 1-product, skip lo ----
__global__ __launch_bounds__(256) void gemm_bt3(const unsigned short* __restrict__ Ah,
                                                const unsigned short* __restrict__ Al,
                                                const unsigned short* __restrict__ Bh,
                                                const unsigned short* __restrict__ Bl,
                                                void* __restrict__ Cp,
                                                unsigned short* __restrict__ Clo,
                                                int K, int ldc, int c_bf16, int og_y0) {
    __shared__ __attribute__((aligned(16))) unsigned short Ash[128 * 32];
    __shared__ __attribute__((aligned(16))) unsigned short Asl[128 * 32];
    __shared__ __attribute__((aligned(16))) unsigned short Bsh[128 * 32];
    __shared__ __attribute__((aligned(16))) unsigned short Bsl[128 * 32];
    const int tid = threadIdx.x;
    const int lane = tid & 63, wv = tid >> 6;
    const int wr = wv >> 1, wc = wv & 1;
    const int fr = lane & 15, fg = lane >> 4;
    const bool full3 = (blockIdx.y < (unsigned)og_y0);
    // staging: thread t, chunk c loads global row (t>>2)+64c, col 8*(t&3)
    const int sr = tid >> 2, sc = (tid & 3) * 8;
    const size_t abase = (size_t)(blockIdx.x * 128 + sr) * K + sc;
    const size_t bbase = (size_t)(blockIdx.y * 128 + sr) * K + sc;
    const size_t rstep = 64ull * K;           // +64 rows for chunk 1
    unsigned short* a0 = &Ash[tid * 8];
    unsigned short* a1 = &Ash[2048 + tid * 8];
    unsigned short* l0 = &Asl[tid * 8];
    unsigned short* l1 = &Asl[2048 + tid * 8];
    unsigned short* b0 = &Bsh[tid * 8];
    unsigned short* b1 = &Bsh[2048 + tid * 8];
    unsigned short* m0 = &Bsl[tid * 8];
    unsigned short* m1 = &Bsl[2048 + tid * 8];
#define GLL(KT)                                                                \
    {                                                                          \
        gll16(Ah + abase + (KT), a0);                                          \
        gll16(Ah + abase + rstep + (KT), a1);                                  \
        gll16(Bh + bbase + (KT), b0);                                          \
        gll16(Bh + bbase + rstep + (KT), b1);                                  \
        if (full3) {                                                           \
            gll16(Al + abase + (KT), l0);                                      \
            gll16(Al + abase + rstep + (KT), l1);                              \
            gll16(Bl + bbase + (KT), m0);                                      \
            gll16(Bl + bbase + rstep + (KT), m1);                              \
        }                                                                      \
    }
    f32x4 acc[4][4] = {};
    GLL(0);
    for (int kt = 0; kt < K; kt += 32) {
        __syncthreads();   // drains vmcnt -> staged tile visible to all waves
        bf16x8 bfh[4], bfl[4];
#pragma unroll
        for (int j = 0; j < 4; j++) {
            bfh[j] = __builtin_bit_cast(bf16x8, *(const us8*)&Bsh[(64 * wc + 16 * j + fr) * 32 + fg * 8]);
            bfl[j] = __builtin_bit_cast(bf16x8, *(const us8*)&Bsl[(64 * wc + 16 * j + fr) * 32 + fg * 8]);
        }
        __builtin_amdgcn_s_setprio(1);
        if (full3) {
#pragma unroll
            for (int i = 0; i < 4; i++) {
                bf16x8 afh = __builtin_bit_cast(bf16x8, *(const us8*)&Ash[(64 * wr + 16 * i + fr) * 32 + fg * 8]);
                bf16x8 afl = __builtin_bit_cast(bf16x8, *(const us8*)&Asl[(64 * wr + 16 * i + fr) * 32 + fg * 8]);
#pragma unroll
                for (int j = 0; j < 4; j++) {
                    acc[i][j] = mfma16(afh, bfh[j], acc[i][j]);
                    acc[i][j] = mfma16(afh, bfl[j], acc[i][j]);
                    acc[i][j] = mfma16(afl, bfh[j], acc[i][j]);
                }
            }
        } else {
#pragma unroll
            for (int i = 0; i < 4; i++) {
                bf16x8 afh = __builtin_bit_cast(bf16x8, *(const us8*)&Ash[(64 * wr + 16 * i + fr) * 32 + fg * 8]);
#pragma unroll
                for (int j = 0; j < 4; j++)
                    acc[i][j] = mfma16(afh, bfh[j], acc[i][j]);
            }
        }
        __builtin_amdgcn_s_setprio(0);
        if (kt + 32 < K) {
            __syncthreads();               // all waves done reading this tile
            GLL(kt + 32);                  // async stage next tile
        }
    }
#undef GLL
#pragma unroll
    for (int i = 0; i < 4; i++)
#pragma unroll
        for (int j = 0; j < 4; j++)
#pragma unroll
            for (int e = 0; e < 4; e++) {
                int r = blockIdx.x * 128 + 64 * wr + 16 * i + fg * 4 + e;
                int c = blockIdx.y * 128 + 64 * wc + 16 * j + fr;
                float v = acc[i][j][e];
                if (c_bf16) {
                    unsigned short h = f2bf(v);
                    ((unsigned short*)Cp)[(size_t)r * ldc + c] = h;
                    Clo[(size_t)r * ldc + c] = f2bf(v - bf2f(h));
                } else {
                    ((float*)Cp)[(size_t)r * ldc + c] = v;
                }
            }
}

// ---------------- K4: vT via coalesced LDS-tiled transpose ----------------
__global__ __launch_bounds__(256) void make_vt(const unsigned short* __restrict__ ph,
                                               const unsigned short* __restrict__ pl,
                                               unsigned short* __restrict__ vTh,
                                               unsigned short* __restrict__ vTl) {
    __shared__ __attribute__((aligned(16))) unsigned short th[64 * 68];
    __shared__ __attribute__((aligned(16))) unsigned short tl[64 * 68];
    const int bid = blockIdx.x;
    const int st = bid & 31, ct = (bid >> 5) & 1, b = bid >> 6;
    const int tid = threadIdx.x;
    {
        const int sr = tid >> 2, cc = (tid & 3) * 16;
        const size_t rbase = (size_t)(b * 2048 + st * 64 + sr) * 2304 + 1152 + ct * 64 + cc;
        us8 a0 = *(const us8*)(ph + rbase);
        us8 a1 = *(const us8*)(ph + rbase + 8);
        us8 c0 = *(const us8*)(pl + rbase);
        us8 c1 = *(const us8*)(pl + rbase + 8);
        *(us8*)&th[sr * 68 + cc] = a0;
        *(us8*)&th[sr * 68 + cc + 8] = a1;
        *(us8*)&tl[sr * 68 + cc] = c0;
        *(us8*)&tl[sr * 68 + cc + 8] = c1;
    }
    __syncthreads();
    {
        const int cr = tid >> 2, ss = (tid & 3) * 16;
        us8 oh0, oh1, ol0, ol1;
#pragma unroll
        for (int e = 0; e < 8; e++) {
            oh0[e] = th[(ss + e) * 68 + cr];
            oh1[e] = th[(ss + 8 + e) * 68 + cr];
            ol0[e] = tl[(ss + e) * 68 + cr];
            ol1[e] = tl[(ss + 8 + e) * 68 + cr];
        }
        const size_t wbase = (size_t)b * 128 * 2048 + (size_t)(ct * 64 + cr) * 2048 + st * 64 + ss;
        *(us8*)&vTh[wbase] = oh0;
        *(us8*)&vTh[wbase + 8] = oh1;
        *(us8*)&vTl[wbase] = ol0;
        *(us8*)&vTl[wbase + 8] = ol1;
    }
}

// ---------------- K5: fused attn — dbuf pair, K-loop unrolled x2 ------------
__global__ __launch_bounds__(256, 2) void attn_fused(const unsigned short* __restrict__ projh,
                                                     const unsigned short* __restrict__ projl,
                                                     const unsigned short* __restrict__ vTh,
                                                     const unsigned short* __restrict__ vTl,
                                                     const float* __restrict__ aarr,
                                                     const float* __restrict__ marr,
                                                     const float* __restrict__ csum,
                                                     const float* __restrict__ lnw,
                                                     unsigned short* __restrict__ ho_hi,
                                                     unsigned short* __restrict__ ho_lo) {
    __shared__ __attribute__((aligned(16))) unsigned short Klh[2][32 * 148];
    __shared__ __attribute__((aligned(16))) unsigned short Kll[2][32 * 148];
    __shared__ __attribute__((aligned(16))) unsigned short Vlh[2][128 * 40];
    __shared__ __attribute__((aligned(16))) unsigned short Vll[2][128 * 40];
    __shared__ float al[2][32];

    const int idx = blockIdx.x;
    const int half = idx >> 8;
    const int pid = idx & 255;
    const int bh = pid & 15;
    const int qt0 = pid >> 4;
    const int qt = half ? (31 - qt0) : qt0;
    const int b = bh >> 3, h = bh & 7;
    const int tid = threadIdx.x, lane = tid & 63, w = tid >> 6;
    const int fr = lane & 15, fg = lane >> 4;
    const int q0 = qt * 64;
    const int qg = q0 + 16 * w + fr;

    bf16x8 qfh[4], qfl[4];
    {
        const size_t qoff = (size_t)(b * 2048 + qg) * 2304 + h * 128;
#pragma unroll
        for (int ks = 0; ks < 4; ks++) {
            qfh[ks] = __builtin_bit_cast(bf16x8, *(const us8*)(projh + qoff + ks * 32 + fg * 8));
            qfl[ks] = __builtin_bit_cast(bf16x8, *(const us8*)(projl + qoff + ks * 32 + fg * 8));
        }
    }
    const float ma_q = marr[(size_t)bh * 2048 + qg];

    f32x4 acc[8] = {};
    float b_run = 0.f;

    const int kr = tid >> 3, kc = (tid & 7) * 16;
    const int vr = tid >> 1, vc = (tid & 1) * 16;
    const size_t kbase = (size_t)(b * 2048) * 2304 + 1024;
    const size_t vtbase = (size_t)b * 128 * 2048;

    const int nt = 2 * qt + 2;   // always even
    us8 kh0A, kh1A, kl0A, kl1A, vh0A, vh1A, vl0A, vl1A;
    us8 kh0B, kh1B, kl0B, kl1B, vh0B, vh1B, vl0B, vl1B;
    float a_stA, a_stB;
#define LOADPAIR(T0)                                                           \
    {                                                                          \
        const size_t koA = kbase + (size_t)((T0) + kr) * 2304 + kc;            \
        const size_t voA = vtbase + (size_t)vr * 2048 + (T0) + vc;             \
        kh0A = *(const us8*)(projh + koA);                                     \
        kh1A = *(const us8*)(projh + koA + 8);                                 \
        kl0A = *(const us8*)(projl + koA);                                     \
        kl1A = *(const us8*)(projl + koA + 8);                                 \
        vh0A = *(const us8*)(vTh + voA);                                       \
        vh1A = *(const us8*)(vTh + voA + 8);                                   \
        vl0A = *(const us8*)(vTl + voA);                                       \
        vl1A = *(const us8*)(vTl + voA + 8);                                   \
        a_stA = (tid < 32) ? aarr[(size_t)bh * 2048 + (T0) + tid] : 0.f;       \
        const size_t koB = koA + 32ull * 2304;                                 \
        const size_t voB = voA + 32;                                           \
        kh0B = *(const us8*)(projh + koB);                                     \
        kh1B = *(const us8*)(projh + koB + 8);                                 \
        kl0B = *(const us8*)(projl + koB);                                     \
        kl1B = *(const us8*)(projl + koB + 8);                                 \
        vh0B = *(const us8*)(vTh + voB);                                       \
        vh1B = *(const us8*)(vTh + voB + 8);                                   \
        vl0B = *(const us8*)(vTl + voB);                                       \
        vl1B = *(const us8*)(vTl + voB + 8);                                   \
        a_stB = (tid < 32) ? aarr[(size_t)bh * 2048 + (T0) + 32 + tid] : 0.f;  \
    }
#define STOREPAIR()                                                            \
    {                                                                          \
        *(us8*)&Klh[0][kr * 148 + kc] = kh0A;                                  \
        *(us8*)&Klh[0][kr * 148 + kc + 8] = kh1A;                              \
        *(us8*)&Kll[0][kr * 148 + kc] = kl0A;                                  \
        *(us8*)&Kll[0][kr * 148 + kc + 8] = kl1A;                              \
        *(us8*)&Vlh[0][vr * 40 + vc] = vh0A;                                   \
        *(us8*)&Vlh[0][vr * 40 + vc + 8] = vh1A;                               \
        *(us8*)&Vll[0][vr * 40 + vc] = vl0A;                                   \
        *(us8*)&Vll[0][vr * 40 + vc + 8] = vl1A;                               \
        *(us8*)&Klh[1][kr * 148 + kc] = kh0B;                                  \
        *(us8*)&Klh[1][kr * 148 + kc + 8] = kh1B;                              \
        *(us8*)&Kll[1][kr * 148 + kc] = kl0B;                                  \
        *(us8*)&Kll[1][kr * 148 + kc + 8] = kl1B;                              \
        *(us8*)&Vlh[1][vr * 40 + vc] = vh0B;                                   \
        *(us8*)&Vlh[1][vr * 40 + vc + 8] = vh1B;                               \
        *(us8*)&Vll[1][vr * 40 + vc] = vl0B;                                   \
        *(us8*)&Vll[1][vr * 40 + vc + 8] = vl1B;                               \
        if (tid < 32) {                                                        \
            al[0][tid] = a_stA;                                                \
            al[1][tid] = a_stB;                                                \
        }                                                                      \
    }

    LOADPAIR(0);
    STOREPAIR();
    if (nt > 2) LOADPAIR(64);
    __syncthreads();

    for (int kt = 0;;) {
        const int t0 = kt * 32;

        float djA[2][4], djB[2][4];
#pragma unroll
        for (int j = 0; j < 2; j++) {
            f32x4 sfaA = {}, sfbA = {}, sfcA = {};
            f32x4 sfaB = {}, sfbB = {}, sfcB = {};
            __builtin_amdgcn_s_setprio(1);
#pragma unroll
            for (int ks = 0; ks < 4; ks++) {
                bf16x8 kfhA = __builtin_bit_cast(bf16x8, *(const us8*)&Klh[0][(j * 16 + fr) * 148 + ks * 32 + fg * 8]);
                bf16x8 kflA = __builtin_bit_cast(bf16x8, *(const us8*)&Kll[0][(j * 16 + fr) * 148 + ks * 32 + fg * 8]);
                bf16x8 kfhB = __builtin_bit_cast(bf16x8, *(const us8*)&Klh[1][(j * 16 + fr) * 148 + ks * 32 + fg * 8]);
                bf16x8 kflB = __builtin_bit_cast(bf16x8, *(const us8*)&Kll[1][(j * 16 + fr) * 148 + ks * 32 + fg * 8]);
                sfaA = mfma16(kfhA, qfh[ks], sfaA);
                sfaB = mfma16(kfhB, qfh[ks], sfaB);
                sfbA = mfma16(kfhA, qfl[ks], sfbA);
                sfbB = mfma16(kfhB, qfl[ks], sfbB);
                sfcA = mfma16(kflA, qfh[ks], sfcA);
                sfcB = mfma16(kflB, qfh[ks], sfcB);
            }
            __builtin_amdgcn_s_setprio(0);
            f32x4 sfA = (sfaA + sfbA) + sfcA;
            f32x4 sfB = (sfaB + sfbB) + sfcB;
#pragma unroll
            for (int r = 0; r < 4; r++) {
                const int kloc = j * 16 + fg * 4 + r;
                const float atvA = al[0][kloc];
                const float atvB = al[1][kloc];
                djA[j][r] = ((t0 + kloc) <= qg) ? sfA[r] * __expf(atvA - ma_q) : 0.f;
                djB[j][r] = ((t0 + 32 + kloc) <= qg) ? sfB[r] * __expf(atvB - ma_q) : 0.f;
            }
        }

        {
            float tsA = djA[0][0] + djA[0][1] + djA[0][2] + djA[0][3]
                      + djA[1][0] + djA[1][1] + djA[1][2] + djA[1][3];
            tsA += __shfl_xor(tsA, 16);
            tsA += __shfl_xor(tsA, 32);
            b_run += tsA;
            float tsB = djB[0][0] + djB[0][1] + djB[0][2] + djB[0][3]
                      + djB[1][0] + djB[1][1] + djB[1][2] + djB[1][3];
            tsB += __shfl_xor(tsB, 16);
            tsB += __shfl_xor(tsB, 32);
            b_run += tsB;
        }

        const int srlo = 32 * ((lane >> 4) & 1) + fr;
        {
            float p8[8];
#pragma unroll
            for (int e = 0; e < 8; e++) {
                const int sl = srlo + ((e >= 4) ? 16 : 0);
                const float v0 = __shfl(djA[0][e & 3], sl);
                const float v1 = __shfl(djA[1][e & 3], sl);
                p8[e] = (lane & 32) ? v1 : v0;
            }
            us8 phu, plu;
#pragma unroll
            for (int e = 0; e < 8; e++) {
                unsigned short hh = f2bf(p8[e]);
                phu[e] = hh;
                plu[e] = f2bf(p8[e] - bf2f(hh));
            }
            const bf16x8 pfh = __builtin_bit_cast(bf16x8, phu);
            const bf16x8 pfl = __builtin_bit_cast(bf16x8, plu);
            __builtin_amdgcn_s_setprio(1);
#pragma unroll
            for (int jb = 0; jb < 8; jb++) {
                bf16x8 vfh = __builtin_bit_cast(bf16x8, *(const us8*)&Vlh[0][(jb * 16 + fr) * 40 + fg * 8]);
                bf16x8 vfl = __builtin_bit_cast(bf16x8, *(const us8*)&Vll[0][(jb * 16 + fr) * 40 + fg * 8]);
                acc[jb] = mfma16(vfh, pfh, acc[jb]);
                acc[jb] = mfma16(vfh, pfl, acc[jb]);
                acc[jb] = mfma16(vfl, pfh, acc[jb]);
            }
            __builtin_amdgcn_s_setprio(0);
        }
        {
            float p8[8];
#pragma unroll
            for (int e = 0; e < 8; e++) {
                const int sl = srlo + ((e >= 4) ? 16 : 0);
                const float v0 = __shfl(djB[0][e & 3], sl);
                const float v1 = __shfl(djB[1][e & 3], sl);
                p8[e] = (lane & 32) ? v1 : v0;
            }
            us8 phu, plu;
#pragma unroll
            for (int e = 0; e < 8; e++) {
                unsigned short hh = f2bf(p8[e]);
                phu[e] = hh;
                plu[e] = f2bf(p8[e] - bf2f(hh));
            }
            const bf16x8 pfh = __builtin_bit_cast(bf16x8, phu);
            const bf16x8 pfl = __builtin_bit_cast(bf16x8, plu);
            __builtin_amdgcn_s_setprio(1);
#pragma unroll
            for (int jb = 0; jb < 8; jb++) {
                bf16x8 vfh = __builtin_bit_cast(bf16x8, *(const us8*)&Vlh[1][(jb * 16 + fr) * 40 + fg * 8]);
                bf16x8 vfl = __builtin_bit_cast(bf16x8, *(const us8*)&Vll[1][(jb * 16 + fr) * 40 + fg * 8]);
                acc[jb] = mfma16(vfh, pfh, acc[jb]);
                acc[jb] = mfma16(vfh, pfl, acc[jb]);
                acc[jb] = mfma16(vfl, pfh, acc[jb]);
            }
            __builtin_amdgcn_s_setprio(0);
        }

        kt += 2;
        if (kt >= nt) break;
        __syncthreads();
        STOREPAIR();
        if (kt + 2 < nt) LOADPAIR((kt + 2) * 32);
        __syncthreads();
    }
#undef LOADPAIR
#undef STOREPAIR

    const float cs_q = csum[(size_t)bh * 2048 + qg];
    const float nf = __expf(-(cs_q + ma_q));
    const float n = fmaxf(fabsf(b_run), nf);
    const float inv = 1.f / (n + 1e-6f);
#pragma unroll
    for (int jb = 0; jb < 8; jb++) acc[jb] *= inv;

    float s1 = 0.f;
#pragma unroll
    for (int jb = 0; jb < 8; jb++) s1 += acc[jb][0] + acc[jb][1] + acc[jb][2] + acc[jb][3];
    s1 += __shfl_xor(s1, 16);
    s1 += __shfl_xor(s1, 32);
    const float mu = s1 * (1.f / 128.f);
    float vv = 0.f;
#pragma unroll
    for (int jb = 0; jb < 8; jb++)
#pragma unroll
        for (int e = 0; e < 4; e++) {
            float d = acc[jb][e] - mu;
            vv += d * d;
        }
    vv += __shfl_xor(vv, 16);
    vv += __shfl_xor(vv, 32);
    const float rstd = rsqrtf(vv * (1.f / 128.f) + 1e-6f);

    const size_t obase = (size_t)(b * 2048 + qg) * 2304 + 1280 + h * 128 + fg * 4;
    const size_t hbase = (size_t)(b * 2048 + qg) * 1024 + h * 128 + fg * 4;
#pragma unroll
    for (int jb = 0; jb < 8; jb++) {
        us4 ogh = *(const us4*)(projh + obase + jb * 16);
        us4 ogl = *(const us4*)(projl + obase + jb * 16);
        f32x4 lw = *(const f32x4*)&lnw[h * 128 + jb * 16 + fg * 4];
        us4 hi4, lo4;
#pragma unroll
        for (int e = 0; e < 4; e++) {
            const float og = bf2f(ogh[e]) + bf2f(ogl[e]);
            const float sig = 1.f / (1.f + __expf(-og));
            const float ho = (acc[jb][e] - mu) * rstd * lw[e] * sig;
            unsigned short h1 = f2bf(ho);
            hi4[e] = h1;
            lo4[e] = f2bf(ho - bf2f(h1));
        }
        *(us4*)&ho_hi[hbase + jb * 16] = hi4;
        *(us4*)&ho_lo[hbase + jb * 16] = lo4;
    }
}

// ---------------------------------------------------------------------------
extern "C" void kernel_launch(void* const* d_in, const int* in_sizes, int n_in,
                              void* d_out, int out_size, void* d_ws, size_t ws_size,
                              hipStream_t stream) {
    (void)in_sizes; (void)n_in; (void)out_size; (void)ws_size;
    const float* x    = (const float*)d_in[0];
    const float* Wq   = (const float*)d_in[1];
    const float* Wk   = (const float*)d_in[2];
    const float* Wv   = (const float*)d_in[3];
    const float* Wog  = (const float*)d_in[4];
    const float* Wi   = (const float*)d_in[5];
    const float* bi   = (const float*)d_in[6];
    const float* Wf   = (const float*)d_in[7];
    const float* bfb  = (const float*)d_in[8];
    const float* lnw  = (const float*)d_in[9];
    const float* Wout = (const float*)d_in[10];

    char* p = (char*)d_ws;
    auto carve = [&](size_t bytes) -> char* {
        char* r = p;
        p += (bytes + 255) & ~(size_t)255;
        return r;
    };
    unsigned short* x_hi   = (unsigned short*)carve(4194304ull * 2);
    unsigned short* x_lo   = (unsigned short*)carve(4194304ull * 2);
    unsigned short* wc_hi  = (unsigned short*)carve(2359296ull * 2);
    unsigned short* wc_lo  = (unsigned short*)carve(2359296ull * 2);
    unsigned short* wo_hi  = (unsigned short*)carve(1048576ull * 2);
    unsigned short* wo_lo  = (unsigned short*)carve(1048576ull * 2);
    unsigned short* pr_hi  = (unsigned short*)carve(4096ull * 2304 * 2);
    unsigned short* pr_lo  = (unsigned short*)carve(4096ull * 2304 * 2);
    unsigned short* vT_hi  = (unsigned short*)carve(524288ull * 2);
    unsigned short* vT_lo  = (unsigned short*)carve(524288ull * 2);
    float* ipre    = (float*)carve(32768ull * 4);
    float* lgf_buf = (float*)carve(32768ull * 4);
    float* csum    = (float*)carve(32768ull * 4);
    float* aarr    = (float*)carve(32768ull * 4);
    float* marr    = (float*)carve(32768ull * 4);
    unsigned short* ho_hi = x_hi;   // x dead after proj GEMM
    unsigned short* ho_lo = x_lo;

    prep<<<7424, 256, 0, stream>>>(x, Wq, Wk, Wv, Wog, Wout,
                                   x_hi, x_lo, wc_hi, wc_lo, wo_hi, wo_lo);
    gates_kernel<<<4096, 256, 0, stream>>>(x, Wi, bi, Wf, bfb, ipre, lgf_buf);
    scan_kernel<<<16, 64, 0, stream>>>(ipre, lgf_buf, csum, aarr, marr);
    gemm_bt3<<<dim3(32, 18), 256, 0, stream>>>(x_hi, x_lo, wc_hi, wc_lo, pr_hi, pr_lo, 1024, 2304, 1, 10);
    make_vt<<<128, 256, 0, stream>>>(pr_hi, pr_lo, vT_hi, vT_lo);
    attn_fused<<<512, 256, 0, stream>>>(pr_hi, pr_lo, vT_hi, vT_lo, aarr, marr, csum, lnw, ho_hi, ho_lo);
    gemm_bt3<<<dim3(32, 8), 256, 0, stream>>>(ho_hi, ho_lo, wo_hi, wo_lo, d_out, nullptr, 1024, 1024, 0, 1000);
}

// Round 22
// 305.880 us; speedup vs baseline: 1.3931x; 1.0433x over previous
//
#include <hip/hip_runtime.h>

// ---------------------------------------------------------------------------
// mLSTM block, MI355X. B=2,S=2048,D=1024,NH=8,DH=128.
// v21 = v20 with attn K/V consumed at plain bf16 (drop kl/vl cross-products):
//       QK = kh*(qh+ql), PV = vh*(ph+pl). LDS 39.5KB -> 3-4 blocks/CU,
//       staging halved, chains 1/3 shorter. Est. absmax ~0.02 (thr 0.0616).
// ---------------------------------------------------------------------------

typedef __bf16 bf16x8 __attribute__((ext_vector_type(8)));
typedef float f32x4 __attribute__((ext_vector_type(4)));
typedef unsigned short us8 __attribute__((ext_vector_type(8)));
typedef unsigned short us4 __attribute__((ext_vector_type(4)));

__device__ __forceinline__ unsigned short f2bf(float f) {
    unsigned int u = __builtin_bit_cast(unsigned int, f);
    unsigned int r = u + 0x7fffu + ((u >> 16) & 1u);
    return (unsigned short)(r >> 16);
}
__device__ __forceinline__ float bf2f(unsigned short h) {
    unsigned int u = ((unsigned int)h) << 16;
    return __builtin_bit_cast(float, u);
}
__device__ __forceinline__ f32x4 mfma16(bf16x8 a, bf16x8 b, f32x4 c) {
    return __builtin_amdgcn_mfma_f32_16x16x32_bf16(a, b, c, 0, 0, 0);
}
__device__ __forceinline__ void gll16(const unsigned short* gsrc, unsigned short* ldst) {
    __builtin_amdgcn_global_load_lds(
        (__attribute__((address_space(1))) void*)gsrc,
        (__attribute__((address_space(3))) void*)ldst, 16, 0, 0);
}

// ---------------- K0: fused prep — x split, Wcat build, Wout split (float4) --
__global__ __launch_bounds__(256) void prep(const float* __restrict__ x,
                                            const float* __restrict__ Wq,
                                            const float* __restrict__ Wk,
                                            const float* __restrict__ Wv,
                                            const float* __restrict__ Wog,
                                            const float* __restrict__ Wout,
                                            unsigned short* __restrict__ x_hi,
                                            unsigned short* __restrict__ x_lo,
                                            unsigned short* __restrict__ wc_hi,
                                            unsigned short* __restrict__ wc_lo,
                                            unsigned short* __restrict__ wo_hi,
                                            unsigned short* __restrict__ wo_lo) {
    const int id = blockIdx.x * 256 + threadIdx.x;
    f32x4 v;
    unsigned short* dh;
    unsigned short* dl;
    size_t off;
    if (id < 1048576) {
        off = (size_t)id * 4;
        v = *(const f32x4*)(x + off);
        dh = x_hi; dl = x_lo;
    } else if (id < 1048576 + 589824) {
        const int e = id - 1048576;
        const int row = e >> 8;
        const int col = (e & 255) * 4;
        off = (size_t)row * 1024 + col;
        if (row < 1024) {
            v = *(const f32x4*)(Wq + off);
#pragma unroll
            for (int t = 0; t < 4; t++) v[t] *= 0.08838834764831845f;
        } else if (row < 1152) {
            v = *(const f32x4*)(Wk + (size_t)(row - 1024) * 1024 + col);
        } else if (row < 1280) {
            v = *(const f32x4*)(Wv + (size_t)(row - 1152) * 1024 + col);
        } else {
            v = *(const f32x4*)(Wog + (size_t)(row - 1280) * 1024 + col);
        }
        dh = wc_hi; dl = wc_lo;
    } else {
        const int e = id - 1048576 - 589824;
        if (e >= 262144) return;
        off = (size_t)e * 4;
        v = *(const f32x4*)(Wout + off);
        dh = wo_hi; dl = wo_lo;
    }
    us4 h4, l4;
#pragma unroll
    for (int t = 0; t < 4; t++) {
        unsigned short hh = f2bf(v[t]);
        h4[t] = hh;
        l4[t] = f2bf(v[t] - bf2f(hh));
    }
    *(us4*)(dh + off) = h4;
    *(us4*)(dl + off) = l4;
}

// ---------------- K1: gates ----------------
__global__ __launch_bounds__(256) void gates_kernel(const float* __restrict__ x,
                                                    const float* __restrict__ Wi,
                                                    const float* __restrict__ bi,
                                                    const float* __restrict__ Wf,
                                                    const float* __restrict__ bfb,
                                                    float* __restrict__ ipre,
                                                    float* __restrict__ lgf) {
    int bs = blockIdx.x;
    int b = bs >> 11, s = bs & 2047;
    const float* xr = x + (size_t)bs * 1024;
    int lane = threadIdx.x & 63, w = threadIdx.x >> 6;
    const float* W = (w < 2) ? Wi : Wf;
    int h0 = (w & 1) * 4;
    float dot0 = 0.f, dot1 = 0.f, dot2 = 0.f, dot3 = 0.f;
    for (int i = lane; i < 1024; i += 64) {
        float xv = xr[i];
        dot0 += xv * W[(size_t)(h0 + 0) * 1024 + i];
        dot1 += xv * W[(size_t)(h0 + 1) * 1024 + i];
        dot2 += xv * W[(size_t)(h0 + 2) * 1024 + i];
        dot3 += xv * W[(size_t)(h0 + 3) * 1024 + i];
    }
#pragma unroll
    for (int o = 32; o; o >>= 1) {
        dot0 += __shfl_xor(dot0, o);
        dot1 += __shfl_xor(dot1, o);
        dot2 += __shfl_xor(dot2, o);
        dot3 += __shfl_xor(dot3, o);
    }
    if (lane == 0) {
        float d[4] = {dot0, dot1, dot2, dot3};
#pragma unroll
        for (int j = 0; j < 4; j++) {
            int hh = h0 + j;
            if (w < 2) {
                float z = d[j] + bi[hh];
                z = 15.f * tanhf(z * (1.f / 15.f));
                ipre[((size_t)b * 8 + hh) * 2048 + s] = z;
            } else {
                float z = d[j] + bfb[hh];
                z = 15.f * tanhf(z * (1.f / 15.f));
                lgf[((size_t)b * 8 + hh) * 2048 + s] = fminf(z, 0.f) - log1pf(expf(-fabsf(z)));
            }
        }
    }
}

// ---------------- K2: scan ----------------
__global__ void scan_kernel(const float* __restrict__ ipre, const float* __restrict__ lgf,
                            float* __restrict__ csum, float* __restrict__ aarr,
                            float* __restrict__ marr) {
    int bh = blockIdx.x;
    int lane = threadIdx.x;
    const float* lf = lgf + (size_t)bh * 2048;
    const float* ip = ipre + (size_t)bh * 2048;
    float* cs = csum + (size_t)bh * 2048;
    float* aa = aarr + (size_t)bh * 2048;
    float* mm = marr + (size_t)bh * 2048;
    float carry = 0.f;
    float carrym = -1e30f;
    for (int c = 0; c < 32; c++) {
        float v = lf[c * 64 + lane];
#pragma unroll
        for (int o = 1; o < 64; o <<= 1) {
            float t = __shfl_up(v, o);
            if (lane >= o) v += t;
        }
        float cval = carry + v;
        cs[c * 64 + lane] = cval;
        float a = ip[c * 64 + lane] - cval;
        aa[c * 64 + lane] = a;
        float mv = a;
#pragma unroll
        for (int o = 1; o < 64; o <<= 1) {
            float t = __shfl_up(mv, o);
            if (lane >= o) mv = fmaxf(mv, t);
        }
        float mval = fmaxf(carrym, mv);
        mm[c * 64 + lane] = mval;
        carry = __shfl(cval, 63);
        carrym = __shfl(mval, 63);
    }
}

// ---- K3/K6: 3-product GEMM, 128x128 tile, global_load_lds staging ----
__global__ __launch_bounds__(256) void gemm_bt3(const unsigned short* __restrict__ Ah,
                                                const unsigned short* __restrict__ Al,
                                                const unsigned short* __restrict__ Bh,
                                                const unsigned short* __restrict__ Bl,
                                                void* __restrict__ Cp,
                                                unsigned short* __restrict__ Clo,
                                                int K, int ldc, int c_bf16, int og_y0) {
    __shared__ __attribute__((aligned(16))) unsigned short Ash[128 * 32];
    __shared__ __attribute__((aligned(16))) unsigned short Asl[128 * 32];
    __shared__ __attribute__((aligned(16))) unsigned short Bsh[128 * 32];
    __shared__ __attribute__((aligned(16))) unsigned short Bsl[128 * 32];
    const int tid = threadIdx.x;
    const int lane = tid & 63, wv = tid >> 6;
    const int wr = wv >> 1, wc = wv & 1;
    const int fr = lane & 15, fg = lane >> 4;
    const bool full3 = (blockIdx.y < (unsigned)og_y0);
    const int sr = tid >> 2, sc = (tid & 3) * 8;
    const size_t abase = (size_t)(blockIdx.x * 128 + sr) * K + sc;
    const size_t bbase = (size_t)(blockIdx.y * 128 + sr) * K + sc;
    const size_t rstep = 64ull * K;
    unsigned short* a0 = &Ash[tid * 8];
    unsigned short* a1 = &Ash[2048 + tid * 8];
    unsigned short* l0 = &Asl[tid * 8];
    unsigned short* l1 = &Asl[2048 + tid * 8];
    unsigned short* b0 = &Bsh[tid * 8];
    unsigned short* b1 = &Bsh[2048 + tid * 8];
    unsigned short* m0 = &Bsl[tid * 8];
    unsigned short* m1 = &Bsl[2048 + tid * 8];
#define GLL(KT)                                                                \
    {                                                                          \
        gll16(Ah + abase + (KT), a0);                                          \
        gll16(Ah + abase + rstep + (KT), a1);                                  \
        gll16(Bh + bbase + (KT), b0);                                          \
        gll16(Bh + bbase + rstep + (KT), b1);                                  \
        if (full3) {                                                           \
            gll16(Al + abase + (KT), l0);                                      \
            gll16(Al + abase + rstep + (KT), l1);                              \
            gll16(Bl + bbase + (KT), m0);                                      \
            gll16(Bl + bbase + rstep + (KT), m1);                              \
        }                                                                      \
    }
    f32x4 acc[4][4] = {};
    GLL(0);
    for (int kt = 0; kt < K; kt += 32) {
        __syncthreads();
        bf16x8 bfh[4], bfl[4];
#pragma unroll
        for (int j = 0; j < 4; j++) {
            bfh[j] = __builtin_bit_cast(bf16x8, *(const us8*)&Bsh[(64 * wc + 16 * j + fr) * 32 + fg * 8]);
            bfl[j] = __builtin_bit_cast(bf16x8, *(const us8*)&Bsl[(64 * wc + 16 * j + fr) * 32 + fg * 8]);
        }
        __builtin_amdgcn_s_setprio(1);
        if (full3) {
#pragma unroll
            for (int i = 0; i < 4; i++) {
                bf16x8 afh = __builtin_bit_cast(bf16x8, *(const us8*)&Ash[(64 * wr + 16 * i + fr) * 32 + fg * 8]);
                bf16x8 afl = __builtin_bit_cast(bf16x8, *(const us8*)&Asl[(64 * wr + 16 * i + fr) * 32 + fg * 8]);
#pragma unroll
                for (int j = 0; j < 4; j++) {
                    acc[i][j] = mfma16(afh, bfh[j], acc[i][j]);
                    acc[i][j] = mfma16(afh, bfl[j], acc[i][j]);
                    acc[i][j] = mfma16(afl, bfh[j], acc[i][j]);
                }
            }
        } else {
#pragma unroll
            for (int i = 0; i < 4; i++) {
                bf16x8 afh = __builtin_bit_cast(bf16x8, *(const us8*)&Ash[(64 * wr + 16 * i + fr) * 32 + fg * 8]);
#pragma unroll
                for (int j = 0; j < 4; j++)
                    acc[i][j] = mfma16(afh, bfh[j], acc[i][j]);
            }
        }
        __builtin_amdgcn_s_setprio(0);
        if (kt + 32 < K) {
            __syncthreads();
            GLL(kt + 32);
        }
    }
#undef GLL
#pragma unroll
    for (int i = 0; i < 4; i++)
#pragma unroll
        for (int j = 0; j < 4; j++)
#pragma unroll
            for (int e = 0; e < 4; e++) {
                int r = blockIdx.x * 128 + 64 * wr + 16 * i + fg * 4 + e;
                int c = blockIdx.y * 128 + 64 * wc + 16 * j + fr;
                float v = acc[i][j][e];
                if (c_bf16) {
                    unsigned short h = f2bf(v);
                    ((unsigned short*)Cp)[(size_t)r * ldc + c] = h;
                    Clo[(size_t)r * ldc + c] = f2bf(v - bf2f(h));
                } else {
                    ((float*)Cp)[(size_t)r * ldc + c] = v;
                }
            }
}

// ---------------- K4: vT (hi only) via coalesced LDS-tiled transpose --------
__global__ __launch_bounds__(256) void make_vt(const unsigned short* __restrict__ ph,
                                               unsigned short* __restrict__ vTh) {
    __shared__ __attribute__((aligned(16))) unsigned short th[64 * 68];
    const int bid = blockIdx.x;
    const int st = bid & 31, ct = (bid >> 5) & 1, b = bid >> 6;
    const int tid = threadIdx.x;
    {
        const int sr = tid >> 2, cc = (tid & 3) * 16;
        const size_t rbase = (size_t)(b * 2048 + st * 64 + sr) * 2304 + 1152 + ct * 64 + cc;
        us8 a0 = *(const us8*)(ph + rbase);
        us8 a1 = *(const us8*)(ph + rbase + 8);
        *(us8*)&th[sr * 68 + cc] = a0;
        *(us8*)&th[sr * 68 + cc + 8] = a1;
    }
    __syncthreads();
    {
        const int cr = tid >> 2, ss = (tid & 3) * 16;
        us8 oh0, oh1;
#pragma unroll
        for (int e = 0; e < 8; e++) {
            oh0[e] = th[(ss + e) * 68 + cr];
            oh1[e] = th[(ss + 8 + e) * 68 + cr];
        }
        const size_t wbase = (size_t)b * 128 * 2048 + (size_t)(ct * 64 + cr) * 2048 + st * 64 + ss;
        *(us8*)&vTh[wbase] = oh0;
        *(us8*)&vTh[wbase + 8] = oh1;
    }
}

// ---------------- K5: fused attn — bf16 K/V, dbuf pair, unrolled x2 ---------
__global__ __launch_bounds__(256, 3) void attn_fused(const unsigned short* __restrict__ projh,
                                                     const unsigned short* __restrict__ projl,
                                                     const unsigned short* __restrict__ vTh,
                                                     const float* __restrict__ aarr,
                                                     const float* __restrict__ marr,
                                                     const float* __restrict__ csum,
                                                     const float* __restrict__ lnw,
                                                     unsigned short* __restrict__ ho_hi,
                                                     unsigned short* __restrict__ ho_lo) {
    __shared__ __attribute__((aligned(16))) unsigned short Klh[2][32 * 148];
    __shared__ __attribute__((aligned(16))) unsigned short Vlh[2][128 * 40];
    __shared__ float al[2][32];

    const int idx = blockIdx.x;
    const int half = idx >> 8;
    const int pid = idx & 255;
    const int bh = pid & 15;
    const int qt0 = pid >> 4;
    const int qt = half ? (31 - qt0) : qt0;
    const int b = bh >> 3, h = bh & 7;
    const int tid = threadIdx.x, lane = tid & 63, w = tid >> 6;
    const int fr = lane & 15, fg = lane >> 4;
    const int q0 = qt * 64;
    const int qg = q0 + 16 * w + fr;

    bf16x8 qfh[4], qfl[4];
    {
        const size_t qoff = (size_t)(b * 2048 + qg) * 2304 + h * 128;
#pragma unroll
        for (int ks = 0; ks < 4; ks++) {
            qfh[ks] = __builtin_bit_cast(bf16x8, *(const us8*)(projh + qoff + ks * 32 + fg * 8));
            qfl[ks] = __builtin_bit_cast(bf16x8, *(const us8*)(projl + qoff + ks * 32 + fg * 8));
        }
    }
    const float ma_q = marr[(size_t)bh * 2048 + qg];

    f32x4 acc[8] = {};
    float b_run = 0.f;

    const int kr = tid >> 3, kc = (tid & 7) * 16;
    const int vr = tid >> 1, vc = (tid & 1) * 16;
    const size_t kbase = (size_t)(b * 2048) * 2304 + 1024;
    const size_t vtbase = (size_t)b * 128 * 2048;

    const int nt = 2 * qt + 2;   // always even
    us8 kh0A, kh1A, vh0A, vh1A;
    us8 kh0B, kh1B, vh0B, vh1B;
    float a_stA, a_stB;
#define LOADPAIR(T0)                                                           \
    {                                                                          \
        const size_t koA = kbase + (size_t)((T0) + kr) * 2304 + kc;            \
        const size_t voA = vtbase + (size_t)vr * 2048 + (T0) + vc;             \
        kh0A = *(const us8*)(projh + koA);                                     \
        kh1A = *(const us8*)(projh + koA + 8);                                 \
        vh0A = *(const us8*)(vTh + voA);                                       \
        vh1A = *(const us8*)(vTh + voA + 8);                                   \
        a_stA = (tid < 32) ? aarr[(size_t)bh * 2048 + (T0) + tid] : 0.f;       \
        const size_t koB = koA + 32ull * 2304;                                 \
        const size_t voB = voA + 32;                                           \
        kh0B = *(const us8*)(projh + koB);                                     \
        kh1B = *(const us8*)(projh + koB + 8);                                 \
        vh0B = *(const us8*)(vTh + voB);                                       \
        vh1B = *(const us8*)(vTh + voB + 8);                                   \
        a_stB = (tid < 32) ? aarr[(size_t)bh * 2048 + (T0) + 32 + tid] : 0.f;  \
    }
#define STOREPAIR()                                                            \
    {                                                                          \
        *(us8*)&Klh[0][kr * 148 + kc] = kh0A;                                  \
        *(us8*)&Klh[0][kr * 148 + kc + 8] = kh1A;                              \
        *(us8*)&Vlh[0][vr * 40 + vc] = vh0A;                                   \
        *(us8*)&Vlh[0][vr * 40 + vc + 8] = vh1A;                               \
        *(us8*)&Klh[1][kr * 148 + kc] = kh0B;                                  \
        *(us8*)&Klh[1][kr * 148 + kc + 8] = kh1B;                              \
        *(us8*)&Vlh[1][vr * 40 + vc] = vh0B;                                   \
        *(us8*)&Vlh[1][vr * 40 + vc + 8] = vh1B;                               \
        if (tid < 32) {                                                        \
            al[0][tid] = a_stA;                                                \
            al[1][tid] = a_stB;                                                \
        }                                                                      \
    }

    LOADPAIR(0);
    STOREPAIR();
    if (nt > 2) LOADPAIR(64);
    __syncthreads();

    for (int kt = 0;;) {
        const int t0 = kt * 32;

        float djA[2][4], djB[2][4];
#pragma unroll
        for (int j = 0; j < 2; j++) {
            f32x4 sfaA = {}, sfbA = {};
            f32x4 sfaB = {}, sfbB = {};
            __builtin_amdgcn_s_setprio(1);
#pragma unroll
            for (int ks = 0; ks < 4; ks++) {
                bf16x8 kfhA = __builtin_bit_cast(bf16x8, *(const us8*)&Klh[0][(j * 16 + fr) * 148 + ks * 32 + fg * 8]);
                bf16x8 kfhB = __builtin_bit_cast(bf16x8, *(const us8*)&Klh[1][(j * 16 + fr) * 148 + ks * 32 + fg * 8]);
                sfaA = mfma16(kfhA, qfh[ks], sfaA);
                sfaB = mfma16(kfhB, qfh[ks], sfaB);
                sfbA = mfma16(kfhA, qfl[ks], sfbA);
                sfbB = mfma16(kfhB, qfl[ks], sfbB);
            }
            __builtin_amdgcn_s_setprio(0);
            f32x4 sfA = sfaA + sfbA;
            f32x4 sfB = sfaB + sfbB;
#pragma unroll
            for (int r = 0; r < 4; r++) {
                const int kloc = j * 16 + fg * 4 + r;
                const float atvA = al[0][kloc];
                const float atvB = al[1][kloc];
                djA[j][r] = ((t0 + kloc) <= qg) ? sfA[r] * __expf(atvA - ma_q) : 0.f;
                djB[j][r] = ((t0 + 32 + kloc) <= qg) ? sfB[r] * __expf(atvB - ma_q) : 0.f;
            }
        }

        {
            float tsA = djA[0][0] + djA[0][1] + djA[0][2] + djA[0][3]
                      + djA[1][0] + djA[1][1] + djA[1][2] + djA[1][3];
            tsA += __shfl_xor(tsA, 16);
            tsA += __shfl_xor(tsA, 32);
            b_run += tsA;
            float tsB = djB[0][0] + djB[0][1] + djB[0][2] + djB[0][3]
                      + djB[1][0] + djB[1][1] + djB[1][2] + djB[1][3];
            tsB += __shfl_xor(tsB, 16);
            tsB += __shfl_xor(tsB, 32);
            b_run += tsB;
        }

        const int srlo = 32 * ((lane >> 4) & 1) + fr;
        {
            float p8[8];
#pragma unroll
            for (int e = 0; e < 8; e++) {
                const int sl = srlo + ((e >= 4) ? 16 : 0);
                const float v0 = __shfl(djA[0][e & 3], sl);
                const float v1 = __shfl(djA[1][e & 3], sl);
                p8[e] = (lane & 32) ? v1 : v0;
            }
            us8 phu, plu;
#pragma unroll
            for (int e = 0; e < 8; e++) {
                unsigned short hh = f2bf(p8[e]);
                phu[e] = hh;
                plu[e] = f2bf(p8[e] - bf2f(hh));
            }
            const bf16x8 pfh = __builtin_bit_cast(bf16x8, phu);
            const bf16x8 pfl = __builtin_bit_cast(bf16x8, plu);
            __builtin_amdgcn_s_setprio(1);
#pragma unroll
            for (int jb = 0; jb < 8; jb++) {
                bf16x8 vfh = __builtin_bit_cast(bf16x8, *(const us8*)&Vlh[0][(jb * 16 + fr) * 40 + fg * 8]);
                acc[jb] = mfma16(vfh, pfh, acc[jb]);
                acc[jb] = mfma16(vfh, pfl, acc[jb]);
            }
            __builtin_amdgcn_s_setprio(0);
        }
        {
            float p8[8];
#pragma unroll
            for (int e = 0; e < 8; e++) {
                const int sl = srlo + ((e >= 4) ? 16 : 0);
                const float v0 = __shfl(djB[0][e & 3], sl);
                const float v1 = __shfl(djB[1][e & 3], sl);
                p8[e] = (lane & 32) ? v1 : v0;
            }
            us8 phu, plu;
#pragma unroll
            for (int e = 0; e < 8; e++) {
                unsigned short hh = f2bf(p8[e]);
                phu[e] = hh;
                plu[e] = f2bf(p8[e] - bf2f(hh));
            }
            const bf16x8 pfh = __builtin_bit_cast(bf16x8, phu);
            const bf16x8 pfl = __builtin_bit_cast(bf16x8, plu);
            __builtin_amdgcn_s_setprio(1);
#pragma unroll
            for (int jb = 0; jb < 8; jb++) {
                bf16x8 vfh = __builtin_bit_cast(bf16x8, *(const us8*)&Vlh[1][(jb * 16 + fr) * 40 + fg * 8]);
                acc[jb] = mfma16(vfh, pfh, acc[jb]);
                acc[jb] = mfma16(vfh, pfl, acc[jb]);
            }
            __builtin_amdgcn_s_setprio(0);
        }

        kt += 2;
        if (kt >= nt) break;
        __syncthreads();
        STOREPAIR();
        if (kt + 2 < nt) LOADPAIR((kt + 2) * 32);
        __syncthreads();
    }
#undef LOADPAIR
#undef STOREPAIR

    const float cs_q = csum[(size_t)bh * 2048 + qg];
    const float nf = __expf(-(cs_q + ma_q));
    const float n = fmaxf(fabsf(b_run), nf);
    const float inv = 1.f / (n + 1e-6f);
#pragma unroll
    for (int jb = 0; jb < 8; jb++) acc[jb] *= inv;

    float s1 = 0.f;
#pragma unroll
    for (int jb = 0; jb < 8; jb++) s1 += acc[jb][0] + acc[jb][1] + acc[jb][2] + acc[jb][3];
    s1 += __shfl_xor(s1, 16);
    s1 += __shfl_xor(s1, 32);
    const float mu = s1 * (1.f / 128.f);
    float vv = 0.f;
#pragma unroll
    for (int jb = 0; jb < 8; jb++)
#pragma unroll
        for (int e = 0; e < 4; e++) {
            float d = acc[jb][e] - mu;
            vv += d * d;
        }
    vv += __shfl_xor(vv, 16);
    vv += __shfl_xor(vv, 32);
    const float rstd = rsqrtf(vv * (1.f / 128.f) + 1e-6f);

    const size_t obase = (size_t)(b * 2048 + qg) * 2304 + 1280 + h * 128 + fg * 4;
    const size_t hbase = (size_t)(b * 2048 + qg) * 1024 + h * 128 + fg * 4;
#pragma unroll
    for (int jb = 0; jb < 8; jb++) {
        us4 ogh = *(const us4*)(projh + obase + jb * 16);
        us4 ogl = *(const us4*)(projl + obase + jb * 16);
        f32x4 lw = *(const f32x4*)&lnw[h * 128 + jb * 16 + fg * 4];
        us4 hi4, lo4;
#pragma unroll
        for (int e = 0; e < 4; e++) {
            const float og = bf2f(ogh[e]) + bf2f(ogl[e]);
            const float sig = 1.f / (1.f + __expf(-og));
            const float ho = (acc[jb][e] - mu) * rstd * lw[e] * sig;
            unsigned short h1 = f2bf(ho);
            hi4[e] = h1;
            lo4[e] = f2bf(ho - bf2f(h1));
        }
        *(us4*)&ho_hi[hbase + jb * 16] = hi4;
        *(us4*)&ho_lo[hbase + jb * 16] = lo4;
    }
}

// ---------------------------------------------------------------------------
extern "C" void kernel_launch(void* const* d_in, const int* in_sizes, int n_in,
                              void* d_out, int out_size, void* d_ws, size_t ws_size,
                              hipStream_t stream) {
    (void)in_sizes; (void)n_in; (void)out_size; (void)ws_size;
    const float* x    = (const float*)d_in[0];
    const float* Wq   = (const float*)d_in[1];
    const float* Wk   = (const float*)d_in[2];
    const float* Wv   = (const float*)d_in[3];
    const float* Wog  = (const float*)d_in[4];
    const float* Wi   = (const float*)d_in[5];
    const float* bi   = (const float*)d_in[6];
    const float* Wf   = (const float*)d_in[7];
    const float* bfb  = (const float*)d_in[8];
    const float* lnw  = (const float*)d_in[9];
    const float* Wout = (const float*)d_in[10];

    char* p = (char*)d_ws;
    auto carve = [&](size_t bytes) -> char* {
        char* r = p;
        p += (bytes + 255) & ~(size_t)255;
        return r;
    };
    unsigned short* x_hi   = (unsigned short*)carve(4194304ull * 2);
    unsigned short* x_lo   = (unsigned short*)carve(4194304ull * 2);
    unsigned short* wc_hi  = (unsigned short*)carve(2359296ull * 2);
    unsigned short* wc_lo  = (unsigned short*)carve(2359296ull * 2);
    unsigned short* wo_hi  = (unsigned short*)carve(1048576ull * 2);
    unsigned short* wo_lo  = (unsigned short*)carve(1048576ull * 2);
    unsigned short* pr_hi  = (unsigned short*)carve(4096ull * 2304 * 2);
    unsigned short* pr_lo  = (unsigned short*)carve(4096ull * 2304 * 2);
    unsigned short* vT_hi  = (unsigned short*)carve(524288ull * 2);
    float* ipre    = (float*)carve(32768ull * 4);
    float* lgf_buf = (float*)carve(32768ull * 4);
    float* csum    = (float*)carve(32768ull * 4);
    float* aarr    = (float*)carve(32768ull * 4);
    float* marr    = (float*)carve(32768ull * 4);
    unsigned short* ho_hi = x_hi;   // x dead after proj GEMM
    unsigned short* ho_lo = x_lo;

    prep<<<7424, 256, 0, stream>>>(x, Wq, Wk, Wv, Wog, Wout,
                                   x_hi, x_lo, wc_hi, wc_lo, wo_hi, wo_lo);
    gates_kernel<<<4096, 256, 0, stream>>>(x, Wi, bi, Wf, bfb, ipre, lgf_buf);
    scan_kernel<<<16, 64, 0, stream>>>(ipre, lgf_buf, csum, aarr, marr);
    gemm_bt3<<<dim3(32, 18), 256, 0, stream>>>(x_hi, x_lo, wc_hi, wc_lo, pr_hi, pr_lo, 1024, 2304, 1, 10);
    make_vt<<<128, 256, 0, stream>>>(pr_hi, vT_hi);
    attn_fused<<<512, 256, 0, stream>>>(pr_hi, pr_lo, vT_hi, aarr, marr, csum, lnw, ho_hi, ho_lo);
    gemm_bt3<<<dim3(32, 8), 256, 0, stream>>>(ho_hi, ho_lo, wo_hi, wo_lo, d_out, nullptr, 1024, 1024, 0, 1000);
}

// Round 23
// 284.609 us; speedup vs baseline: 1.4972x; 1.0747x over previous
//
#include <hip/hip_runtime.h>

// ---------------------------------------------------------------------------
// mLSTM block, MI355X. B=2,S=2048,D=1024,NH=8,DH=128.
// v22 = v21 + attn quad-buffer single-barrier rotation (1 barrier/pair,
//       stores issue before compute). Bitwise-identical numerics to v21
//       (absmax 0.04101562).
// ---------------------------------------------------------------------------

typedef __bf16 bf16x8 __attribute__((ext_vector_type(8)));
typedef float f32x4 __attribute__((ext_vector_type(4)));
typedef unsigned short us8 __attribute__((ext_vector_type(8)));
typedef unsigned short us4 __attribute__((ext_vector_type(4)));

__device__ __forceinline__ unsigned short f2bf(float f) {
    unsigned int u = __builtin_bit_cast(unsigned int, f);
    unsigned int r = u + 0x7fffu + ((u >> 16) & 1u);
    return (unsigned short)(r >> 16);
}
__device__ __forceinline__ float bf2f(unsigned short h) {
    unsigned int u = ((unsigned int)h) << 16;
    return __builtin_bit_cast(float, u);
}
__device__ __forceinline__ f32x4 mfma16(bf16x8 a, bf16x8 b, f32x4 c) {
    return __builtin_amdgcn_mfma_f32_16x16x32_bf16(a, b, c, 0, 0, 0);
}
__device__ __forceinline__ void gll16(const unsigned short* gsrc, unsigned short* ldst) {
    __builtin_amdgcn_global_load_lds(
        (__attribute__((address_space(1))) void*)gsrc,
        (__attribute__((address_space(3))) void*)ldst, 16, 0, 0);
}

// ---------------- K0: fused prep — x split, Wcat build, Wout split (float4) --
__global__ __launch_bounds__(256) void prep(const float* __restrict__ x,
                                            const float* __restrict__ Wq,
                                            const float* __restrict__ Wk,
                                            const float* __restrict__ Wv,
                                            const float* __restrict__ Wog,
                                            const float* __restrict__ Wout,
                                            unsigned short* __restrict__ x_hi,
                                            unsigned short* __restrict__ x_lo,
                                            unsigned short* __restrict__ wc_hi,
                                            unsigned short* __restrict__ wc_lo,
                                            unsigned short* __restrict__ wo_hi,
                                            unsigned short* __restrict__ wo_lo) {
    const int id = blockIdx.x * 256 + threadIdx.x;
    f32x4 v;
    unsigned short* dh;
    unsigned short* dl;
    size_t off;
    if (id < 1048576) {
        off = (size_t)id * 4;
        v = *(const f32x4*)(x + off);
        dh = x_hi; dl = x_lo;
    } else if (id < 1048576 + 589824) {
        const int e = id - 1048576;
        const int row = e >> 8;
        const int col = (e & 255) * 4;
        off = (size_t)row * 1024 + col;
        if (row < 1024) {
            v = *(const f32x4*)(Wq + off);
#pragma unroll
            for (int t = 0; t < 4; t++) v[t] *= 0.08838834764831845f;
        } else if (row < 1152) {
            v = *(const f32x4*)(Wk + (size_t)(row - 1024) * 1024 + col);
        } else if (row < 1280) {
            v = *(const f32x4*)(Wv + (size_t)(row - 1152) * 1024 + col);
        } else {
            v = *(const f32x4*)(Wog + (size_t)(row - 1280) * 1024 + col);
        }
        dh = wc_hi; dl = wc_lo;
    } else {
        const int e = id - 1048576 - 589824;
        if (e >= 262144) return;
        off = (size_t)e * 4;
        v = *(const f32x4*)(Wout + off);
        dh = wo_hi; dl = wo_lo;
    }
    us4 h4, l4;
#pragma unroll
    for (int t = 0; t < 4; t++) {
        unsigned short hh = f2bf(v[t]);
        h4[t] = hh;
        l4[t] = f2bf(v[t] - bf2f(hh));
    }
    *(us4*)(dh + off) = h4;
    *(us4*)(dl + off) = l4;
}

// ---------------- K1: gates ----------------
__global__ __launch_bounds__(256) void gates_kernel(const float* __restrict__ x,
                                                    const float* __restrict__ Wi,
                                                    const float* __restrict__ bi,
                                                    const float* __restrict__ Wf,
                                                    const float* __restrict__ bfb,
                                                    float* __restrict__ ipre,
                                                    float* __restrict__ lgf) {
    int bs = blockIdx.x;
    int b = bs >> 11, s = bs & 2047;
    const float* xr = x + (size_t)bs * 1024;
    int lane = threadIdx.x & 63, w = threadIdx.x >> 6;
    const float* W = (w < 2) ? Wi : Wf;
    int h0 = (w & 1) * 4;
    float dot0 = 0.f, dot1 = 0.f, dot2 = 0.f, dot3 = 0.f;
    for (int i = lane; i < 1024; i += 64) {
        float xv = xr[i];
        dot0 += xv * W[(size_t)(h0 + 0) * 1024 + i];
        dot1 += xv * W[(size_t)(h0 + 1) * 1024 + i];
        dot2 += xv * W[(size_t)(h0 + 2) * 1024 + i];
        dot3 += xv * W[(size_t)(h0 + 3) * 1024 + i];
    }
#pragma unroll
    for (int o = 32; o; o >>= 1) {
        dot0 += __shfl_xor(dot0, o);
        dot1 += __shfl_xor(dot1, o);
        dot2 += __shfl_xor(dot2, o);
        dot3 += __shfl_xor(dot3, o);
    }
    if (lane == 0) {
        float d[4] = {dot0, dot1, dot2, dot3};
#pragma unroll
        for (int j = 0; j < 4; j++) {
            int hh = h0 + j;
            if (w < 2) {
                float z = d[j] + bi[hh];
                z = 15.f * tanhf(z * (1.f / 15.f));
                ipre[((size_t)b * 8 + hh) * 2048 + s] = z;
            } else {
                float z = d[j] + bfb[hh];
                z = 15.f * tanhf(z * (1.f / 15.f));
                lgf[((size_t)b * 8 + hh) * 2048 + s] = fminf(z, 0.f) - log1pf(expf(-fabsf(z)));
            }
        }
    }
}

// ---------------- K2: scan ----------------
__global__ void scan_kernel(const float* __restrict__ ipre, const float* __restrict__ lgf,
                            float* __restrict__ csum, float* __restrict__ aarr,
                            float* __restrict__ marr) {
    int bh = blockIdx.x;
    int lane = threadIdx.x;
    const float* lf = lgf + (size_t)bh * 2048;
    const float* ip = ipre + (size_t)bh * 2048;
    float* cs = csum + (size_t)bh * 2048;
    float* aa = aarr + (size_t)bh * 2048;
    float* mm = marr + (size_t)bh * 2048;
    float carry = 0.f;
    float carrym = -1e30f;
    for (int c = 0; c < 32; c++) {
        float v = lf[c * 64 + lane];
#pragma unroll
        for (int o = 1; o < 64; o <<= 1) {
            float t = __shfl_up(v, o);
            if (lane >= o) v += t;
        }
        float cval = carry + v;
        cs[c * 64 + lane] = cval;
        float a = ip[c * 64 + lane] - cval;
        aa[c * 64 + lane] = a;
        float mv = a;
#pragma unroll
        for (int o = 1; o < 64; o <<= 1) {
            float t = __shfl_up(mv, o);
            if (lane >= o) mv = fmaxf(mv, t);
        }
        float mval = fmaxf(carrym, mv);
        mm[c * 64 + lane] = mval;
        carry = __shfl(cval, 63);
        carrym = __shfl(mval, 63);
    }
}

// ---- K3/K6: 3-product GEMM, 128x128 tile, global_load_lds staging ----
__global__ __launch_bounds__(256) void gemm_bt3(const unsigned short* __restrict__ Ah,
                                                const unsigned short* __restrict__ Al,
                                                const unsigned short* __restrict__ Bh,
                                                const unsigned short* __restrict__ Bl,
                                                void* __restrict__ Cp,
                                                unsigned short* __restrict__ Clo,
                                                int K, int ldc, int c_bf16, int og_y0) {
    __shared__ __attribute__((aligned(16))) unsigned short Ash[128 * 32];
    __shared__ __attribute__((aligned(16))) unsigned short Asl[128 * 32];
    __shared__ __attribute__((aligned(16))) unsigned short Bsh[128 * 32];
    __shared__ __attribute__((aligned(16))) unsigned short Bsl[128 * 32];
    const int tid = threadIdx.x;
    const int lane = tid & 63, wv = tid >> 6;
    const int wr = wv >> 1, wc = wv & 1;
    const int fr = lane & 15, fg = lane >> 4;
    const bool full3 = (blockIdx.y < (unsigned)og_y0);
    const int sr = tid >> 2, sc = (tid & 3) * 8;
    const size_t abase = (size_t)(blockIdx.x * 128 + sr) * K + sc;
    const size_t bbase = (size_t)(blockIdx.y * 128 + sr) * K + sc;
    const size_t rstep = 64ull * K;
    unsigned short* a0 = &Ash[tid * 8];
    unsigned short* a1 = &Ash[2048 + tid * 8];
    unsigned short* l0 = &Asl[tid * 8];
    unsigned short* l1 = &Asl[2048 + tid * 8];
    unsigned short* b0 = &Bsh[tid * 8];
    unsigned short* b1 = &Bsh[2048 + tid * 8];
    unsigned short* m0 = &Bsl[tid * 8];
    unsigned short* m1 = &Bsl[2048 + tid * 8];
#define GLL(KT)                                                                \
    {                                                                          \
        gll16(Ah + abase + (KT), a0);                                          \
        gll16(Ah + abase + rstep + (KT), a1);                                  \
        gll16(Bh + bbase + (KT), b0);                                          \
        gll16(Bh + bbase + rstep + (KT), b1);                                  \
        if (full3) {                                                           \
            gll16(Al + abase + (KT), l0);                                      \
            gll16(Al + abase + rstep + (KT), l1);                              \
            gll16(Bl + bbase + (KT), m0);                                      \
            gll16(Bl + bbase + rstep + (KT), m1);                              \
        }                                                                      \
    }
    f32x4 acc[4][4] = {};
    GLL(0);
    for (int kt = 0; kt < K; kt += 32) {
        __syncthreads();
        bf16x8 bfh[4], bfl[4];
#pragma unroll
        for (int j = 0; j < 4; j++) {
            bfh[j] = __builtin_bit_cast(bf16x8, *(const us8*)&Bsh[(64 * wc + 16 * j + fr) * 32 + fg * 8]);
            bfl[j] = __builtin_bit_cast(bf16x8, *(const us8*)&Bsl[(64 * wc + 16 * j + fr) * 32 + fg * 8]);
        }
        __builtin_amdgcn_s_setprio(1);
        if (full3) {
#pragma unroll
            for (int i = 0; i < 4; i++) {
                bf16x8 afh = __builtin_bit_cast(bf16x8, *(const us8*)&Ash[(64 * wr + 16 * i + fr) * 32 + fg * 8]);
                bf16x8 afl = __builtin_bit_cast(bf16x8, *(const us8*)&Asl[(64 * wr + 16 * i + fr) * 32 + fg * 8]);
#pragma unroll
                for (int j = 0; j < 4; j++) {
                    acc[i][j] = mfma16(afh, bfh[j], acc[i][j]);
                    acc[i][j] = mfma16(afh, bfl[j], acc[i][j]);
                    acc[i][j] = mfma16(afl, bfh[j], acc[i][j]);
                }
            }
        } else {
#pragma unroll
            for (int i = 0; i < 4; i++) {
                bf16x8 afh = __builtin_bit_cast(bf16x8, *(const us8*)&Ash[(64 * wr + 16 * i + fr) * 32 + fg * 8]);
#pragma unroll
                for (int j = 0; j < 4; j++)
                    acc[i][j] = mfma16(afh, bfh[j], acc[i][j]);
            }
        }
        __builtin_amdgcn_s_setprio(0);
        if (kt + 32 < K) {
            __syncthreads();
            GLL(kt + 32);
        }
    }
#undef GLL
#pragma unroll
    for (int i = 0; i < 4; i++)
#pragma unroll
        for (int j = 0; j < 4; j++)
#pragma unroll
            for (int e = 0; e < 4; e++) {
                int r = blockIdx.x * 128 + 64 * wr + 16 * i + fg * 4 + e;
                int c = blockIdx.y * 128 + 64 * wc + 16 * j + fr;
                float v = acc[i][j][e];
                if (c_bf16) {
                    unsigned short h = f2bf(v);
                    ((unsigned short*)Cp)[(size_t)r * ldc + c] = h;
                    Clo[(size_t)r * ldc + c] = f2bf(v - bf2f(h));
                } else {
                    ((float*)Cp)[(size_t)r * ldc + c] = v;
                }
            }
}

// ---------------- K4: vT (hi only) via coalesced LDS-tiled transpose --------
__global__ __launch_bounds__(256) void make_vt(const unsigned short* __restrict__ ph,
                                               unsigned short* __restrict__ vTh) {
    __shared__ __attribute__((aligned(16))) unsigned short th[64 * 68];
    const int bid = blockIdx.x;
    const int st = bid & 31, ct = (bid >> 5) & 1, b = bid >> 6;
    const int tid = threadIdx.x;
    {
        const int sr = tid >> 2, cc = (tid & 3) * 16;
        const size_t rbase = (size_t)(b * 2048 + st * 64 + sr) * 2304 + 1152 + ct * 64 + cc;
        us8 a0 = *(const us8*)(ph + rbase);
        us8 a1 = *(const us8*)(ph + rbase + 8);
        *(us8*)&th[sr * 68 + cc] = a0;
        *(us8*)&th[sr * 68 + cc + 8] = a1;
    }
    __syncthreads();
    {
        const int cr = tid >> 2, ss = (tid & 3) * 16;
        us8 oh0, oh1;
#pragma unroll
        for (int e = 0; e < 8; e++) {
            oh0[e] = th[(ss + e) * 68 + cr];
            oh1[e] = th[(ss + 8 + e) * 68 + cr];
        }
        const size_t wbase = (size_t)b * 128 * 2048 + (size_t)(ct * 64 + cr) * 2048 + st * 64 + ss;
        *(us8*)&vTh[wbase] = oh0;
        *(us8*)&vTh[wbase + 8] = oh1;
    }
}

// ---------------- K5: fused attn — bf16 K/V, quad-buffer, 1 barrier/pair ----
__global__ __launch_bounds__(256, 2) void attn_fused(const unsigned short* __restrict__ projh,
                                                     const unsigned short* __restrict__ projl,
                                                     const unsigned short* __restrict__ vTh,
                                                     const float* __restrict__ aarr,
                                                     const float* __restrict__ marr,
                                                     const float* __restrict__ csum,
                                                     const float* __restrict__ lnw,
                                                     unsigned short* __restrict__ ho_hi,
                                                     unsigned short* __restrict__ ho_lo) {
    __shared__ __attribute__((aligned(16))) unsigned short Klh[4][32 * 148];
    __shared__ __attribute__((aligned(16))) unsigned short Vlh[4][128 * 40];
    __shared__ float al[4][32];

    const int idx = blockIdx.x;
    const int half = idx >> 8;
    const int pid = idx & 255;
    const int bh = pid & 15;
    const int qt0 = pid >> 4;
    const int qt = half ? (31 - qt0) : qt0;
    const int b = bh >> 3, h = bh & 7;
    const int tid = threadIdx.x, lane = tid & 63, w = tid >> 6;
    const int fr = lane & 15, fg = lane >> 4;
    const int q0 = qt * 64;
    const int qg = q0 + 16 * w + fr;

    bf16x8 qfh[4], qfl[4];
    {
        const size_t qoff = (size_t)(b * 2048 + qg) * 2304 + h * 128;
#pragma unroll
        for (int ks = 0; ks < 4; ks++) {
            qfh[ks] = __builtin_bit_cast(bf16x8, *(const us8*)(projh + qoff + ks * 32 + fg * 8));
            qfl[ks] = __builtin_bit_cast(bf16x8, *(const us8*)(projl + qoff + ks * 32 + fg * 8));
        }
    }
    const float ma_q = marr[(size_t)bh * 2048 + qg];

    f32x4 acc[8] = {};
    float b_run = 0.f;

    const int kr = tid >> 3, kc = (tid & 7) * 16;
    const int vr = tid >> 1, vc = (tid & 1) * 16;
    const size_t kbase = (size_t)(b * 2048) * 2304 + 1024;
    const size_t vtbase = (size_t)b * 128 * 2048;

    const int npairs = qt + 1;   // nt = 2*(qt+1) tiles = npairs pairs
    us8 kh0A, kh1A, vh0A, vh1A;
    us8 kh0B, kh1B, vh0B, vh1B;
    float a_stA, a_stB;
#define LOADPAIR(P)                                                            \
    {                                                                          \
        const int T0 = (P) * 64;                                               \
        const size_t koA = kbase + (size_t)(T0 + kr) * 2304 + kc;              \
        const size_t voA = vtbase + (size_t)vr * 2048 + T0 + vc;               \
        kh0A = *(const us8*)(projh + koA);                                     \
        kh1A = *(const us8*)(projh + koA + 8);                                 \
        vh0A = *(const us8*)(vTh + voA);                                       \
        vh1A = *(const us8*)(vTh + voA + 8);                                   \
        a_stA = (tid < 32) ? aarr[(size_t)bh * 2048 + T0 + tid] : 0.f;         \
        const size_t koB = koA + 32ull * 2304;                                 \
        const size_t voB = voA + 32;                                           \
        kh0B = *(const us8*)(projh + koB);                                     \
        kh1B = *(const us8*)(projh + koB + 8);                                 \
        vh0B = *(const us8*)(vTh + voB);                                       \
        vh1B = *(const us8*)(vTh + voB + 8);                                   \
        a_stB = (tid < 32) ? aarr[(size_t)bh * 2048 + T0 + 32 + tid] : 0.f;    \
    }
#define STOREPAIR(S)                                                           \
    {                                                                          \
        const int bA = 2 * (S), bB = 2 * (S) + 1;                              \
        *(us8*)&Klh[bA][kr * 148 + kc] = kh0A;                                 \
        *(us8*)&Klh[bA][kr * 148 + kc + 8] = kh1A;                             \
        *(us8*)&Vlh[bA][vr * 40 + vc] = vh0A;                                  \
        *(us8*)&Vlh[bA][vr * 40 + vc + 8] = vh1A;                              \
        *(us8*)&Klh[bB][kr * 148 + kc] = kh0B;                                 \
        *(us8*)&Klh[bB][kr * 148 + kc + 8] = kh1B;                             \
        *(us8*)&Vlh[bB][vr * 40 + vc] = vh0B;                                  \
        *(us8*)&Vlh[bB][vr * 40 + vc + 8] = vh1B;                              \
        if (tid < 32) {                                                        \
            al[bA][tid] = a_stA;                                               \
            al[bB][tid] = a_stB;                                               \
        }                                                                      \
    }

    LOADPAIR(0);
    STOREPAIR(0);
    if (npairs > 1) LOADPAIR(1);
    __syncthreads();

    for (int p = 0;;) {
        const int cur = p & 1;
        const int bA = 2 * cur, bB = 2 * cur + 1;
        const int t0 = p * 64;
        // store next pair into the other set (readers finished pre-barrier),
        // then prefetch pair p+2 into regs
        if (p + 1 < npairs) {
            STOREPAIR((p + 1) & 1);
            if (p + 2 < npairs) LOADPAIR(p + 2);
        }

        float djA[2][4], djB[2][4];
#pragma unroll
        for (int j = 0; j < 2; j++) {
            f32x4 sfaA = {}, sfbA = {};
            f32x4 sfaB = {}, sfbB = {};
            __builtin_amdgcn_s_setprio(1);
#pragma unroll
            for (int ks = 0; ks < 4; ks++) {
                bf16x8 kfhA = __builtin_bit_cast(bf16x8, *(const us8*)&Klh[bA][(j * 16 + fr) * 148 + ks * 32 + fg * 8]);
                bf16x8 kfhB = __builtin_bit_cast(bf16x8, *(const us8*)&Klh[bB][(j * 16 + fr) * 148 + ks * 32 + fg * 8]);
                sfaA = mfma16(kfhA, qfh[ks], sfaA);
                sfaB = mfma16(kfhB, qfh[ks], sfaB);
                sfbA = mfma16(kfhA, qfl[ks], sfbA);
                sfbB = mfma16(kfhB, qfl[ks], sfbB);
            }
            __builtin_amdgcn_s_setprio(0);
            f32x4 sfA = sfaA + sfbA;
            f32x4 sfB = sfaB + sfbB;
#pragma unroll
            for (int r = 0; r < 4; r++) {
                const int kloc = j * 16 + fg * 4 + r;
                const float atvA = al[bA][kloc];
                const float atvB = al[bB][kloc];
                djA[j][r] = ((t0 + kloc) <= qg) ? sfA[r] * __expf(atvA - ma_q) : 0.f;
                djB[j][r] = ((t0 + 32 + kloc) <= qg) ? sfB[r] * __expf(atvB - ma_q) : 0.f;
            }
        }

        {
            float tsA = djA[0][0] + djA[0][1] + djA[0][2] + djA[0][3]
                      + djA[1][0] + djA[1][1] + djA[1][2] + djA[1][3];
            tsA += __shfl_xor(tsA, 16);
            tsA += __shfl_xor(tsA, 32);
            b_run += tsA;
            float tsB = djB[0][0] + djB[0][1] + djB[0][2] + djB[0][3]
                      + djB[1][0] + djB[1][1] + djB[1][2] + djB[1][3];
            tsB += __shfl_xor(tsB, 16);
            tsB += __shfl_xor(tsB, 32);
            b_run += tsB;
        }

        const int srlo = 32 * ((lane >> 4) & 1) + fr;
        {
            float p8[8];
#pragma unroll
            for (int e = 0; e < 8; e++) {
                const int sl = srlo + ((e >= 4) ? 16 : 0);
                const float v0 = __shfl(djA[0][e & 3], sl);
                const float v1 = __shfl(djA[1][e & 3], sl);
                p8[e] = (lane & 32) ? v1 : v0;
            }
            us8 phu, plu;
#pragma unroll
            for (int e = 0; e < 8; e++) {
                unsigned short hh = f2bf(p8[e]);
                phu[e] = hh;
                plu[e] = f2bf(p8[e] - bf2f(hh));
            }
            const bf16x8 pfh = __builtin_bit_cast(bf16x8, phu);
            const bf16x8 pfl = __builtin_bit_cast(bf16x8, plu);
            __builtin_amdgcn_s_setprio(1);
#pragma unroll
            for (int jb = 0; jb < 8; jb++) {
                bf16x8 vfh = __builtin_bit_cast(bf16x8, *(const us8*)&Vlh[bA][(jb * 16 + fr) * 40 + fg * 8]);
                acc[jb] = mfma16(vfh, pfh, acc[jb]);
                acc[jb] = mfma16(vfh, pfl, acc[jb]);
            }
            __builtin_amdgcn_s_setprio(0);
        }
        {
            float p8[8];
#pragma unroll
            for (int e = 0; e < 8; e++) {
                const int sl = srlo + ((e >= 4) ? 16 : 0);
                const float v0 = __shfl(djB[0][e & 3], sl);
                const float v1 = __shfl(djB[1][e & 3], sl);
                p8[e] = (lane & 32) ? v1 : v0;
            }
            us8 phu, plu;
#pragma unroll
            for (int e = 0; e < 8; e++) {
                unsigned short hh = f2bf(p8[e]);
                phu[e] = hh;
                plu[e] = f2bf(p8[e] - bf2f(hh));
            }
            const bf16x8 pfh = __builtin_bit_cast(bf16x8, phu);
            const bf16x8 pfl = __builtin_bit_cast(bf16x8, plu);
            __builtin_amdgcn_s_setprio(1);
#pragma unroll
            for (int jb = 0; jb < 8; jb++) {
                bf16x8 vfh = __builtin_bit_cast(bf16x8, *(const us8*)&Vlh[bB][(jb * 16 + fr) * 40 + fg * 8]);
                acc[jb] = mfma16(vfh, pfh, acc[jb]);
                acc[jb] = mfma16(vfh, pfl, acc[jb]);
            }
            __builtin_amdgcn_s_setprio(0);
        }

        p++;
        if (p >= npairs) break;
        __syncthreads();   // next-set stores visible; current set safe to reuse
    }
#undef LOADPAIR
#undef STOREPAIR

    const float cs_q = csum[(size_t)bh * 2048 + qg];
    const float nf = __expf(-(cs_q + ma_q));
    const float n = fmaxf(fabsf(b_run), nf);
    const float inv = 1.f / (n + 1e-6f);
#pragma unroll
    for (int jb = 0; jb < 8; jb++) acc[jb] *= inv;

    float s1 = 0.f;
#pragma unroll
    for (int jb = 0; jb < 8; jb++) s1 += acc[jb][0] + acc[jb][1] + acc[jb][2] + acc[jb][3];
    s1 += __shfl_xor(s1, 16);
    s1 += __shfl_xor(s1, 32);
    const float mu = s1 * (1.f / 128.f);
    float vv = 0.f;
#pragma unroll
    for (int jb = 0; jb < 8; jb++)
#pragma unroll
        for (int e = 0; e < 4; e++) {
            float d = acc[jb][e] - mu;
            vv += d * d;
        }
    vv += __shfl_xor(vv, 16);
    vv += __shfl_xor(vv, 32);
    const float rstd = rsqrtf(vv * (1.f / 128.f) + 1e-6f);

    const size_t obase = (size_t)(b * 2048 + qg) * 2304 + 1280 + h * 128 + fg * 4;
    const size_t hbase = (size_t)(b * 2048 + qg) * 1024 + h * 128 + fg * 4;
#pragma unroll
    for (int jb = 0; jb < 8; jb++) {
        us4 ogh = *(const us4*)(projh + obase + jb * 16);
        us4 ogl = *(const us4*)(projl + obase + jb * 16);
        f32x4 lw = *(const f32x4*)&lnw[h * 128 + jb * 16 + fg * 4];
        us4 hi4, lo4;
#pragma unroll
        for (int e = 0; e < 4; e++) {
            const float og = bf2f(ogh[e]) + bf2f(ogl[e]);
            const float sig = 1.f / (1.f + __expf(-og));
            const float ho = (acc[jb][e] - mu) * rstd * lw[e] * sig;
            unsigned short h1 = f2bf(ho);
            hi4[e] = h1;
            lo4[e] = f2bf(ho - bf2f(h1));
        }
        *(us4*)&ho_hi[hbase + jb * 16] = hi4;
        *(us4*)&ho_lo[hbase + jb * 16] = lo4;
    }
}

// ---------------------------------------------------------------------------
extern "C" void kernel_launch(void* const* d_in, const int* in_sizes, int n_in,
                              void* d_out, int out_size, void* d_ws, size_t ws_size,
                              hipStream_t stream) {
    (void)in_sizes; (void)n_in; (void)out_size; (void)ws_size;
    const float* x    = (const float*)d_in[0];
    const float* Wq   = (const float*)d_in[1];
    const float* Wk   = (const float*)d_in[2];
    const float* Wv   = (const float*)d_in[3];
    const float* Wog  = (const float*)d_in[4];
    const float* Wi   = (const float*)d_in[5];
    const float* bi   = (const float*)d_in[6];
    const float* Wf   = (const float*)d_in[7];
    const float* bfb  = (const float*)d_in[8];
    const float* lnw  = (const float*)d_in[9];
    const float* Wout = (const float*)d_in[10];

    char* p = (char*)d_ws;
    auto carve = [&](size_t bytes) -> char* {
        char* r = p;
        p += (bytes + 255) & ~(size_t)255;
        return r;
    };
    unsigned short* x_hi   = (unsigned short*)carve(4194304ull * 2);
    unsigned short* x_lo   = (unsigned short*)carve(4194304ull * 2);
    unsigned short* wc_hi  = (unsigned short*)carve(2359296ull * 2);
    unsigned short* wc_lo  = (unsigned short*)carve(2359296ull * 2);
    unsigned short* wo_hi  = (unsigned short*)carve(1048576ull * 2);
    unsigned short* wo_lo  = (unsigned short*)carve(1048576ull * 2);
    unsigned short* pr_hi  = (unsigned short*)carve(4096ull * 2304 * 2);
    unsigned short* pr_lo  = (unsigned short*)carve(4096ull * 2304 * 2);
    unsigned short* vT_hi  = (unsigned short*)carve(524288ull * 2);
    float* ipre    = (float*)carve(32768ull * 4);
    float* lgf_buf = (float*)carve(32768ull * 4);
    float* csum    = (float*)carve(32768ull * 4);
    float* aarr    = (float*)carve(32768ull * 4);
    float* marr    = (float*)carve(32768ull * 4);
    unsigned short* ho_hi = x_hi;   // x dead after proj GEMM
    unsigned short* ho_lo = x_lo;

    prep<<<7424, 256, 0, stream>>>(x, Wq, Wk, Wv, Wog, Wout,
                                   x_hi, x_lo, wc_hi, wc_lo, wo_hi, wo_lo);
    gates_kernel<<<4096, 256, 0, stream>>>(x, Wi, bi, Wf, bfb, ipre, lgf_buf);
    scan_kernel<<<16, 64, 0, stream>>>(ipre, lgf_buf, csum, aarr, marr);
    gemm_bt3<<<dim3(32, 18), 256, 0, stream>>>(x_hi, x_lo, wc_hi, wc_lo, pr_hi, pr_lo, 1024, 2304, 1, 10);
    make_vt<<<128, 256, 0, stream>>>(pr_hi, vT_hi);
    attn_fused<<<512, 256, 0, stream>>>(pr_hi, pr_lo, vT_hi, aarr, marr, csum, lnw, ho_hi, ho_lo);
    gemm_bt3<<<dim3(32, 8), 256, 0, stream>>>(ho_hi, ho_lo, wo_hi, wo_lo, d_out, nullptr, 1024, 1024, 0, 1000);
}